// Round 1
// baseline (1239.640 us; speedup 1.0000x reference)
//
#include <hip/hip_runtime.h>
#include <hip/hip_bf16.h>

// 3-layer GCN, fp32. Pipeline per launch:
//   deg count -> norms -> CSR build (scan + fill) ->
//   [gemm -> csr-agg -> bn_reduce -> bn_finalize -> bn_apply(relu)] x2 ->
//   gemm(40, padded to 64) -> csr-agg + bias -> d_out
// Workspace layout (~111 MB): A(51.2M) B(51.2M) ns nd outdeg indeg row_ptr
// cursor sorted_src stats0 stats1 ab0 ab1.

#define D_H 128

// ---------------- degree / norms / CSR ----------------

__global__ void deg_kernel(const int* __restrict__ src, const int* __restrict__ dst,
                           int* __restrict__ outdeg, int* __restrict__ indeg, int E) {
    int e = blockIdx.x * 256 + threadIdx.x;
    if (e < E) {
        atomicAdd(&outdeg[src[e]], 1);
        atomicAdd(&indeg[dst[e]], 1);
    }
}

__global__ void norm_kernel(const int* __restrict__ outdeg, const int* __restrict__ indeg,
                            float* __restrict__ ns, float* __restrict__ nd, int n) {
    int i = blockIdx.x * 256 + threadIdx.x;
    if (i < n) {
        ns[i] = rsqrtf((float)max(outdeg[i], 1));
        nd[i] = rsqrtf((float)max(indeg[i], 1));
    }
}

// single block, 1024 threads: exclusive prefix sum of indeg -> row_ptr, cursor
__global__ void scan_kernel(const int* __restrict__ deg, int* __restrict__ row_ptr,
                            int* __restrict__ cursor, int n) {
    __shared__ int sums[1024];
    int tid = threadIdx.x;
    int chunk = (n + 1023) >> 10;
    int start = tid * chunk;
    int end = min(start + chunk, n);
    int s = 0;
    for (int i = start; i < end; ++i) s += deg[i];
    sums[tid] = s;
    __syncthreads();
    for (int off = 1; off < 1024; off <<= 1) {
        int v = (tid >= off) ? sums[tid - off] : 0;
        __syncthreads();
        sums[tid] += v;
        __syncthreads();
    }
    int base = sums[tid] - s;  // exclusive
    for (int i = start; i < end; ++i) {
        row_ptr[i] = base;
        cursor[i] = base;
        base += deg[i];
    }
    if (tid == 1023) row_ptr[n] = sums[1023];
}

__global__ void fill_kernel(const int* __restrict__ src, const int* __restrict__ dst,
                            int* __restrict__ cursor, int* __restrict__ ssrc, int E) {
    int e = blockIdx.x * 256 + threadIdx.x;
    if (e < E) {
        int p = atomicAdd(&cursor[dst[e]], 1);
        ssrc[p] = src[e];
    }
}

// ---------------- GEMM: Y[r][c] = sum_k X[r][k]*ns[r]*W[k][c] ----------------
// BM=128, BK=32, 256 threads (16x16), thread tile 8 x (BN/16).
template <int BN, int WCOLS>
__global__ __launch_bounds__(256) void gemm_kernel(
    const float* __restrict__ X, const float* __restrict__ W,
    const float* __restrict__ ns, float* __restrict__ Y, int nrows) {
    constexpr int BM = 128, BK = 32;
    constexpr int TN = BN / 16;  // 8 (BN=128) or 4 (BN=64)
    constexpr int TM = 8;
    __shared__ float As[BK][BM + 4];  // stride 132 floats = 528B, 16B aligned
    __shared__ float Bs[BK][BN + 4];
    int tid = threadIdx.x;
    int tc = tid & 15, tr = tid >> 4;
    int row0 = blockIdx.x * BM;
    float acc[TM][TN] = {};

    for (int kc = 0; kc < D_H; kc += BK) {
        // stage A transposed (k-major), scaled by ns
        for (int i = tid; i < BM * BK / 4; i += 256) {
            int r = i >> 3;
            int k4 = (i & 7) << 2;
            int row = row0 + r;
            float4 v = make_float4(0.f, 0.f, 0.f, 0.f);
            float sc = 0.f;
            if (row < nrows) {
                v = *(const float4*)(X + (size_t)row * D_H + kc + k4);
                sc = ns[row];
            }
            As[k4 + 0][r] = v.x * sc;
            As[k4 + 1][r] = v.y * sc;
            As[k4 + 2][r] = v.z * sc;
            As[k4 + 3][r] = v.w * sc;
        }
        // stage B (zero-pad cols >= WCOLS)
        for (int i = tid; i < BK * BN; i += 256) {
            int k = i / BN, c = i % BN;
            Bs[k][c] = (c < WCOLS) ? W[(size_t)(kc + k) * WCOLS + c] : 0.f;
        }
        __syncthreads();
#pragma unroll
        for (int k = 0; k < BK; ++k) {
            float a[TM], b[TN];
            *(float4*)&a[0] = *(const float4*)&As[k][tr * TM];
            *(float4*)&a[4] = *(const float4*)&As[k][tr * TM + 4];
#pragma unroll
            for (int j = 0; j < TN; j += 4)
                *(float4*)&b[j] = *(const float4*)&Bs[k][tc * TN + j];
#pragma unroll
            for (int m = 0; m < TM; ++m)
#pragma unroll
                for (int n = 0; n < TN; ++n)
                    acc[m][n] = fmaf(a[m], b[n], acc[m][n]);
        }
        __syncthreads();
    }
#pragma unroll
    for (int m = 0; m < TM; ++m) {
        int row = row0 + tr * TM + m;
        if (row < nrows) {
#pragma unroll
            for (int j = 0; j < TN; j += 4)
                *(float4*)(Y + (size_t)row * BN + tc * TN + j) = *(float4*)&acc[m][j];
        }
    }
}

// ---------------- CSR aggregation (no atomics) ----------------
// one wave (64 lanes) per node; lane handles 2 floats of the 128-wide row
__global__ __launch_bounds__(256) void agg128_kernel(
    const float* __restrict__ xw, const int* __restrict__ row_ptr,
    const int* __restrict__ ssrc, const float* __restrict__ nd,
    float* __restrict__ out, int n) {
    int node = blockIdx.x * 4 + (threadIdx.x >> 6);
    if (node >= n) return;
    int lane = threadIdx.x & 63;
    int beg = row_ptr[node], end = row_ptr[node + 1];
    float x = 0.f, y = 0.f;
    int e = beg;
    for (; e + 1 < end; e += 2) {
        int s0 = ssrc[e], s1 = ssrc[e + 1];
        float2 v0 = *(const float2*)(xw + (size_t)s0 * D_H + lane * 2);
        float2 v1 = *(const float2*)(xw + (size_t)s1 * D_H + lane * 2);
        x += v0.x + v1.x;
        y += v0.y + v1.y;
    }
    if (e < end) {
        int s0 = ssrc[e];
        float2 v0 = *(const float2*)(xw + (size_t)s0 * D_H + lane * 2);
        x += v0.x;
        y += v0.y;
    }
    float s = nd[node];
    *(float2*)(out + (size_t)node * D_H + lane * 2) = make_float2(x * s, y * s);
}

// final layer: xw has row stride 64 (cols 40..63 are zero), out 40 cols + bias
__global__ __launch_bounds__(256) void agg_final_kernel(
    const float* __restrict__ xw, const int* __restrict__ row_ptr,
    const int* __restrict__ ssrc, const float* __restrict__ nd,
    const float* __restrict__ bias, float* __restrict__ out, int n) {
    int node = blockIdx.x * 4 + (threadIdx.x >> 6);
    if (node >= n) return;
    int lane = threadIdx.x & 63;
    int beg = row_ptr[node], end = row_ptr[node + 1];
    float acc = 0.f;
    for (int e = beg; e < end; ++e) {
        int s0 = ssrc[e];
        acc += xw[(size_t)s0 * 64 + lane];
    }
    if (lane < 40) out[(size_t)node * 40 + lane] = acc * nd[node] + bias[lane];
}

// ---------------- batchnorm ----------------

__global__ __launch_bounds__(256) void bn_reduce_kernel(const float* __restrict__ x,
                                                        float* __restrict__ stats, int n) {
    int tid = threadIdx.x;
    int col = tid & 127, half = tid >> 7;
    float s = 0.f, s2 = 0.f;
    for (int r = blockIdx.x * 2 + half; r < n; r += gridDim.x * 2) {
        float v = x[(size_t)r * D_H + col];
        s += v;
        s2 = fmaf(v, v, s2);
    }
    __shared__ float red[256];
    red[tid] = s;
    __syncthreads();
    if (half == 0) atomicAdd(&stats[col], s + red[tid + 128]);
    __syncthreads();
    red[tid] = s2;
    __syncthreads();
    if (half == 0) atomicAdd(&stats[128 + col], s2 + red[tid + 128]);
}

__global__ void bn_finalize_kernel(const float* __restrict__ stats,
                                   const float* __restrict__ g,
                                   const float* __restrict__ beta,
                                   float* __restrict__ ab, float inv_n) {
    int c = threadIdx.x;  // 128 threads
    float mean = stats[c] * inv_n;
    float var = stats[128 + c] * inv_n - mean * mean;
    float a = rsqrtf(var + 1e-5f) * g[c];
    ab[c] = a;
    ab[128 + c] = beta[c] - mean * a;
}

// y = relu(x*a + b), in place; one float4 per thread
__global__ __launch_bounds__(256) void bn_apply_kernel(float* __restrict__ x,
                                                       const float* __restrict__ ab,
                                                       size_t total4) {
    size_t i = (size_t)blockIdx.x * 256 + threadIdx.x;
    if (i >= total4) return;
    float4 v = ((float4*)x)[i];
    int c = (int)(i & 31) * 4;  // 32 float4 per 128-wide row
    const float4 a = *(const float4*)&ab[c];
    const float4 b = *(const float4*)&ab[128 + c];
    v.x = fmaxf(fmaf(v.x, a.x, b.x), 0.f);
    v.y = fmaxf(fmaf(v.y, a.y, b.y), 0.f);
    v.z = fmaxf(fmaf(v.z, a.z, b.z), 0.f);
    v.w = fmaxf(fmaf(v.w, a.w, b.w), 0.f);
    ((float4*)x)[i] = v;
}

// ---------------- launch ----------------

extern "C" void kernel_launch(void* const* d_in, const int* in_sizes, int n_in,
                              void* d_out, int out_size, void* d_ws, size_t ws_size,
                              hipStream_t stream) {
    const float* feat = (const float*)d_in[0];
    const int* edge_src = (const int*)d_in[1];
    const int* edge_dst = (const int*)d_in[2];
    const float* W0 = (const float*)d_in[3];
    const float* W1 = (const float*)d_in[4];
    const float* W2 = (const float*)d_in[5];
    const float* b2 = (const float*)d_in[6];
    const float* g0 = (const float*)d_in[7];
    const float* beta0 = (const float*)d_in[8];
    const float* g1 = (const float*)d_in[9];
    const float* beta1 = (const float*)d_in[10];
    float* out = (float*)d_out;

    const int N = in_sizes[0] / D_H;  // 100000
    const int E = in_sizes[1];        // 1600000

    // workspace carve-up
    char* p = (char*)d_ws;
    auto alloc = [&](size_t bytes) {
        char* r = p;
        p += (bytes + 255) & ~(size_t)255;
        return r;
    };
    float* A = (float*)alloc((size_t)N * D_H * 4);
    float* B = (float*)alloc((size_t)N * D_H * 4);
    float* ns = (float*)alloc((size_t)N * 4);
    float* nd = (float*)alloc((size_t)N * 4);
    int* outdeg = (int*)alloc((size_t)N * 4);
    int* indeg = (int*)alloc((size_t)N * 4);
    int* row_ptr = (int*)alloc((size_t)(N + 1) * 4);
    int* cursor = (int*)alloc((size_t)N * 4);
    int* ssrc = (int*)alloc((size_t)E * 4);
    float* stats0 = (float*)alloc(256 * 4);
    float* stats1 = (float*)alloc(256 * 4);
    float* ab0 = (float*)alloc(256 * 4);
    float* ab1 = (float*)alloc(256 * 4);
    (void)ws_size;

    // zero what must start at 0 (ws is poisoned 0xAA before every call)
    hipMemsetAsync(outdeg, 0, (size_t)N * 4, stream);
    hipMemsetAsync(indeg, 0, (size_t)N * 4, stream);
    hipMemsetAsync(stats0, 0, 256 * 4, stream);
    hipMemsetAsync(stats1, 0, 256 * 4, stream);

    const int egrid = (E + 255) / 256;
    const int ngrid = (N + 255) / 256;
    const int ggrid = (N + 127) / 128;
    const int agrid = (N + 3) / 4;

    deg_kernel<<<egrid, 256, 0, stream>>>(edge_src, edge_dst, outdeg, indeg, E);
    norm_kernel<<<ngrid, 256, 0, stream>>>(outdeg, indeg, ns, nd, N);
    scan_kernel<<<1, 1024, 0, stream>>>(indeg, row_ptr, cursor, N);
    fill_kernel<<<egrid, 256, 0, stream>>>(edge_src, edge_dst, cursor, ssrc, E);

    // layer 0: feat -> B -> A, bn+relu
    gemm_kernel<128, 128><<<ggrid, 256, 0, stream>>>(feat, W0, ns, B, N);
    agg128_kernel<<<agrid, 256, 0, stream>>>(B, row_ptr, ssrc, nd, A, N);
    bn_reduce_kernel<<<512, 256, 0, stream>>>(A, stats0, N);
    bn_finalize_kernel<<<1, 128, 0, stream>>>(stats0, g0, beta0, ab0, 1.0f / N);
    bn_apply_kernel<<<(N * 32 + 255) / 256, 256, 0, stream>>>(A, ab0, (size_t)N * 32);

    // layer 1: A -> B -> A, bn+relu
    gemm_kernel<128, 128><<<ggrid, 256, 0, stream>>>(A, W1, ns, B, N);
    agg128_kernel<<<agrid, 256, 0, stream>>>(B, row_ptr, ssrc, nd, A, N);
    bn_reduce_kernel<<<512, 256, 0, stream>>>(A, stats1, N);
    bn_finalize_kernel<<<1, 128, 0, stream>>>(stats1, g1, beta1, ab1, 1.0f / N);
    bn_apply_kernel<<<(N * 32 + 255) / 256, 256, 0, stream>>>(A, ab1, (size_t)N * 32);

    // layer 2: A -> B (stride 64, cols 40..63 zero) -> out (+bias)
    gemm_kernel<64, 40><<<ggrid, 256, 0, stream>>>(A, W2, ns, B, N);
    agg_final_kernel<<<agrid, 256, 0, stream>>>(B, row_ptr, ssrc, nd, b2, out, N);
}

// Round 3
// 1018.571 us; speedup vs baseline: 1.2170x; 1.2170x over previous
//
#include <hip/hip_runtime.h>
#include <hip/hip_bf16.h>

// 3-layer GCN, fp32. Pipeline per launch:
//   deg count -> norms -> CSR scan (scan1: block sums; scan3: per-block base
//   recomputed from bsum + local scan + write row_ptr/cursor) -> fill ->
//   [gemm -> csr-agg -> bn_reduce -> bn_finalize -> bn_apply(relu)] x2 ->
//   gemm(40, padded to 64) -> csr-agg + bias -> d_out
// R3: scan2 removed (bsum is now write-once in scan1, read-only after);
// cursor aliases the indeg buffer (dead after scan3) so total ws footprint
// (110.8 MB) is strictly below the R1 footprint that passed all tripwires.

#define D_H 128
#define SCAN_CHUNK 1024  // per block: 256 threads x 4 ints

// ---------------- degree / norms ----------------

__global__ void deg_kernel(const int* __restrict__ src, const int* __restrict__ dst,
                           int* __restrict__ outdeg, int* __restrict__ indeg, int E) {
    int e = blockIdx.x * 256 + threadIdx.x;
    if (e < E) {
        atomicAdd(&outdeg[src[e]], 1);
        atomicAdd(&indeg[dst[e]], 1);
    }
}

__global__ void norm_kernel(const int* __restrict__ outdeg, const int* __restrict__ indeg,
                            float* __restrict__ ns, float* __restrict__ nd, int n) {
    int i = blockIdx.x * 256 + threadIdx.x;
    if (i < n) {
        ns[i] = rsqrtf((float)max(outdeg[i], 1));
        nd[i] = rsqrtf((float)max(indeg[i], 1));
    }
}

// ---------------- CSR scan: indeg -> row_ptr, cursor (cursor aliases indeg) --

// per-block sums of SCAN_CHUNK ints -> bsum[block]  (bsum is write-once here)
__global__ __launch_bounds__(256) void scan1_kernel(const int* __restrict__ deg,
                                                    int* __restrict__ bsum, int n) {
    int tid = threadIdx.x;
    int base = blockIdx.x * SCAN_CHUNK + tid * 4;
    int4 v = make_int4(0, 0, 0, 0);
    if (base + 3 < n) {
        v = *(const int4*)(deg + base);
    } else {
        if (base + 0 < n) v.x = deg[base + 0];
        if (base + 1 < n) v.y = deg[base + 1];
        if (base + 2 < n) v.z = deg[base + 2];
        if (base + 3 < n) v.w = deg[base + 3];
    }
    int s = v.x + v.y + v.z + v.w;
    __shared__ int red[256];
    red[tid] = s;
    __syncthreads();
#pragma unroll
    for (int off = 128; off > 0; off >>= 1) {
        if (tid < off) red[tid] += red[tid + off];
        __syncthreads();
    }
    if (tid == 0) bsum[blockIdx.x] = red[0];
}

// each block: scan bsum[0..g) in LDS (g<=128) for its own base, local scan of
// its chunk, write row_ptr+cursor. degcur serves as BOTH deg input and cursor
// output (each slot read then written by exactly one thread). Last block
// writes row_ptr[n] = total.
__global__ __launch_bounds__(256) void scan3_kernel(int* degcur,
                                                    const int* __restrict__ bsum,
                                                    int* __restrict__ row_ptr,
                                                    int g, int n) {
    int tid = threadIdx.x;
    int base = blockIdx.x * SCAN_CHUNK + tid * 4;
    int4 v = make_int4(0, 0, 0, 0);
    if (base + 3 < n) {
        v = *(const int4*)(degcur + base);
    } else {
        if (base + 0 < n) v.x = degcur[base + 0];
        if (base + 1 < n) v.y = degcur[base + 1];
        if (base + 2 < n) v.z = degcur[base + 2];
        if (base + 3 < n) v.w = degcur[base + 3];
    }
    int s = v.x + v.y + v.z + v.w;

    // inclusive scan of block sums (g <= 128) in LDS
    __shared__ int bs[128];
    if (tid < 128) bs[tid] = (tid < g) ? bsum[tid] : 0;
    __syncthreads();
#pragma unroll
    for (int off = 1; off < 128; off <<= 1) {
        int t = (tid < 128 && tid >= off) ? bs[tid - off] : 0;
        __syncthreads();
        if (tid < 128) bs[tid] += t;
        __syncthreads();
    }
    int blockbase = (blockIdx.x == 0) ? 0 : bs[blockIdx.x - 1];
    int total = bs[g - 1];

    // local inclusive scan of per-thread sums
    __shared__ int sc[256];
    sc[tid] = s;
    __syncthreads();
#pragma unroll
    for (int off = 1; off < 256; off <<= 1) {
        int t = (tid >= off) ? sc[tid - off] : 0;
        __syncthreads();
        sc[tid] += t;
        __syncthreads();
    }
    int excl = sc[tid] - s + blockbase;
    int p0 = excl;
    int p1 = p0 + v.x;
    int p2 = p1 + v.y;
    int p3 = p2 + v.z;
    if (base + 3 < n) {
        *(int4*)(row_ptr + base) = make_int4(p0, p1, p2, p3);
        *(int4*)(degcur + base) = make_int4(p0, p1, p2, p3);  // cursor
    } else {
        if (base + 0 < n) { row_ptr[base + 0] = p0; degcur[base + 0] = p0; }
        if (base + 1 < n) { row_ptr[base + 1] = p1; degcur[base + 1] = p1; }
        if (base + 2 < n) { row_ptr[base + 2] = p2; degcur[base + 2] = p2; }
    }
    if (blockIdx.x == g - 1 && tid == 0) row_ptr[n] = total;
}

__global__ void fill_kernel(const int* __restrict__ src, const int* __restrict__ dst,
                            int* __restrict__ cursor, int* __restrict__ ssrc, int E) {
    int e = blockIdx.x * 256 + threadIdx.x;
    if (e < E) {
        int p = atomicAdd(&cursor[dst[e]], 1);
        ssrc[p] = src[e];
    }
}

// ---------------- GEMM: Y[r][c] = sum_k X[r][k]*ns[r]*W[k][c] ----------------
// BM=128, BK=32, 256 threads (16x16), thread tile 8 x (BN/16).
template <int BN, int WCOLS>
__global__ __launch_bounds__(256) void gemm_kernel(
    const float* __restrict__ X, const float* __restrict__ W,
    const float* __restrict__ ns, float* __restrict__ Y, int nrows) {
    constexpr int BM = 128, BK = 32;
    constexpr int TN = BN / 16;  // 8 (BN=128) or 4 (BN=64)
    constexpr int TM = 8;
    __shared__ float As[BK][BM + 4];  // stride 132 floats = 528B, 16B aligned
    __shared__ float Bs[BK][BN + 4];
    int tid = threadIdx.x;
    int tc = tid & 15, tr = tid >> 4;
    int row0 = blockIdx.x * BM;
    float acc[TM][TN] = {};

    for (int kc = 0; kc < D_H; kc += BK) {
        // stage A transposed (k-major), scaled by ns
        for (int i = tid; i < BM * BK / 4; i += 256) {
            int r = i >> 3;
            int k4 = (i & 7) << 2;
            int row = row0 + r;
            float4 v = make_float4(0.f, 0.f, 0.f, 0.f);
            float sc = 0.f;
            if (row < nrows) {
                v = *(const float4*)(X + (size_t)row * D_H + kc + k4);
                sc = ns[row];
            }
            As[k4 + 0][r] = v.x * sc;
            As[k4 + 1][r] = v.y * sc;
            As[k4 + 2][r] = v.z * sc;
            As[k4 + 3][r] = v.w * sc;
        }
        // stage B (zero-pad cols >= WCOLS)
        for (int i = tid; i < BK * BN; i += 256) {
            int k = i / BN, c = i % BN;
            Bs[k][c] = (c < WCOLS) ? W[(size_t)(kc + k) * WCOLS + c] : 0.f;
        }
        __syncthreads();
#pragma unroll
        for (int k = 0; k < BK; ++k) {
            float a[TM], b[TN];
            *(float4*)&a[0] = *(const float4*)&As[k][tr * TM];
            *(float4*)&a[4] = *(const float4*)&As[k][tr * TM + 4];
#pragma unroll
            for (int j = 0; j < TN; j += 4)
                *(float4*)&b[j] = *(const float4*)&Bs[k][tc * TN + j];
#pragma unroll
            for (int m = 0; m < TM; ++m)
#pragma unroll
                for (int n = 0; n < TN; ++n)
                    acc[m][n] = fmaf(a[m], b[n], acc[m][n]);
        }
        __syncthreads();
    }
#pragma unroll
    for (int m = 0; m < TM; ++m) {
        int row = row0 + tr * TM + m;
        if (row < nrows) {
#pragma unroll
            for (int j = 0; j < TN; j += 4)
                *(float4*)(Y + (size_t)row * BN + tc * TN + j) = *(float4*)&acc[m][j];
        }
    }
}

// ---------------- CSR aggregation (no atomics) ----------------
// one wave (64 lanes) per node; lane handles 2 floats of the 128-wide row
__global__ __launch_bounds__(256) void agg128_kernel(
    const float* __restrict__ xw, const int* __restrict__ row_ptr,
    const int* __restrict__ ssrc, const float* __restrict__ nd,
    float* __restrict__ out, int n) {
    int node = blockIdx.x * 4 + (threadIdx.x >> 6);
    if (node >= n) return;
    int lane = threadIdx.x & 63;
    int beg = row_ptr[node], end = row_ptr[node + 1];
    float x = 0.f, y = 0.f;
    int e = beg;
    for (; e + 1 < end; e += 2) {
        int s0 = ssrc[e], s1 = ssrc[e + 1];
        float2 v0 = *(const float2*)(xw + (size_t)s0 * D_H + lane * 2);
        float2 v1 = *(const float2*)(xw + (size_t)s1 * D_H + lane * 2);
        x += v0.x + v1.x;
        y += v0.y + v1.y;
    }
    if (e < end) {
        int s0 = ssrc[e];
        float2 v0 = *(const float2*)(xw + (size_t)s0 * D_H + lane * 2);
        x += v0.x;
        y += v0.y;
    }
    float s = nd[node];
    *(float2*)(out + (size_t)node * D_H + lane * 2) = make_float2(x * s, y * s);
}

// final layer: xw has row stride 64 (cols 40..63 are zero), out 40 cols + bias
__global__ __launch_bounds__(256) void agg_final_kernel(
    const float* __restrict__ xw, const int* __restrict__ row_ptr,
    const int* __restrict__ ssrc, const float* __restrict__ nd,
    const float* __restrict__ bias, float* __restrict__ out, int n) {
    int node = blockIdx.x * 4 + (threadIdx.x >> 6);
    if (node >= n) return;
    int lane = threadIdx.x & 63;
    int beg = row_ptr[node], end = row_ptr[node + 1];
    float acc = 0.f;
    for (int e = beg; e < end; ++e) {
        int s0 = ssrc[e];
        acc += xw[(size_t)s0 * 64 + lane];
    }
    if (lane < 40) out[(size_t)node * 40 + lane] = acc * nd[node] + bias[lane];
}

// ---------------- batchnorm ----------------

__global__ __launch_bounds__(256) void bn_reduce_kernel(const float* __restrict__ x,
                                                        float* __restrict__ stats, int n) {
    int tid = threadIdx.x;
    int col = tid & 127, half = tid >> 7;
    float s = 0.f, s2 = 0.f;
    for (int r = blockIdx.x * 2 + half; r < n; r += gridDim.x * 2) {
        float v = x[(size_t)r * D_H + col];
        s += v;
        s2 = fmaf(v, v, s2);
    }
    __shared__ float red[256];
    red[tid] = s;
    __syncthreads();
    if (half == 0) atomicAdd(&stats[col], s + red[tid + 128]);
    __syncthreads();
    red[tid] = s2;
    __syncthreads();
    if (half == 0) atomicAdd(&stats[128 + col], s2 + red[tid + 128]);
}

__global__ void bn_finalize_kernel(const float* __restrict__ stats,
                                   const float* __restrict__ g,
                                   const float* __restrict__ beta,
                                   float* __restrict__ ab, float inv_n) {
    int c = threadIdx.x;  // 128 threads
    float mean = stats[c] * inv_n;
    float var = stats[128 + c] * inv_n - mean * mean;
    float a = rsqrtf(var + 1e-5f) * g[c];
    ab[c] = a;
    ab[128 + c] = beta[c] - mean * a;
}

// y = relu(x*a + b), in place; one float4 per thread
__global__ __launch_bounds__(256) void bn_apply_kernel(float* __restrict__ x,
                                                       const float* __restrict__ ab,
                                                       size_t total4) {
    size_t i = (size_t)blockIdx.x * 256 + threadIdx.x;
    if (i >= total4) return;
    float4 v = ((float4*)x)[i];
    int c = (int)(i & 31) * 4;  // 32 float4 per 128-wide row
    const float4 a = *(const float4*)&ab[c];
    const float4 b = *(const float4*)&ab[128 + c];
    v.x = fmaxf(fmaf(v.x, a.x, b.x), 0.f);
    v.y = fmaxf(fmaf(v.y, a.y, b.y), 0.f);
    v.z = fmaxf(fmaf(v.z, a.z, b.z), 0.f);
    v.w = fmaxf(fmaf(v.w, a.w, b.w), 0.f);
    ((float4*)x)[i] = v;
}

// ---------------- launch ----------------

extern "C" void kernel_launch(void* const* d_in, const int* in_sizes, int n_in,
                              void* d_out, int out_size, void* d_ws, size_t ws_size,
                              hipStream_t stream) {
    const float* feat = (const float*)d_in[0];
    const int* edge_src = (const int*)d_in[1];
    const int* edge_dst = (const int*)d_in[2];
    const float* W0 = (const float*)d_in[3];
    const float* W1 = (const float*)d_in[4];
    const float* W2 = (const float*)d_in[5];
    const float* b2 = (const float*)d_in[6];
    const float* g0 = (const float*)d_in[7];
    const float* beta0 = (const float*)d_in[8];
    const float* g1 = (const float*)d_in[9];
    const float* beta1 = (const float*)d_in[10];
    float* out = (float*)d_out;

    const int N = in_sizes[0] / D_H;  // 100000
    const int E = in_sizes[1];        // 1600000

    // workspace carve-up (total ~110.8 MB, below the R1-proven footprint)
    char* p = (char*)d_ws;
    auto alloc = [&](size_t bytes) {
        char* r = p;
        p += (bytes + 255) & ~(size_t)255;
        return r;
    };
    float* A = (float*)alloc((size_t)N * D_H * 4);
    float* B = (float*)alloc((size_t)N * D_H * 4);
    float* ns = (float*)alloc((size_t)N * 4);
    float* nd = (float*)alloc((size_t)N * 4);
    int* outdeg = (int*)alloc((size_t)N * 4);
    int* indeg = (int*)alloc((size_t)N * 4);  // becomes cursor after scan3
    int* row_ptr = (int*)alloc((size_t)(N + 1) * 4);
    int* ssrc = (int*)alloc((size_t)E * 4);
    int* bsum = (int*)alloc(256 * 4);
    float* stats0 = (float*)alloc(256 * 4);
    float* stats1 = (float*)alloc(256 * 4);
    float* ab0 = (float*)alloc(256 * 4);
    float* ab1 = (float*)alloc(256 * 4);
    int* cursor = indeg;  // alias: indeg is dead after scan3 rewrites it
    (void)ws_size;

    // zero what must start at 0 (ws is poisoned 0xAA before every call)
    hipMemsetAsync(outdeg, 0, (size_t)N * 4, stream);
    hipMemsetAsync(indeg, 0, (size_t)N * 4, stream);
    hipMemsetAsync(stats0, 0, 256 * 4, stream);
    hipMemsetAsync(stats1, 0, 256 * 4, stream);

    const int egrid = (E + 255) / 256;
    const int ngrid = (N + 255) / 256;
    const int ggrid = (N + 127) / 128;
    const int agrid = (N + 3) / 4;
    const int sgrid = (N + SCAN_CHUNK - 1) / SCAN_CHUNK;  // 98 blocks (<=128)

    deg_kernel<<<egrid, 256, 0, stream>>>(edge_src, edge_dst, outdeg, indeg, E);
    norm_kernel<<<ngrid, 256, 0, stream>>>(outdeg, indeg, ns, nd, N);
    scan1_kernel<<<sgrid, 256, 0, stream>>>(indeg, bsum, N);
    scan3_kernel<<<sgrid, 256, 0, stream>>>(indeg, bsum, row_ptr, sgrid, N);
    fill_kernel<<<egrid, 256, 0, stream>>>(edge_src, edge_dst, cursor, ssrc, E);

    // layer 0: feat -> B -> A, bn+relu
    gemm_kernel<128, 128><<<ggrid, 256, 0, stream>>>(feat, W0, ns, B, N);
    agg128_kernel<<<agrid, 256, 0, stream>>>(B, row_ptr, ssrc, nd, A, N);
    bn_reduce_kernel<<<512, 256, 0, stream>>>(A, stats0, N);
    bn_finalize_kernel<<<1, 128, 0, stream>>>(stats0, g0, beta0, ab0, 1.0f / N);
    bn_apply_kernel<<<(N * 32 + 255) / 256, 256, 0, stream>>>(A, ab0, (size_t)N * 32);

    // layer 1: A -> B -> A, bn+relu
    gemm_kernel<128, 128><<<ggrid, 256, 0, stream>>>(A, W1, ns, B, N);
    agg128_kernel<<<agrid, 256, 0, stream>>>(B, row_ptr, ssrc, nd, A, N);
    bn_reduce_kernel<<<512, 256, 0, stream>>>(A, stats1, N);
    bn_finalize_kernel<<<1, 128, 0, stream>>>(stats1, g1, beta1, ab1, 1.0f / N);
    bn_apply_kernel<<<(N * 32 + 255) / 256, 256, 0, stream>>>(A, ab1, (size_t)N * 32);

    // layer 2: A -> B (stride 64, cols 40..63 zero) -> out (+bias)
    gemm_kernel<64, 40><<<ggrid, 256, 0, stream>>>(A, W2, ns, B, N);
    agg_final_kernel<<<agrid, 256, 0, stream>>>(B, row_ptr, ssrc, nd, b2, out, N);
}

// Round 4
// 971.138 us; speedup vs baseline: 1.2765x; 1.0488x over previous
//
#include <hip/hip_runtime.h>
#include <hip/hip_bf16.h>

// 3-layer GCN, fp32.
// R4: (1) layer-2 reordered: aggregate-then-project (agg commutes with W2),
//     deleting agg_final_kernel (148us latency-bound, 16 serial gathers/node);
//     layer-2's ns folded into layer-1 bn_apply epilogue.
// (2) agg128 unrolled to 8 edges in flight (+2x tail) to cut dependent-latency
//     steps per node from 8 to ~2.

#define D_H 128
#define SCAN_CHUNK 1024  // per block: 256 threads x 4 ints

// ---------------- degree / norms ----------------

__global__ void deg_kernel(const int* __restrict__ src, const int* __restrict__ dst,
                           int* __restrict__ outdeg, int* __restrict__ indeg, int E) {
    int e = blockIdx.x * 256 + threadIdx.x;
    if (e < E) {
        atomicAdd(&outdeg[src[e]], 1);
        atomicAdd(&indeg[dst[e]], 1);
    }
}

__global__ void norm_kernel(const int* __restrict__ outdeg, const int* __restrict__ indeg,
                            float* __restrict__ ns, float* __restrict__ nd, int n) {
    int i = blockIdx.x * 256 + threadIdx.x;
    if (i < n) {
        ns[i] = rsqrtf((float)max(outdeg[i], 1));
        nd[i] = rsqrtf((float)max(indeg[i], 1));
    }
}

// ---------------- CSR scan: indeg -> row_ptr, cursor (cursor aliases indeg) --

__global__ __launch_bounds__(256) void scan1_kernel(const int* __restrict__ deg,
                                                    int* __restrict__ bsum, int n) {
    int tid = threadIdx.x;
    int base = blockIdx.x * SCAN_CHUNK + tid * 4;
    int4 v = make_int4(0, 0, 0, 0);
    if (base + 3 < n) {
        v = *(const int4*)(deg + base);
    } else {
        if (base + 0 < n) v.x = deg[base + 0];
        if (base + 1 < n) v.y = deg[base + 1];
        if (base + 2 < n) v.z = deg[base + 2];
        if (base + 3 < n) v.w = deg[base + 3];
    }
    int s = v.x + v.y + v.z + v.w;
    __shared__ int red[256];
    red[tid] = s;
    __syncthreads();
#pragma unroll
    for (int off = 128; off > 0; off >>= 1) {
        if (tid < off) red[tid] += red[tid + off];
        __syncthreads();
    }
    if (tid == 0) bsum[blockIdx.x] = red[0];
}

// each block: scan bsum[0..g) in LDS for its own base, local scan of its
// chunk, write row_ptr + cursor (degcur is both deg input and cursor output).
__global__ __launch_bounds__(256) void scan3_kernel(int* degcur,
                                                    const int* __restrict__ bsum,
                                                    int* __restrict__ row_ptr,
                                                    int g, int n) {
    int tid = threadIdx.x;
    int base = blockIdx.x * SCAN_CHUNK + tid * 4;
    int4 v = make_int4(0, 0, 0, 0);
    if (base + 3 < n) {
        v = *(const int4*)(degcur + base);
    } else {
        if (base + 0 < n) v.x = degcur[base + 0];
        if (base + 1 < n) v.y = degcur[base + 1];
        if (base + 2 < n) v.z = degcur[base + 2];
        if (base + 3 < n) v.w = degcur[base + 3];
    }
    int s = v.x + v.y + v.z + v.w;

    __shared__ int bs[128];
    if (tid < 128) bs[tid] = (tid < g) ? bsum[tid] : 0;
    __syncthreads();
#pragma unroll
    for (int off = 1; off < 128; off <<= 1) {
        int t = (tid < 128 && tid >= off) ? bs[tid - off] : 0;
        __syncthreads();
        if (tid < 128) bs[tid] += t;
        __syncthreads();
    }
    int blockbase = (blockIdx.x == 0) ? 0 : bs[blockIdx.x - 1];
    int total = bs[g - 1];

    __shared__ int sc[256];
    sc[tid] = s;
    __syncthreads();
#pragma unroll
    for (int off = 1; off < 256; off <<= 1) {
        int t = (tid >= off) ? sc[tid - off] : 0;
        __syncthreads();
        sc[tid] += t;
        __syncthreads();
    }
    int excl = sc[tid] - s + blockbase;
    int p0 = excl;
    int p1 = p0 + v.x;
    int p2 = p1 + v.y;
    int p3 = p2 + v.z;
    if (base + 3 < n) {
        *(int4*)(row_ptr + base) = make_int4(p0, p1, p2, p3);
        *(int4*)(degcur + base) = make_int4(p0, p1, p2, p3);  // cursor
    } else {
        if (base + 0 < n) { row_ptr[base + 0] = p0; degcur[base + 0] = p0; }
        if (base + 1 < n) { row_ptr[base + 1] = p1; degcur[base + 1] = p1; }
        if (base + 2 < n) { row_ptr[base + 2] = p2; degcur[base + 2] = p2; }
    }
    if (blockIdx.x == g - 1 && tid == 0) row_ptr[n] = total;
}

__global__ void fill_kernel(const int* __restrict__ src, const int* __restrict__ dst,
                            int* __restrict__ cursor, int* __restrict__ ssrc, int E) {
    int e = blockIdx.x * 256 + threadIdx.x;
    if (e < E) {
        int p = atomicAdd(&cursor[dst[e]], 1);
        ssrc[p] = src[e];
    }
}

// ---------------- GEMM (layers 0/1): Y = (X*ns) @ W, 128x128 ----------------
__global__ __launch_bounds__(256) void gemm_kernel(
    const float* __restrict__ X, const float* __restrict__ W,
    const float* __restrict__ ns, float* __restrict__ Y, int nrows) {
    constexpr int BM = 128, BK = 32, BN = 128, TM = 8, TN = 8;
    __shared__ float As[BK][BM + 4];
    __shared__ float Bs[BK][BN + 4];
    int tid = threadIdx.x;
    int tc = tid & 15, tr = tid >> 4;
    int row0 = blockIdx.x * BM;
    float acc[TM][TN] = {};

    for (int kc = 0; kc < D_H; kc += BK) {
        for (int i = tid; i < BM * BK / 4; i += 256) {
            int r = i >> 3;
            int k4 = (i & 7) << 2;
            int row = row0 + r;
            float4 v = make_float4(0.f, 0.f, 0.f, 0.f);
            float sc = 0.f;
            if (row < nrows) {
                v = *(const float4*)(X + (size_t)row * D_H + kc + k4);
                sc = ns[row];
            }
            As[k4 + 0][r] = v.x * sc;
            As[k4 + 1][r] = v.y * sc;
            As[k4 + 2][r] = v.z * sc;
            As[k4 + 3][r] = v.w * sc;
        }
        for (int i = tid; i < BK * BN / 4; i += 256) {
            int k = i >> 5;
            int c = (i & 31) << 2;
            *(float4*)&Bs[k][c] = *(const float4*)(W + (size_t)(kc + k) * BN + c);
        }
        __syncthreads();
#pragma unroll
        for (int k = 0; k < BK; ++k) {
            float a[TM], b[TN];
            *(float4*)&a[0] = *(const float4*)&As[k][tr * TM];
            *(float4*)&a[4] = *(const float4*)&As[k][tr * TM + 4];
            *(float4*)&b[0] = *(const float4*)&Bs[k][tc * TN];
            *(float4*)&b[4] = *(const float4*)&Bs[k][tc * TN + 4];
#pragma unroll
            for (int m = 0; m < TM; ++m)
#pragma unroll
                for (int n = 0; n < TN; ++n)
                    acc[m][n] = fmaf(a[m], b[n], acc[m][n]);
        }
        __syncthreads();
    }
#pragma unroll
    for (int m = 0; m < TM; ++m) {
        int row = row0 + tr * TM + m;
        if (row < nrows) {
#pragma unroll
            for (int j = 0; j < TN; j += 4)
                *(float4*)(Y + (size_t)row * BN + tc * TN + j) = *(float4*)&acc[m][j];
        }
    }
}

// ---------------- final GEMM: out = X @ W2 + b2, 128->40, out stride 40 -----
__global__ __launch_bounds__(256) void gemm_final_kernel(
    const float* __restrict__ X, const float* __restrict__ W,
    const float* __restrict__ bias, float* __restrict__ Y, int nrows) {
    constexpr int BM = 128, BK = 32, BN = 64, WCOLS = 40, TM = 8, TN = 4;
    __shared__ float As[BK][BM + 4];
    __shared__ float Bs[BK][BN + 4];
    int tid = threadIdx.x;
    int tc = tid & 15, tr = tid >> 4;
    int row0 = blockIdx.x * BM;
    float acc[TM][TN] = {};

    for (int kc = 0; kc < D_H; kc += BK) {
        for (int i = tid; i < BM * BK / 4; i += 256) {
            int r = i >> 3;
            int k4 = (i & 7) << 2;
            int row = row0 + r;
            float4 v = make_float4(0.f, 0.f, 0.f, 0.f);
            if (row < nrows) v = *(const float4*)(X + (size_t)row * D_H + kc + k4);
            As[k4 + 0][r] = v.x;
            As[k4 + 1][r] = v.y;
            As[k4 + 2][r] = v.z;
            As[k4 + 3][r] = v.w;
        }
        for (int i = tid; i < BK * BN; i += 256) {
            int k = i >> 6, c = i & 63;
            Bs[k][c] = (c < WCOLS) ? W[(size_t)(kc + k) * WCOLS + c] : 0.f;
        }
        __syncthreads();
#pragma unroll
        for (int k = 0; k < BK; ++k) {
            float a[TM], b[TN];
            *(float4*)&a[0] = *(const float4*)&As[k][tr * TM];
            *(float4*)&a[4] = *(const float4*)&As[k][tr * TM + 4];
            *(float4*)&b[0] = *(const float4*)&Bs[k][tc * TN];
#pragma unroll
            for (int m = 0; m < TM; ++m)
#pragma unroll
                for (int n = 0; n < TN; ++n)
                    acc[m][n] = fmaf(a[m], b[n], acc[m][n]);
        }
        __syncthreads();
    }
    int col = tc * TN;
    if (col < WCOLS) {
        float4 bb = *(const float4*)&bias[col];
#pragma unroll
        for (int m = 0; m < TM; ++m) {
            int row = row0 + tr * TM + m;
            if (row < nrows) {
                float4 v = *(float4*)&acc[m][0];
                v.x += bb.x; v.y += bb.y; v.z += bb.z; v.w += bb.w;
                *(float4*)(Y + (size_t)row * WCOLS + col) = v;
            }
        }
    }
}

// ---------------- CSR aggregation: out[v] = nd[v] * sum_{e:dst=v} xw[src_e] --
// one wave per node; lane handles 2 floats; 8 edges in flight.
__global__ __launch_bounds__(256) void agg128_kernel(
    const float* __restrict__ xw, const int* __restrict__ row_ptr,
    const int* __restrict__ ssrc, const float* __restrict__ nd,
    float* __restrict__ out, int n) {
    int node = blockIdx.x * 4 + (threadIdx.x >> 6);
    if (node >= n) return;
    int lane = threadIdx.x & 63;
    int beg = row_ptr[node], end = row_ptr[node + 1];
    float x = 0.f, y = 0.f;
    int e = beg;
    for (; e + 8 <= end; e += 8) {
        int s[8];
#pragma unroll
        for (int j = 0; j < 8; ++j) s[j] = ssrc[e + j];
        float2 v[8];
#pragma unroll
        for (int j = 0; j < 8; ++j)
            v[j] = *(const float2*)(xw + (size_t)s[j] * D_H + lane * 2);
#pragma unroll
        for (int j = 0; j < 8; ++j) { x += v[j].x; y += v[j].y; }
    }
    for (; e + 2 <= end; e += 2) {
        int s0 = ssrc[e], s1 = ssrc[e + 1];
        float2 v0 = *(const float2*)(xw + (size_t)s0 * D_H + lane * 2);
        float2 v1 = *(const float2*)(xw + (size_t)s1 * D_H + lane * 2);
        x += v0.x + v1.x;
        y += v0.y + v1.y;
    }
    if (e < end) {
        float2 v0 = *(const float2*)(xw + (size_t)ssrc[e] * D_H + lane * 2);
        x += v0.x;
        y += v0.y;
    }
    float s = nd[node];
    *(float2*)(out + (size_t)node * D_H + lane * 2) = make_float2(x * s, y * s);
}

// ---------------- batchnorm ----------------

__global__ __launch_bounds__(256) void bn_reduce_kernel(const float* __restrict__ x,
                                                        float* __restrict__ stats, int n) {
    int tid = threadIdx.x;
    int col = tid & 127, half = tid >> 7;
    float s = 0.f, s2 = 0.f;
    for (int r = blockIdx.x * 2 + half; r < n; r += gridDim.x * 2) {
        float v = x[(size_t)r * D_H + col];
        s += v;
        s2 = fmaf(v, v, s2);
    }
    __shared__ float red[256];
    red[tid] = s;
    __syncthreads();
    if (half == 0) atomicAdd(&stats[col], s + red[tid + 128]);
    __syncthreads();
    red[tid] = s2;
    __syncthreads();
    if (half == 0) atomicAdd(&stats[128 + col], s2 + red[tid + 128]);
}

__global__ void bn_finalize_kernel(const float* __restrict__ stats,
                                   const float* __restrict__ g,
                                   const float* __restrict__ beta,
                                   float* __restrict__ ab, float inv_n) {
    int c = threadIdx.x;  // 128 threads
    float mean = stats[c] * inv_n;
    float var = stats[128 + c] * inv_n - mean * mean;
    float a = rsqrtf(var + 1e-5f) * g[c];
    ab[c] = a;
    ab[128 + c] = beta[c] - mean * a;
}

// y = relu(x*a + b) [* ns[row] if USE_NS], in place; one float4 per thread
template <bool USE_NS>
__global__ __launch_bounds__(256) void bn_apply_kernel(float* __restrict__ x,
                                                       const float* __restrict__ ab,
                                                       const float* __restrict__ ns,
                                                       size_t total4) {
    size_t i = (size_t)blockIdx.x * 256 + threadIdx.x;
    if (i >= total4) return;
    float4 v = ((float4*)x)[i];
    int c = (int)(i & 31) * 4;  // 32 float4 per 128-wide row
    const float4 a = *(const float4*)&ab[c];
    const float4 b = *(const float4*)&ab[128 + c];
    v.x = fmaxf(fmaf(v.x, a.x, b.x), 0.f);
    v.y = fmaxf(fmaf(v.y, a.y, b.y), 0.f);
    v.z = fmaxf(fmaf(v.z, a.z, b.z), 0.f);
    v.w = fmaxf(fmaf(v.w, a.w, b.w), 0.f);
    if (USE_NS) {
        float sc = ns[i >> 5];
        v.x *= sc; v.y *= sc; v.z *= sc; v.w *= sc;
    }
    ((float4*)x)[i] = v;
}

// ---------------- launch ----------------

extern "C" void kernel_launch(void* const* d_in, const int* in_sizes, int n_in,
                              void* d_out, int out_size, void* d_ws, size_t ws_size,
                              hipStream_t stream) {
    const float* feat = (const float*)d_in[0];
    const int* edge_src = (const int*)d_in[1];
    const int* edge_dst = (const int*)d_in[2];
    const float* W0 = (const float*)d_in[3];
    const float* W1 = (const float*)d_in[4];
    const float* W2 = (const float*)d_in[5];
    const float* b2 = (const float*)d_in[6];
    const float* g0 = (const float*)d_in[7];
    const float* beta0 = (const float*)d_in[8];
    const float* g1 = (const float*)d_in[9];
    const float* beta1 = (const float*)d_in[10];
    float* out = (float*)d_out;

    const int N = in_sizes[0] / D_H;  // 100000
    const int E = in_sizes[1];        // 1600000

    // workspace carve-up (same footprint as R3-proven layout)
    char* p = (char*)d_ws;
    auto alloc = [&](size_t bytes) {
        char* r = p;
        p += (bytes + 255) & ~(size_t)255;
        return r;
    };
    float* A = (float*)alloc((size_t)N * D_H * 4);
    float* B = (float*)alloc((size_t)N * D_H * 4);
    float* ns = (float*)alloc((size_t)N * 4);
    float* nd = (float*)alloc((size_t)N * 4);
    int* outdeg = (int*)alloc((size_t)N * 4);
    int* indeg = (int*)alloc((size_t)N * 4);  // becomes cursor after scan3
    int* row_ptr = (int*)alloc((size_t)(N + 1) * 4);
    int* ssrc = (int*)alloc((size_t)E * 4);
    int* bsum = (int*)alloc(256 * 4);
    float* stats0 = (float*)alloc(256 * 4);
    float* stats1 = (float*)alloc(256 * 4);
    float* ab0 = (float*)alloc(256 * 4);
    float* ab1 = (float*)alloc(256 * 4);
    int* cursor = indeg;
    (void)ws_size;

    hipMemsetAsync(outdeg, 0, (size_t)N * 4, stream);
    hipMemsetAsync(indeg, 0, (size_t)N * 4, stream);
    hipMemsetAsync(stats0, 0, 256 * 4, stream);
    hipMemsetAsync(stats1, 0, 256 * 4, stream);

    const int egrid = (E + 255) / 256;
    const int ngrid = (N + 255) / 256;
    const int ggrid = (N + 127) / 128;
    const int agrid = (N + 3) / 4;
    const int sgrid = (N + SCAN_CHUNK - 1) / SCAN_CHUNK;

    deg_kernel<<<egrid, 256, 0, stream>>>(edge_src, edge_dst, outdeg, indeg, E);
    norm_kernel<<<ngrid, 256, 0, stream>>>(outdeg, indeg, ns, nd, N);
    scan1_kernel<<<sgrid, 256, 0, stream>>>(indeg, bsum, N);
    scan3_kernel<<<sgrid, 256, 0, stream>>>(indeg, bsum, row_ptr, sgrid, N);
    fill_kernel<<<egrid, 256, 0, stream>>>(edge_src, edge_dst, cursor, ssrc, E);

    // layer 0: feat -> B -> A, bn+relu
    gemm_kernel<<<ggrid, 256, 0, stream>>>(feat, W0, ns, B, N);
    agg128_kernel<<<agrid, 256, 0, stream>>>(B, row_ptr, ssrc, nd, A, N);
    bn_reduce_kernel<<<512, 256, 0, stream>>>(A, stats0, N);
    bn_finalize_kernel<<<1, 128, 0, stream>>>(stats0, g0, beta0, ab0, 1.0f / N);
    bn_apply_kernel<false><<<(N * 32 + 255) / 256, 256, 0, stream>>>(
        A, ab0, nullptr, (size_t)N * 32);

    // layer 1: A -> B -> A, bn+relu, fold layer-2 ns into epilogue
    gemm_kernel<<<ggrid, 256, 0, stream>>>(A, W1, ns, B, N);
    agg128_kernel<<<agrid, 256, 0, stream>>>(B, row_ptr, ssrc, nd, A, N);
    bn_reduce_kernel<<<512, 256, 0, stream>>>(A, stats1, N);
    bn_finalize_kernel<<<1, 128, 0, stream>>>(stats1, g1, beta1, ab1, 1.0f / N);
    bn_apply_kernel<true><<<(N * 32 + 255) / 256, 256, 0, stream>>>(
        A, ab1, ns, (size_t)N * 32);

    // layer 2 (reordered): aggregate (A holds h1*ns) -> B, then B @ W2 + b2
    agg128_kernel<<<agrid, 256, 0, stream>>>(A, row_ptr, ssrc, nd, B, N);
    gemm_final_kernel<<<ggrid, 256, 0, stream>>>(B, W2, b2, out, N);
}

// Round 5
// 892.441 us; speedup vs baseline: 1.3890x; 1.0882x over previous
//
#include <hip/hip_runtime.h>
#include <hip/hip_bf16.h>

// 3-layer GCN, fp32.
// R5: (1) fill_kernel de-atomicized: deg_kernel's indeg atomicAdd already
//     returns each edge's within-row rank -> store it (coalesced); fill becomes
//     ssrc[row_ptr[dst]+rank]=src with x4 ILP, no RMW chain. cursor deleted.
// (2) bn_apply(layer0) fused into layer-1 gemm A-staging; bn_apply+ns(layer1)
//     fused into layer-2 aggregation gather. Two 51MB passes deleted.

#define D_H 128
#define SCAN_CHUNK 1024  // per block: 256 threads x 4 ints

// ---------------- degree / rank / norms ----------------

// x4 unrolled; captures per-edge rank (old indeg value) for atomic-free fill
__global__ __launch_bounds__(256) void deg_kernel(
    const int* __restrict__ src, const int* __restrict__ dst,
    int* __restrict__ outdeg, int* __restrict__ indeg,
    int* __restrict__ rank, int E) {
    int e0 = (blockIdx.x * 256 + threadIdx.x) * 4;
    if (e0 + 3 < E) {
        int4 s = *(const int4*)(src + e0);
        int4 d = *(const int4*)(dst + e0);
        atomicAdd(&outdeg[s.x], 1);
        atomicAdd(&outdeg[s.y], 1);
        atomicAdd(&outdeg[s.z], 1);
        atomicAdd(&outdeg[s.w], 1);
        int4 r;
        r.x = atomicAdd(&indeg[d.x], 1);
        r.y = atomicAdd(&indeg[d.y], 1);
        r.z = atomicAdd(&indeg[d.z], 1);
        r.w = atomicAdd(&indeg[d.w], 1);
        *(int4*)(rank + e0) = r;
    } else {
        for (int e = e0; e < E; ++e) {
            atomicAdd(&outdeg[src[e]], 1);
            rank[e] = atomicAdd(&indeg[dst[e]], 1);
        }
    }
}

__global__ void norm_kernel(const int* __restrict__ outdeg, const int* __restrict__ indeg,
                            float* __restrict__ ns, float* __restrict__ nd, int n) {
    int i = blockIdx.x * 256 + threadIdx.x;
    if (i < n) {
        ns[i] = rsqrtf((float)max(outdeg[i], 1));
        nd[i] = rsqrtf((float)max(indeg[i], 1));
    }
}

// ---------------- CSR scan: indeg -> row_ptr ----------------

__global__ __launch_bounds__(256) void scan1_kernel(const int* __restrict__ deg,
                                                    int* __restrict__ bsum, int n) {
    int tid = threadIdx.x;
    int base = blockIdx.x * SCAN_CHUNK + tid * 4;
    int4 v = make_int4(0, 0, 0, 0);
    if (base + 3 < n) {
        v = *(const int4*)(deg + base);
    } else {
        if (base + 0 < n) v.x = deg[base + 0];
        if (base + 1 < n) v.y = deg[base + 1];
        if (base + 2 < n) v.z = deg[base + 2];
        if (base + 3 < n) v.w = deg[base + 3];
    }
    int s = v.x + v.y + v.z + v.w;
    __shared__ int red[256];
    red[tid] = s;
    __syncthreads();
#pragma unroll
    for (int off = 128; off > 0; off >>= 1) {
        if (tid < off) red[tid] += red[tid + off];
        __syncthreads();
    }
    if (tid == 0) bsum[blockIdx.x] = red[0];
}

// each block: scan bsum[0..g) in LDS for its own base, local scan, write row_ptr
__global__ __launch_bounds__(256) void scan3_kernel(const int* __restrict__ deg,
                                                    const int* __restrict__ bsum,
                                                    int* __restrict__ row_ptr,
                                                    int g, int n) {
    int tid = threadIdx.x;
    int base = blockIdx.x * SCAN_CHUNK + tid * 4;
    int4 v = make_int4(0, 0, 0, 0);
    if (base + 3 < n) {
        v = *(const int4*)(deg + base);
    } else {
        if (base + 0 < n) v.x = deg[base + 0];
        if (base + 1 < n) v.y = deg[base + 1];
        if (base + 2 < n) v.z = deg[base + 2];
        if (base + 3 < n) v.w = deg[base + 3];
    }
    int s = v.x + v.y + v.z + v.w;

    __shared__ int bs[128];
    if (tid < 128) bs[tid] = (tid < g) ? bsum[tid] : 0;
    __syncthreads();
#pragma unroll
    for (int off = 1; off < 128; off <<= 1) {
        int t = (tid < 128 && tid >= off) ? bs[tid - off] : 0;
        __syncthreads();
        if (tid < 128) bs[tid] += t;
        __syncthreads();
    }
    int blockbase = (blockIdx.x == 0) ? 0 : bs[blockIdx.x - 1];
    int total = bs[g - 1];

    __shared__ int sc[256];
    sc[tid] = s;
    __syncthreads();
#pragma unroll
    for (int off = 1; off < 256; off <<= 1) {
        int t = (tid >= off) ? sc[tid - off] : 0;
        __syncthreads();
        sc[tid] += t;
        __syncthreads();
    }
    int excl = sc[tid] - s + blockbase;
    int p0 = excl;
    int p1 = p0 + v.x;
    int p2 = p1 + v.y;
    int p3 = p2 + v.z;
    if (base + 3 < n) {
        *(int4*)(row_ptr + base) = make_int4(p0, p1, p2, p3);
    } else {
        if (base + 0 < n) row_ptr[base + 0] = p0;
        if (base + 1 < n) row_ptr[base + 1] = p1;
        if (base + 2 < n) row_ptr[base + 2] = p2;
    }
    if (blockIdx.x == g - 1 && tid == 0) row_ptr[n] = total;
}

// atomic-free scatter: ssrc[row_ptr[dst]+rank] = src, x4 ILP
__global__ __launch_bounds__(256) void fill_kernel(
    const int* __restrict__ src, const int* __restrict__ dst,
    const int* __restrict__ rank, const int* __restrict__ row_ptr,
    int* __restrict__ ssrc, int E) {
    int e0 = (blockIdx.x * 256 + threadIdx.x) * 4;
    if (e0 + 3 < E) {
        int4 s = *(const int4*)(src + e0);
        int4 d = *(const int4*)(dst + e0);
        int4 r = *(const int4*)(rank + e0);
        int p0 = row_ptr[d.x] + r.x;
        int p1 = row_ptr[d.y] + r.y;
        int p2 = row_ptr[d.z] + r.z;
        int p3 = row_ptr[d.w] + r.w;
        ssrc[p0] = s.x;
        ssrc[p1] = s.y;
        ssrc[p2] = s.z;
        ssrc[p3] = s.w;
    } else {
        for (int e = e0; e < E; ++e) ssrc[row_ptr[dst[e]] + rank[e]] = src[e];
    }
}

// ---------------- GEMM (layers 0/1): Y = (act(X)*ns) @ W, 128x128 ----------
// FUSE_BN: act(x) = relu(ab[k]*x + ab[128+k]) applied during A-staging.
template <bool FUSE_BN>
__global__ __launch_bounds__(256) void gemm_kernel(
    const float* __restrict__ X, const float* __restrict__ W,
    const float* __restrict__ ns, const float* __restrict__ ab,
    float* __restrict__ Y, int nrows) {
    constexpr int BM = 128, BK = 32, BN = 128, TM = 8, TN = 8;
    __shared__ float As[BK][BM + 4];
    __shared__ float Bs[BK][BN + 4];
    int tid = threadIdx.x;
    int tc = tid & 15, tr = tid >> 4;
    int row0 = blockIdx.x * BM;
    float acc[TM][TN] = {};

    for (int kc = 0; kc < D_H; kc += BK) {
        for (int i = tid; i < BM * BK / 4; i += 256) {
            int r = i >> 3;
            int k4 = (i & 7) << 2;
            int row = row0 + r;
            float4 v = make_float4(0.f, 0.f, 0.f, 0.f);
            float sc = 0.f;
            if (row < nrows) {
                v = *(const float4*)(X + (size_t)row * D_H + kc + k4);
                sc = ns[row];
            }
            if (FUSE_BN) {
                float4 a4 = *(const float4*)&ab[kc + k4];
                float4 b4 = *(const float4*)&ab[128 + kc + k4];
                v.x = fmaxf(fmaf(v.x, a4.x, b4.x), 0.f);
                v.y = fmaxf(fmaf(v.y, a4.y, b4.y), 0.f);
                v.z = fmaxf(fmaf(v.z, a4.z, b4.z), 0.f);
                v.w = fmaxf(fmaf(v.w, a4.w, b4.w), 0.f);
            }
            As[k4 + 0][r] = v.x * sc;
            As[k4 + 1][r] = v.y * sc;
            As[k4 + 2][r] = v.z * sc;
            As[k4 + 3][r] = v.w * sc;
        }
        for (int i = tid; i < BK * BN / 4; i += 256) {
            int k = i >> 5;
            int c = (i & 31) << 2;
            *(float4*)&Bs[k][c] = *(const float4*)(W + (size_t)(kc + k) * BN + c);
        }
        __syncthreads();
#pragma unroll
        for (int k = 0; k < BK; ++k) {
            float a[TM], b[TN];
            *(float4*)&a[0] = *(const float4*)&As[k][tr * TM];
            *(float4*)&a[4] = *(const float4*)&As[k][tr * TM + 4];
            *(float4*)&b[0] = *(const float4*)&Bs[k][tc * TN];
            *(float4*)&b[4] = *(const float4*)&Bs[k][tc * TN + 4];
#pragma unroll
            for (int m = 0; m < TM; ++m)
#pragma unroll
                for (int n = 0; n < TN; ++n)
                    acc[m][n] = fmaf(a[m], b[n], acc[m][n]);
        }
        __syncthreads();
    }
#pragma unroll
    for (int m = 0; m < TM; ++m) {
        int row = row0 + tr * TM + m;
        if (row < nrows) {
#pragma unroll
            for (int j = 0; j < TN; j += 4)
                *(float4*)(Y + (size_t)row * BN + tc * TN + j) = *(float4*)&acc[m][j];
        }
    }
}

// ---------------- final GEMM: out = X @ W2 + b2, 128->40, out stride 40 -----
__global__ __launch_bounds__(256) void gemm_final_kernel(
    const float* __restrict__ X, const float* __restrict__ W,
    const float* __restrict__ bias, float* __restrict__ Y, int nrows) {
    constexpr int BM = 128, BK = 32, BN = 64, WCOLS = 40, TM = 8, TN = 4;
    __shared__ float As[BK][BM + 4];
    __shared__ float Bs[BK][BN + 4];
    int tid = threadIdx.x;
    int tc = tid & 15, tr = tid >> 4;
    int row0 = blockIdx.x * BM;
    float acc[TM][TN] = {};

    for (int kc = 0; kc < D_H; kc += BK) {
        for (int i = tid; i < BM * BK / 4; i += 256) {
            int r = i >> 3;
            int k4 = (i & 7) << 2;
            int row = row0 + r;
            float4 v = make_float4(0.f, 0.f, 0.f, 0.f);
            if (row < nrows) v = *(const float4*)(X + (size_t)row * D_H + kc + k4);
            As[k4 + 0][r] = v.x;
            As[k4 + 1][r] = v.y;
            As[k4 + 2][r] = v.z;
            As[k4 + 3][r] = v.w;
        }
        for (int i = tid; i < BK * BN; i += 256) {
            int k = i >> 6, c = i & 63;
            Bs[k][c] = (c < WCOLS) ? W[(size_t)(kc + k) * WCOLS + c] : 0.f;
        }
        __syncthreads();
#pragma unroll
        for (int k = 0; k < BK; ++k) {
            float a[TM], b[TN];
            *(float4*)&a[0] = *(const float4*)&As[k][tr * TM];
            *(float4*)&a[4] = *(const float4*)&As[k][tr * TM + 4];
            *(float4*)&b[0] = *(const float4*)&Bs[k][tc * TN];
#pragma unroll
            for (int m = 0; m < TM; ++m)
#pragma unroll
                for (int n = 0; n < TN; ++n)
                    acc[m][n] = fmaf(a[m], b[n], acc[m][n]);
        }
        __syncthreads();
    }
    int col = tc * TN;
    if (col < WCOLS) {
        float4 bb = *(const float4*)&bias[col];
#pragma unroll
        for (int m = 0; m < TM; ++m) {
            int row = row0 + tr * TM + m;
            if (row < nrows) {
                float4 v = *(float4*)&acc[m][0];
                v.x += bb.x; v.y += bb.y; v.z += bb.z; v.w += bb.w;
                *(float4*)(Y + (size_t)row * WCOLS + col) = v;
            }
        }
    }
}

// ---------------- CSR aggregation: out[v] = nd[v] * sum_{e:dst=v} xw[src_e] --
// one wave per node; lane handles 2 floats; 8 edges in flight.
__global__ __launch_bounds__(256) void agg128_kernel(
    const float* __restrict__ xw, const int* __restrict__ row_ptr,
    const int* __restrict__ ssrc, const float* __restrict__ nd,
    float* __restrict__ out, int n) {
    int node = blockIdx.x * 4 + (threadIdx.x >> 6);
    if (node >= n) return;
    int lane = threadIdx.x & 63;
    int beg = row_ptr[node], end = row_ptr[node + 1];
    float x = 0.f, y = 0.f;
    int e = beg;
    for (; e + 8 <= end; e += 8) {
        int s[8];
#pragma unroll
        for (int j = 0; j < 8; ++j) s[j] = ssrc[e + j];
        float2 v[8];
#pragma unroll
        for (int j = 0; j < 8; ++j)
            v[j] = *(const float2*)(xw + (size_t)s[j] * D_H + lane * 2);
#pragma unroll
        for (int j = 0; j < 8; ++j) { x += v[j].x; y += v[j].y; }
    }
    for (; e + 2 <= end; e += 2) {
        int s0 = ssrc[e], s1 = ssrc[e + 1];
        float2 v0 = *(const float2*)(xw + (size_t)s0 * D_H + lane * 2);
        float2 v1 = *(const float2*)(xw + (size_t)s1 * D_H + lane * 2);
        x += v0.x + v1.x;
        y += v0.y + v1.y;
    }
    if (e < end) {
        float2 v0 = *(const float2*)(xw + (size_t)ssrc[e] * D_H + lane * 2);
        x += v0.x;
        y += v0.y;
    }
    float s = nd[node];
    *(float2*)(out + (size_t)node * D_H + lane * 2) = make_float2(x * s, y * s);
}

// layer-2 variant: gathers raw agg1 output, applies relu(a*x+b)*ns[src] on the
// fly (fused bn_apply + ns), sums, scales by nd[node].
__global__ __launch_bounds__(256) void agg128_bn_kernel(
    const float* __restrict__ xw, const int* __restrict__ row_ptr,
    const int* __restrict__ ssrc, const float* __restrict__ nd,
    const float* __restrict__ ns, const float* __restrict__ ab,
    float* __restrict__ out, int n) {
    int node = blockIdx.x * 4 + (threadIdx.x >> 6);
    if (node >= n) return;
    int lane = threadIdx.x & 63;
    float2 a2 = *(const float2*)&ab[lane * 2];
    float2 b2 = *(const float2*)&ab[128 + lane * 2];
    int beg = row_ptr[node], end = row_ptr[node + 1];
    float x = 0.f, y = 0.f;
    int e = beg;
    for (; e + 8 <= end; e += 8) {
        int s[8];
#pragma unroll
        for (int j = 0; j < 8; ++j) s[j] = ssrc[e + j];
        float2 v[8];
        float sc[8];
#pragma unroll
        for (int j = 0; j < 8; ++j) {
            v[j] = *(const float2*)(xw + (size_t)s[j] * D_H + lane * 2);
            sc[j] = ns[s[j]];
        }
#pragma unroll
        for (int j = 0; j < 8; ++j) {
            x += fmaxf(fmaf(v[j].x, a2.x, b2.x), 0.f) * sc[j];
            y += fmaxf(fmaf(v[j].y, a2.y, b2.y), 0.f) * sc[j];
        }
    }
    for (; e < end; ++e) {
        int s0 = ssrc[e];
        float2 v0 = *(const float2*)(xw + (size_t)s0 * D_H + lane * 2);
        float sc0 = ns[s0];
        x += fmaxf(fmaf(v0.x, a2.x, b2.x), 0.f) * sc0;
        y += fmaxf(fmaf(v0.y, a2.y, b2.y), 0.f) * sc0;
    }
    float s = nd[node];
    *(float2*)(out + (size_t)node * D_H + lane * 2) = make_float2(x * s, y * s);
}

// ---------------- batchnorm stats ----------------

__global__ __launch_bounds__(256) void bn_reduce_kernel(const float* __restrict__ x,
                                                        float* __restrict__ stats, int n) {
    int tid = threadIdx.x;
    int col = tid & 127, half = tid >> 7;
    float s = 0.f, s2 = 0.f;
    for (int r = blockIdx.x * 2 + half; r < n; r += gridDim.x * 2) {
        float v = x[(size_t)r * D_H + col];
        s += v;
        s2 = fmaf(v, v, s2);
    }
    __shared__ float red[256];
    red[tid] = s;
    __syncthreads();
    if (half == 0) atomicAdd(&stats[col], s + red[tid + 128]);
    __syncthreads();
    red[tid] = s2;
    __syncthreads();
    if (half == 0) atomicAdd(&stats[128 + col], s2 + red[tid + 128]);
}

__global__ void bn_finalize_kernel(const float* __restrict__ stats,
                                   const float* __restrict__ g,
                                   const float* __restrict__ beta,
                                   float* __restrict__ ab, float inv_n) {
    int c = threadIdx.x;  // 128 threads
    float mean = stats[c] * inv_n;
    float var = stats[128 + c] * inv_n - mean * mean;
    float a = rsqrtf(var + 1e-5f) * g[c];
    ab[c] = a;
    ab[128 + c] = beta[c] - mean * a;
}

// ---------------- launch ----------------

extern "C" void kernel_launch(void* const* d_in, const int* in_sizes, int n_in,
                              void* d_out, int out_size, void* d_ws, size_t ws_size,
                              hipStream_t stream) {
    const float* feat = (const float*)d_in[0];
    const int* edge_src = (const int*)d_in[1];
    const int* edge_dst = (const int*)d_in[2];
    const float* W0 = (const float*)d_in[3];
    const float* W1 = (const float*)d_in[4];
    const float* W2 = (const float*)d_in[5];
    const float* b2 = (const float*)d_in[6];
    const float* g0 = (const float*)d_in[7];
    const float* beta0 = (const float*)d_in[8];
    const float* g1 = (const float*)d_in[9];
    const float* beta1 = (const float*)d_in[10];
    float* out = (float*)d_out;

    const int N = in_sizes[0] / D_H;  // 100000
    const int E = in_sizes[1];        // 1600000

    char* p = (char*)d_ws;
    auto alloc = [&](size_t bytes) {
        char* r = p;
        p += (bytes + 255) & ~(size_t)255;
        return r;
    };
    float* A = (float*)alloc((size_t)N * D_H * 4);
    float* B = (float*)alloc((size_t)N * D_H * 4);
    float* ns = (float*)alloc((size_t)N * 4);
    float* nd = (float*)alloc((size_t)N * 4);
    int* outdeg = (int*)alloc((size_t)N * 4);
    int* indeg = (int*)alloc((size_t)N * 4);
    int* row_ptr = (int*)alloc((size_t)(N + 1) * 4);
    int* ssrc = (int*)alloc((size_t)E * 4);
    int* rank = (int*)alloc((size_t)E * 4);
    int* bsum = (int*)alloc(256 * 4);
    float* stats0 = (float*)alloc(256 * 4);
    float* stats1 = (float*)alloc(256 * 4);
    float* ab0 = (float*)alloc(256 * 4);
    float* ab1 = (float*)alloc(256 * 4);
    (void)ws_size;

    hipMemsetAsync(outdeg, 0, (size_t)N * 4, stream);
    hipMemsetAsync(indeg, 0, (size_t)N * 4, stream);
    hipMemsetAsync(stats0, 0, 256 * 4, stream);
    hipMemsetAsync(stats1, 0, 256 * 4, stream);

    const int e4grid = (E + 1023) / 1024;  // x4 unrolled edge kernels
    const int ngrid = (N + 255) / 256;
    const int ggrid = (N + 127) / 128;
    const int agrid = (N + 3) / 4;
    const int sgrid = (N + SCAN_CHUNK - 1) / SCAN_CHUNK;

    deg_kernel<<<e4grid, 256, 0, stream>>>(edge_src, edge_dst, outdeg, indeg, rank, E);
    norm_kernel<<<ngrid, 256, 0, stream>>>(outdeg, indeg, ns, nd, N);
    scan1_kernel<<<sgrid, 256, 0, stream>>>(indeg, bsum, N);
    scan3_kernel<<<sgrid, 256, 0, stream>>>(indeg, bsum, row_ptr, sgrid, N);
    fill_kernel<<<e4grid, 256, 0, stream>>>(edge_src, edge_dst, rank, row_ptr, ssrc, E);

    // layer 0: gemm(feat*ns @ W0) -> B; agg -> A; stats
    gemm_kernel<false><<<ggrid, 256, 0, stream>>>(feat, W0, ns, nullptr, B, N);
    agg128_kernel<<<agrid, 256, 0, stream>>>(B, row_ptr, ssrc, nd, A, N);
    bn_reduce_kernel<<<512, 256, 0, stream>>>(A, stats0, N);
    bn_finalize_kernel<<<1, 128, 0, stream>>>(stats0, g0, beta0, ab0, 1.0f / N);

    // layer 1: gemm(relu(bn0(A))*ns @ W1) -> B; agg -> A; stats
    gemm_kernel<true><<<ggrid, 256, 0, stream>>>(A, W1, ns, ab0, B, N);
    agg128_kernel<<<agrid, 256, 0, stream>>>(B, row_ptr, ssrc, nd, A, N);
    bn_reduce_kernel<<<512, 256, 0, stream>>>(A, stats1, N);
    bn_finalize_kernel<<<1, 128, 0, stream>>>(stats1, g1, beta1, ab1, 1.0f / N);

    // layer 2 (reordered): agg(relu(bn1(A))*ns) -> B; gemm_final(B) -> out
    agg128_bn_kernel<<<agrid, 256, 0, stream>>>(A, row_ptr, ssrc, nd, ns, ab1, B, N);
    gemm_final_kernel<<<ggrid, 256, 0, stream>>>(B, W2, b2, out, N);
}

// Round 6
// 784.190 us; speedup vs baseline: 1.5808x; 1.1380x over previous
//
#include <hip/hip_runtime.h>
#include <hip/hip_bf16.h>

// 3-layer GCN. R6: pre-aggregation GEMM output B stored as bf16 (storage only;
// all math fp32). Halves the dominant traffic: 2x 819MB agg gathers -> 410MB,
// 2x 51MB gemm writes -> 25.6MB. A/BN/agg_bn/gemm_final stay fp32 for accuracy.

#define D_H 128
#define SCAN_CHUNK 1024

typedef unsigned int uint32;
typedef unsigned short ushort16;

__device__ __forceinline__ ushort16 f2bf(float f) {
    union { float f; uint32 u; } v;
    v.f = f;
    uint32 u = v.u;
    return (ushort16)((u + 0x7fffu + ((u >> 16) & 1u)) >> 16);  // RNE
}
__device__ __forceinline__ float2 bf2f2(uint32 u) {
    union { uint32 i; float f; } a, b;
    a.i = u << 16;          // low ushort = element 2l
    b.i = u & 0xffff0000u;  // high ushort = element 2l+1
    return make_float2(a.f, b.f);
}

// ---------------- degree / rank / norms ----------------

__global__ __launch_bounds__(256) void deg_kernel(
    const int* __restrict__ src, const int* __restrict__ dst,
    int* __restrict__ outdeg, int* __restrict__ indeg,
    int* __restrict__ rank, int E) {
    int e0 = (blockIdx.x * 256 + threadIdx.x) * 4;
    if (e0 + 3 < E) {
        int4 s = *(const int4*)(src + e0);
        int4 d = *(const int4*)(dst + e0);
        atomicAdd(&outdeg[s.x], 1);
        atomicAdd(&outdeg[s.y], 1);
        atomicAdd(&outdeg[s.z], 1);
        atomicAdd(&outdeg[s.w], 1);
        int4 r;
        r.x = atomicAdd(&indeg[d.x], 1);
        r.y = atomicAdd(&indeg[d.y], 1);
        r.z = atomicAdd(&indeg[d.z], 1);
        r.w = atomicAdd(&indeg[d.w], 1);
        *(int4*)(rank + e0) = r;
    } else {
        for (int e = e0; e < E; ++e) {
            atomicAdd(&outdeg[src[e]], 1);
            rank[e] = atomicAdd(&indeg[dst[e]], 1);
        }
    }
}

__global__ void norm_kernel(const int* __restrict__ outdeg, const int* __restrict__ indeg,
                            float* __restrict__ ns, float* __restrict__ nd, int n) {
    int i = blockIdx.x * 256 + threadIdx.x;
    if (i < n) {
        ns[i] = rsqrtf((float)max(outdeg[i], 1));
        nd[i] = rsqrtf((float)max(indeg[i], 1));
    }
}

// ---------------- CSR scan: indeg -> row_ptr ----------------

__global__ __launch_bounds__(256) void scan1_kernel(const int* __restrict__ deg,
                                                    int* __restrict__ bsum, int n) {
    int tid = threadIdx.x;
    int base = blockIdx.x * SCAN_CHUNK + tid * 4;
    int4 v = make_int4(0, 0, 0, 0);
    if (base + 3 < n) {
        v = *(const int4*)(deg + base);
    } else {
        if (base + 0 < n) v.x = deg[base + 0];
        if (base + 1 < n) v.y = deg[base + 1];
        if (base + 2 < n) v.z = deg[base + 2];
        if (base + 3 < n) v.w = deg[base + 3];
    }
    int s = v.x + v.y + v.z + v.w;
    __shared__ int red[256];
    red[tid] = s;
    __syncthreads();
#pragma unroll
    for (int off = 128; off > 0; off >>= 1) {
        if (tid < off) red[tid] += red[tid + off];
        __syncthreads();
    }
    if (tid == 0) bsum[blockIdx.x] = red[0];
}

__global__ __launch_bounds__(256) void scan3_kernel(const int* __restrict__ deg,
                                                    const int* __restrict__ bsum,
                                                    int* __restrict__ row_ptr,
                                                    int g, int n) {
    int tid = threadIdx.x;
    int base = blockIdx.x * SCAN_CHUNK + tid * 4;
    int4 v = make_int4(0, 0, 0, 0);
    if (base + 3 < n) {
        v = *(const int4*)(deg + base);
    } else {
        if (base + 0 < n) v.x = deg[base + 0];
        if (base + 1 < n) v.y = deg[base + 1];
        if (base + 2 < n) v.z = deg[base + 2];
        if (base + 3 < n) v.w = deg[base + 3];
    }
    int s = v.x + v.y + v.z + v.w;

    __shared__ int bs[128];
    if (tid < 128) bs[tid] = (tid < g) ? bsum[tid] : 0;
    __syncthreads();
#pragma unroll
    for (int off = 1; off < 128; off <<= 1) {
        int t = (tid < 128 && tid >= off) ? bs[tid - off] : 0;
        __syncthreads();
        if (tid < 128) bs[tid] += t;
        __syncthreads();
    }
    int blockbase = (blockIdx.x == 0) ? 0 : bs[blockIdx.x - 1];
    int total = bs[g - 1];

    __shared__ int sc[256];
    sc[tid] = s;
    __syncthreads();
#pragma unroll
    for (int off = 1; off < 256; off <<= 1) {
        int t = (tid >= off) ? sc[tid - off] : 0;
        __syncthreads();
        sc[tid] += t;
        __syncthreads();
    }
    int excl = sc[tid] - s + blockbase;
    int p0 = excl;
    int p1 = p0 + v.x;
    int p2 = p1 + v.y;
    int p3 = p2 + v.z;
    if (base + 3 < n) {
        *(int4*)(row_ptr + base) = make_int4(p0, p1, p2, p3);
    } else {
        if (base + 0 < n) row_ptr[base + 0] = p0;
        if (base + 1 < n) row_ptr[base + 1] = p1;
        if (base + 2 < n) row_ptr[base + 2] = p2;
    }
    if (blockIdx.x == g - 1 && tid == 0) row_ptr[n] = total;
}

__global__ __launch_bounds__(256) void fill_kernel(
    const int* __restrict__ src, const int* __restrict__ dst,
    const int* __restrict__ rank, const int* __restrict__ row_ptr,
    int* __restrict__ ssrc, int E) {
    int e0 = (blockIdx.x * 256 + threadIdx.x) * 4;
    if (e0 + 3 < E) {
        int4 s = *(const int4*)(src + e0);
        int4 d = *(const int4*)(dst + e0);
        int4 r = *(const int4*)(rank + e0);
        int p0 = row_ptr[d.x] + r.x;
        int p1 = row_ptr[d.y] + r.y;
        int p2 = row_ptr[d.z] + r.z;
        int p3 = row_ptr[d.w] + r.w;
        ssrc[p0] = s.x;
        ssrc[p1] = s.y;
        ssrc[p2] = s.z;
        ssrc[p3] = s.w;
    } else {
        for (int e = e0; e < E; ++e) ssrc[row_ptr[dst[e]] + rank[e]] = src[e];
    }
}

// ---------------- GEMM (layers 0/1): Yb = bf16((act(X)*ns) @ W) -------------
// FUSE_BN: act(x) = relu(ab[k]*x + ab[128+k]) applied during A-staging.
template <bool FUSE_BN>
__global__ __launch_bounds__(256) void gemm_kernel(
    const float* __restrict__ X, const float* __restrict__ W,
    const float* __restrict__ ns, const float* __restrict__ ab,
    ushort16* __restrict__ Yb, int nrows) {
    constexpr int BM = 128, BK = 32, BN = 128, TM = 8, TN = 8;
    __shared__ float As[BK][BM + 4];
    __shared__ float Bs[BK][BN + 4];
    int tid = threadIdx.x;
    int tc = tid & 15, tr = tid >> 4;
    int row0 = blockIdx.x * BM;
    float acc[TM][TN] = {};

    for (int kc = 0; kc < D_H; kc += BK) {
        for (int i = tid; i < BM * BK / 4; i += 256) {
            int r = i >> 3;
            int k4 = (i & 7) << 2;
            int row = row0 + r;
            float4 v = make_float4(0.f, 0.f, 0.f, 0.f);
            float sc = 0.f;
            if (row < nrows) {
                v = *(const float4*)(X + (size_t)row * D_H + kc + k4);
                sc = ns[row];
            }
            if (FUSE_BN) {
                float4 a4 = *(const float4*)&ab[kc + k4];
                float4 b4 = *(const float4*)&ab[128 + kc + k4];
                v.x = fmaxf(fmaf(v.x, a4.x, b4.x), 0.f);
                v.y = fmaxf(fmaf(v.y, a4.y, b4.y), 0.f);
                v.z = fmaxf(fmaf(v.z, a4.z, b4.z), 0.f);
                v.w = fmaxf(fmaf(v.w, a4.w, b4.w), 0.f);
            }
            As[k4 + 0][r] = v.x * sc;
            As[k4 + 1][r] = v.y * sc;
            As[k4 + 2][r] = v.z * sc;
            As[k4 + 3][r] = v.w * sc;
        }
        for (int i = tid; i < BK * BN / 4; i += 256) {
            int k = i >> 5;
            int c = (i & 31) << 2;
            *(float4*)&Bs[k][c] = *(const float4*)(W + (size_t)(kc + k) * BN + c);
        }
        __syncthreads();
#pragma unroll
        for (int k = 0; k < BK; ++k) {
            float a[TM], b[TN];
            *(float4*)&a[0] = *(const float4*)&As[k][tr * TM];
            *(float4*)&a[4] = *(const float4*)&As[k][tr * TM + 4];
            *(float4*)&b[0] = *(const float4*)&Bs[k][tc * TN];
            *(float4*)&b[4] = *(const float4*)&Bs[k][tc * TN + 4];
#pragma unroll
            for (int m = 0; m < TM; ++m)
#pragma unroll
                for (int n = 0; n < TN; ++n)
                    acc[m][n] = fmaf(a[m], b[n], acc[m][n]);
        }
        __syncthreads();
    }
#pragma unroll
    for (int m = 0; m < TM; ++m) {
        int row = row0 + tr * TM + m;
        if (row < nrows) {
            ushort16 h[8];
#pragma unroll
            for (int j = 0; j < TN; ++j) h[j] = f2bf(acc[m][j]);
            *(uint4*)(Yb + (size_t)row * BN + tc * TN) = *(uint4*)&h[0];
        }
    }
}

// ---------------- final GEMM: out = X @ W2 + b2, 128->40, fp32 --------------
__global__ __launch_bounds__(256) void gemm_final_kernel(
    const float* __restrict__ X, const float* __restrict__ W,
    const float* __restrict__ bias, float* __restrict__ Y, int nrows) {
    constexpr int BM = 128, BK = 32, BN = 64, WCOLS = 40, TM = 8, TN = 4;
    __shared__ float As[BK][BM + 4];
    __shared__ float Bs[BK][BN + 4];
    int tid = threadIdx.x;
    int tc = tid & 15, tr = tid >> 4;
    int row0 = blockIdx.x * BM;
    float acc[TM][TN] = {};

    for (int kc = 0; kc < D_H; kc += BK) {
        for (int i = tid; i < BM * BK / 4; i += 256) {
            int r = i >> 3;
            int k4 = (i & 7) << 2;
            int row = row0 + r;
            float4 v = make_float4(0.f, 0.f, 0.f, 0.f);
            if (row < nrows) v = *(const float4*)(X + (size_t)row * D_H + kc + k4);
            As[k4 + 0][r] = v.x;
            As[k4 + 1][r] = v.y;
            As[k4 + 2][r] = v.z;
            As[k4 + 3][r] = v.w;
        }
        for (int i = tid; i < BK * BN; i += 256) {
            int k = i >> 6, c = i & 63;
            Bs[k][c] = (c < WCOLS) ? W[(size_t)(kc + k) * WCOLS + c] : 0.f;
        }
        __syncthreads();
#pragma unroll
        for (int k = 0; k < BK; ++k) {
            float a[TM], b[TN];
            *(float4*)&a[0] = *(const float4*)&As[k][tr * TM];
            *(float4*)&a[4] = *(const float4*)&As[k][tr * TM + 4];
            *(float4*)&b[0] = *(const float4*)&Bs[k][tc * TN];
#pragma unroll
            for (int m = 0; m < TM; ++m)
#pragma unroll
                for (int n = 0; n < TN; ++n)
                    acc[m][n] = fmaf(a[m], b[n], acc[m][n]);
        }
        __syncthreads();
    }
    int col = tc * TN;
    if (col < WCOLS) {
        float4 bb = *(const float4*)&bias[col];
#pragma unroll
        for (int m = 0; m < TM; ++m) {
            int row = row0 + tr * TM + m;
            if (row < nrows) {
                float4 v = *(float4*)&acc[m][0];
                v.x += bb.x; v.y += bb.y; v.z += bb.z; v.w += bb.w;
                *(float4*)(Y + (size_t)row * WCOLS + col) = v;
            }
        }
    }
}

// ------- CSR aggregation (bf16 input): A[v] = nd[v]*sum xwb[src_e] ----------
// one wave per node; lane reads one uint (2 bf16) per edge; fp32 accumulate.
__global__ __launch_bounds__(256) void agg128_kernel(
    const ushort16* __restrict__ xwb, const int* __restrict__ row_ptr,
    const int* __restrict__ ssrc, const float* __restrict__ nd,
    float* __restrict__ out, int n) {
    int node = blockIdx.x * 4 + (threadIdx.x >> 6);
    if (node >= n) return;
    int lane = threadIdx.x & 63;
    int beg = row_ptr[node], end = row_ptr[node + 1];
    float x = 0.f, y = 0.f;
    int e = beg;
    for (; e + 8 <= end; e += 8) {
        int s[8];
#pragma unroll
        for (int j = 0; j < 8; ++j) s[j] = ssrc[e + j];
        uint32 u[8];
#pragma unroll
        for (int j = 0; j < 8; ++j)
            u[j] = *(const uint32*)(xwb + (size_t)s[j] * D_H + lane * 2);
#pragma unroll
        for (int j = 0; j < 8; ++j) {
            float2 v = bf2f2(u[j]);
            x += v.x;
            y += v.y;
        }
    }
    for (; e + 2 <= end; e += 2) {
        uint32 u0 = *(const uint32*)(xwb + (size_t)ssrc[e] * D_H + lane * 2);
        uint32 u1 = *(const uint32*)(xwb + (size_t)ssrc[e + 1] * D_H + lane * 2);
        float2 v0 = bf2f2(u0), v1 = bf2f2(u1);
        x += v0.x + v1.x;
        y += v0.y + v1.y;
    }
    if (e < end) {
        float2 v0 = bf2f2(*(const uint32*)(xwb + (size_t)ssrc[e] * D_H + lane * 2));
        x += v0.x;
        y += v0.y;
    }
    float s = nd[node];
    *(float2*)(out + (size_t)node * D_H + lane * 2) = make_float2(x * s, y * s);
}

// layer-2 variant: gathers fp32 A, applies relu(a*x+b)*ns[src] on the fly.
__global__ __launch_bounds__(256) void agg128_bn_kernel(
    const float* __restrict__ xw, const int* __restrict__ row_ptr,
    const int* __restrict__ ssrc, const float* __restrict__ nd,
    const float* __restrict__ ns, const float* __restrict__ ab,
    float* __restrict__ out, int n) {
    int node = blockIdx.x * 4 + (threadIdx.x >> 6);
    if (node >= n) return;
    int lane = threadIdx.x & 63;
    float2 a2 = *(const float2*)&ab[lane * 2];
    float2 b2 = *(const float2*)&ab[128 + lane * 2];
    int beg = row_ptr[node], end = row_ptr[node + 1];
    float x = 0.f, y = 0.f;
    int e = beg;
    for (; e + 8 <= end; e += 8) {
        int s[8];
#pragma unroll
        for (int j = 0; j < 8; ++j) s[j] = ssrc[e + j];
        float2 v[8];
        float sc[8];
#pragma unroll
        for (int j = 0; j < 8; ++j) {
            v[j] = *(const float2*)(xw + (size_t)s[j] * D_H + lane * 2);
            sc[j] = ns[s[j]];
        }
#pragma unroll
        for (int j = 0; j < 8; ++j) {
            x += fmaxf(fmaf(v[j].x, a2.x, b2.x), 0.f) * sc[j];
            y += fmaxf(fmaf(v[j].y, a2.y, b2.y), 0.f) * sc[j];
        }
    }
    for (; e < end; ++e) {
        int s0 = ssrc[e];
        float2 v0 = *(const float2*)(xw + (size_t)s0 * D_H + lane * 2);
        float sc0 = ns[s0];
        x += fmaxf(fmaf(v0.x, a2.x, b2.x), 0.f) * sc0;
        y += fmaxf(fmaf(v0.y, a2.y, b2.y), 0.f) * sc0;
    }
    float s = nd[node];
    *(float2*)(out + (size_t)node * D_H + lane * 2) = make_float2(x * s, y * s);
}

// ---------------- batchnorm stats ----------------

__global__ __launch_bounds__(256) void bn_reduce_kernel(const float* __restrict__ x,
                                                        float* __restrict__ stats, int n) {
    int tid = threadIdx.x;
    int col = tid & 127, half = tid >> 7;
    float s = 0.f, s2 = 0.f;
    for (int r = blockIdx.x * 2 + half; r < n; r += gridDim.x * 2) {
        float v = x[(size_t)r * D_H + col];
        s += v;
        s2 = fmaf(v, v, s2);
    }
    __shared__ float red[256];
    red[tid] = s;
    __syncthreads();
    if (half == 0) atomicAdd(&stats[col], s + red[tid + 128]);
    __syncthreads();
    red[tid] = s2;
    __syncthreads();
    if (half == 0) atomicAdd(&stats[128 + col], s2 + red[tid + 128]);
}

__global__ void bn_finalize_kernel(const float* __restrict__ stats,
                                   const float* __restrict__ g,
                                   const float* __restrict__ beta,
                                   float* __restrict__ ab, float inv_n) {
    int c = threadIdx.x;  // 128 threads
    float mean = stats[c] * inv_n;
    float var = stats[128 + c] * inv_n - mean * mean;
    float a = rsqrtf(var + 1e-5f) * g[c];
    ab[c] = a;
    ab[128 + c] = beta[c] - mean * a;
}

// ---------------- launch ----------------

extern "C" void kernel_launch(void* const* d_in, const int* in_sizes, int n_in,
                              void* d_out, int out_size, void* d_ws, size_t ws_size,
                              hipStream_t stream) {
    const float* feat = (const float*)d_in[0];
    const int* edge_src = (const int*)d_in[1];
    const int* edge_dst = (const int*)d_in[2];
    const float* W0 = (const float*)d_in[3];
    const float* W1 = (const float*)d_in[4];
    const float* W2 = (const float*)d_in[5];
    const float* b2 = (const float*)d_in[6];
    const float* g0 = (const float*)d_in[7];
    const float* beta0 = (const float*)d_in[8];
    const float* g1 = (const float*)d_in[9];
    const float* beta1 = (const float*)d_in[10];
    float* out = (float*)d_out;

    const int N = in_sizes[0] / D_H;  // 100000
    const int E = in_sizes[1];        // 1600000

    char* p = (char*)d_ws;
    auto alloc = [&](size_t bytes) {
        char* r = p;
        p += (bytes + 255) & ~(size_t)255;
        return r;
    };
    float* A = (float*)alloc((size_t)N * D_H * 4);
    float* B = (float*)alloc((size_t)N * D_H * 4);  // used as bf16 by gemm/agg, fp32 by agg_bn
    float* ns = (float*)alloc((size_t)N * 4);
    float* nd = (float*)alloc((size_t)N * 4);
    int* outdeg = (int*)alloc((size_t)N * 4);
    int* indeg = (int*)alloc((size_t)N * 4);
    int* row_ptr = (int*)alloc((size_t)(N + 1) * 4);
    int* ssrc = (int*)alloc((size_t)E * 4);
    int* rank = (int*)alloc((size_t)E * 4);
    int* bsum = (int*)alloc(256 * 4);
    float* stats0 = (float*)alloc(256 * 4);
    float* stats1 = (float*)alloc(256 * 4);
    float* ab0 = (float*)alloc(256 * 4);
    float* ab1 = (float*)alloc(256 * 4);
    ushort16* Bb = (ushort16*)B;
    (void)ws_size;

    hipMemsetAsync(outdeg, 0, (size_t)N * 4, stream);
    hipMemsetAsync(indeg, 0, (size_t)N * 4, stream);
    hipMemsetAsync(stats0, 0, 256 * 4, stream);
    hipMemsetAsync(stats1, 0, 256 * 4, stream);

    const int e4grid = (E + 1023) / 1024;
    const int ngrid = (N + 255) / 256;
    const int ggrid = (N + 127) / 128;
    const int agrid = (N + 3) / 4;
    const int sgrid = (N + SCAN_CHUNK - 1) / SCAN_CHUNK;

    deg_kernel<<<e4grid, 256, 0, stream>>>(edge_src, edge_dst, outdeg, indeg, rank, E);
    norm_kernel<<<ngrid, 256, 0, stream>>>(outdeg, indeg, ns, nd, N);
    scan1_kernel<<<sgrid, 256, 0, stream>>>(indeg, bsum, N);
    scan3_kernel<<<sgrid, 256, 0, stream>>>(indeg, bsum, row_ptr, sgrid, N);
    fill_kernel<<<e4grid, 256, 0, stream>>>(edge_src, edge_dst, rank, row_ptr, ssrc, E);

    // layer 0: gemm(feat*ns @ W0) -> Bb (bf16); agg -> A (fp32); stats
    gemm_kernel<false><<<ggrid, 256, 0, stream>>>(feat, W0, ns, nullptr, Bb, N);
    agg128_kernel<<<agrid, 256, 0, stream>>>(Bb, row_ptr, ssrc, nd, A, N);
    bn_reduce_kernel<<<512, 256, 0, stream>>>(A, stats0, N);
    bn_finalize_kernel<<<1, 128, 0, stream>>>(stats0, g0, beta0, ab0, 1.0f / N);

    // layer 1: gemm(relu(bn0(A))*ns @ W1) -> Bb (bf16); agg -> A; stats
    gemm_kernel<true><<<ggrid, 256, 0, stream>>>(A, W1, ns, ab0, Bb, N);
    agg128_kernel<<<agrid, 256, 0, stream>>>(Bb, row_ptr, ssrc, nd, A, N);
    bn_reduce_kernel<<<512, 256, 0, stream>>>(A, stats1, N);
    bn_finalize_kernel<<<1, 128, 0, stream>>>(stats1, g1, beta1, ab1, 1.0f / N);

    // layer 2 (reordered): agg(relu(bn1(A))*ns) -> B (fp32); gemm_final -> out
    agg128_bn_kernel<<<agrid, 256, 0, stream>>>(A, row_ptr, ssrc, nd, ns, ab1, B, N);
    gemm_final_kernel<<<ggrid, 256, 0, stream>>>(B, W2, b2, out, N);
}

// Round 7
// 661.389 us; speedup vs baseline: 1.8743x; 1.1857x over previous
//
#include <hip/hip_runtime.h>
#include <hip/hip_bf16.h>

// 3-layer GCN. R7: (1) gemm0/gemm1 -> MFMA 16x16x32 bf16 (fp32 acc); W0/W1
// pre-transposed to bf16 Wt[n][k]; A staged bf16 in LDS (stride 72, b128-clean).
// (2) A stored bf16 (agg writes packed bf16; bn_reduce/agg_bn read bf16) ->
// agg_bn gather halves. (3) gemm_final + W2 stay fp32 (output-adjacent path).

#define D_H 128
#define SCAN_CHUNK 1024

typedef unsigned int uint32;
typedef unsigned short ushort16;
typedef __attribute__((ext_vector_type(8))) short short8v;   // 8 bf16 = 4 VGPR
typedef __attribute__((ext_vector_type(4))) float float4v;   // MFMA acc

__device__ __forceinline__ ushort16 f2bf(float f) {
    union { float f; uint32 u; } v;
    v.f = f;
    uint32 u = v.u;
    return (ushort16)((u + 0x7fffu + ((u >> 16) & 1u)) >> 16);  // RNE
}
__device__ __forceinline__ float2 bf2f2(uint32 u) {
    union { uint32 i; float f; } a, b;
    a.i = u << 16;          // low ushort = element 2l
    b.i = u & 0xffff0000u;  // high ushort = element 2l+1
    return make_float2(a.f, b.f);
}
__device__ __forceinline__ float bf2f(ushort16 h) {
    union { uint32 i; float f; } t;
    t.i = ((uint32)h) << 16;
    return t.f;
}

// ---------------- degree / rank / norms ----------------

__global__ __launch_bounds__(256) void deg_kernel(
    const int* __restrict__ src, const int* __restrict__ dst,
    int* __restrict__ outdeg, int* __restrict__ indeg,
    int* __restrict__ rank, int E) {
    int e0 = (blockIdx.x * 256 + threadIdx.x) * 4;
    if (e0 + 3 < E) {
        int4 s = *(const int4*)(src + e0);
        int4 d = *(const int4*)(dst + e0);
        atomicAdd(&outdeg[s.x], 1);
        atomicAdd(&outdeg[s.y], 1);
        atomicAdd(&outdeg[s.z], 1);
        atomicAdd(&outdeg[s.w], 1);
        int4 r;
        r.x = atomicAdd(&indeg[d.x], 1);
        r.y = atomicAdd(&indeg[d.y], 1);
        r.z = atomicAdd(&indeg[d.z], 1);
        r.w = atomicAdd(&indeg[d.w], 1);
        *(int4*)(rank + e0) = r;
    } else {
        for (int e = e0; e < E; ++e) {
            atomicAdd(&outdeg[src[e]], 1);
            rank[e] = atomicAdd(&indeg[dst[e]], 1);
        }
    }
}

__global__ void norm_kernel(const int* __restrict__ outdeg, const int* __restrict__ indeg,
                            float* __restrict__ ns, float* __restrict__ nd, int n) {
    int i = blockIdx.x * 256 + threadIdx.x;
    if (i < n) {
        ns[i] = rsqrtf((float)max(outdeg[i], 1));
        nd[i] = rsqrtf((float)max(indeg[i], 1));
    }
}

// ---------------- CSR scan ----------------

__global__ __launch_bounds__(256) void scan1_kernel(const int* __restrict__ deg,
                                                    int* __restrict__ bsum, int n) {
    int tid = threadIdx.x;
    int base = blockIdx.x * SCAN_CHUNK + tid * 4;
    int4 v = make_int4(0, 0, 0, 0);
    if (base + 3 < n) {
        v = *(const int4*)(deg + base);
    } else {
        if (base + 0 < n) v.x = deg[base + 0];
        if (base + 1 < n) v.y = deg[base + 1];
        if (base + 2 < n) v.z = deg[base + 2];
        if (base + 3 < n) v.w = deg[base + 3];
    }
    int s = v.x + v.y + v.z + v.w;
    __shared__ int red[256];
    red[tid] = s;
    __syncthreads();
#pragma unroll
    for (int off = 128; off > 0; off >>= 1) {
        if (tid < off) red[tid] += red[tid + off];
        __syncthreads();
    }
    if (tid == 0) bsum[blockIdx.x] = red[0];
}

__global__ __launch_bounds__(256) void scan3_kernel(const int* __restrict__ deg,
                                                    const int* __restrict__ bsum,
                                                    int* __restrict__ row_ptr,
                                                    int g, int n) {
    int tid = threadIdx.x;
    int base = blockIdx.x * SCAN_CHUNK + tid * 4;
    int4 v = make_int4(0, 0, 0, 0);
    if (base + 3 < n) {
        v = *(const int4*)(deg + base);
    } else {
        if (base + 0 < n) v.x = deg[base + 0];
        if (base + 1 < n) v.y = deg[base + 1];
        if (base + 2 < n) v.z = deg[base + 2];
        if (base + 3 < n) v.w = deg[base + 3];
    }
    int s = v.x + v.y + v.z + v.w;

    __shared__ int bs[128];
    if (tid < 128) bs[tid] = (tid < g) ? bsum[tid] : 0;
    __syncthreads();
#pragma unroll
    for (int off = 1; off < 128; off <<= 1) {
        int t = (tid < 128 && tid >= off) ? bs[tid - off] : 0;
        __syncthreads();
        if (tid < 128) bs[tid] += t;
        __syncthreads();
    }
    int blockbase = (blockIdx.x == 0) ? 0 : bs[blockIdx.x - 1];
    int total = bs[g - 1];

    __shared__ int sc[256];
    sc[tid] = s;
    __syncthreads();
#pragma unroll
    for (int off = 1; off < 256; off <<= 1) {
        int t = (tid >= off) ? sc[tid - off] : 0;
        __syncthreads();
        sc[tid] += t;
        __syncthreads();
    }
    int excl = sc[tid] - s + blockbase;
    int p0 = excl;
    int p1 = p0 + v.x;
    int p2 = p1 + v.y;
    int p3 = p2 + v.z;
    if (base + 3 < n) {
        *(int4*)(row_ptr + base) = make_int4(p0, p1, p2, p3);
    } else {
        if (base + 0 < n) row_ptr[base + 0] = p0;
        if (base + 1 < n) row_ptr[base + 1] = p1;
        if (base + 2 < n) row_ptr[base + 2] = p2;
    }
    if (blockIdx.x == g - 1 && tid == 0) row_ptr[n] = total;
}

__global__ __launch_bounds__(256) void fill_kernel(
    const int* __restrict__ src, const int* __restrict__ dst,
    const int* __restrict__ rank, const int* __restrict__ row_ptr,
    int* __restrict__ ssrc, int E) {
    int e0 = (blockIdx.x * 256 + threadIdx.x) * 4;
    if (e0 + 3 < E) {
        int4 s = *(const int4*)(src + e0);
        int4 d = *(const int4*)(dst + e0);
        int4 r = *(const int4*)(rank + e0);
        ssrc[row_ptr[d.x] + r.x] = s.x;
        ssrc[row_ptr[d.y] + r.y] = s.y;
        ssrc[row_ptr[d.z] + r.z] = s.z;
        ssrc[row_ptr[d.w] + r.w] = s.w;
    } else {
        for (int e = e0; e < E; ++e) ssrc[row_ptr[dst[e]] + rank[e]] = src[e];
    }
}

// ---------------- weight prep: Wt[n][k] = bf16(W[k][n]), 128x128 ------------

__global__ void prepw_kernel(const float* __restrict__ W0, const float* __restrict__ W1,
                             ushort16* __restrict__ Wt0, ushort16* __restrict__ Wt1) {
    int idx = blockIdx.x * 256 + threadIdx.x;  // 16384
    int n = idx & 127, k = idx >> 7;
    Wt0[n * 128 + k] = f2bf(W0[k * 128 + n]);
    Wt1[n * 128 + k] = f2bf(W1[k * 128 + n]);
}

// ---------------- MFMA GEMM: Yb = bf16((act(X)*ns) @ W), 128-wide -----------
// block 128 rows x 128 cols, 4 waves (2x2 of 64x64), 16x16x32 bf16 MFMA.
// LDS stride 72 bf16 (144B): 16B-aligned rows, <=2 lanes/bank on b128 reads.
template <bool XBF16, bool FUSE_BN>
__global__ __launch_bounds__(256) void gemm_mfma_kernel(
    const void* __restrict__ Xv, const ushort16* __restrict__ Wt,
    const float* __restrict__ ns, const float* __restrict__ ab,
    ushort16* __restrict__ Yb, int nrows) {
    constexpr int LDK = 72;
    __shared__ short As[128 * LDK];
    __shared__ short Ws[128 * LDK];
    int tid = threadIdx.x;
    int row0 = blockIdx.x * 128;
    int wave = tid >> 6, lane = tid & 63;
    int wm = (wave >> 1) * 64, wn = (wave & 1) * 64;
    int l15 = lane & 15, quad = lane >> 4;
    float4v acc[4][4] = {{}};

#pragma unroll
    for (int p = 0; p < 2; ++p) {
        int k0 = p * 64;
        {
            int srow = tid >> 1;
            int half = (tid & 1) * 32;
            int grow = row0 + srow;
            bool ok = grow < nrows;
            float sc = ok ? ns[grow] : 0.f;
            uint32 outu[16];
            if (XBF16) {
                const uint4* xp = (const uint4*)((const uint32*)Xv +
                                                 (size_t)grow * 64 + ((k0 + half) >> 1));
                uint4 u4[4];
#pragma unroll
                for (int q = 0; q < 4; ++q)
                    u4[q] = ok ? xp[q] : make_uint4(0, 0, 0, 0);
                const uint32* uu = (const uint32*)u4;
#pragma unroll
                for (int j = 0; j < 16; ++j) {
                    float2 f = bf2f2(uu[j]);
                    if (FUSE_BN) {
                        int c = k0 + half + j * 2;
                        f.x = fmaxf(fmaf(f.x, ab[c], ab[128 + c]), 0.f);
                        f.y = fmaxf(fmaf(f.y, ab[c + 1], ab[128 + c + 1]), 0.f);
                    }
                    outu[j] = (uint32)f2bf(f.x * sc) | ((uint32)f2bf(f.y * sc) << 16);
                }
            } else {
                const float4* xp = (const float4*)((const float*)Xv +
                                                   (size_t)grow * 128 + k0 + half);
                float4 f4[8];
#pragma unroll
                for (int q = 0; q < 8; ++q)
                    f4[q] = ok ? xp[q] : make_float4(0.f, 0.f, 0.f, 0.f);
                const float* ff = (const float*)f4;
#pragma unroll
                for (int j = 0; j < 16; ++j) {
                    float fx = ff[2 * j], fy = ff[2 * j + 1];
                    if (FUSE_BN) {
                        int c = k0 + half + j * 2;
                        fx = fmaxf(fmaf(fx, ab[c], ab[128 + c]), 0.f);
                        fy = fmaxf(fmaf(fy, ab[c + 1], ab[128 + c + 1]), 0.f);
                    }
                    outu[j] = (uint32)f2bf(fx * sc) | ((uint32)f2bf(fy * sc) << 16);
                }
            }
            uint4* dstA = (uint4*)&As[srow * LDK + half];
#pragma unroll
            for (int q = 0; q < 4; ++q) dstA[q] = ((uint4*)outu)[q];
            // W chunk copy (Wt row stride = 64 uints)
            const uint4* wp = (const uint4*)((const uint32*)Wt +
                                             srow * 64 + ((k0 + half) >> 1));
            uint4* dstW = (uint4*)&Ws[srow * LDK + half];
#pragma unroll
            for (int q = 0; q < 4; ++q) dstW[q] = wp[q];
        }
        __syncthreads();
#pragma unroll
        for (int ks = 0; ks < 2; ++ks) {
            int koff = ks * 32 + quad * 8;
            short8v a[4], b[4];
#pragma unroll
            for (int t = 0; t < 4; ++t)
                a[t] = *(const short8v*)&As[(wm + t * 16 + l15) * LDK + koff];
#pragma unroll
            for (int u = 0; u < 4; ++u)
                b[u] = *(const short8v*)&Ws[(wn + u * 16 + l15) * LDK + koff];
#pragma unroll
            for (int t = 0; t < 4; ++t)
#pragma unroll
                for (int u = 0; u < 4; ++u)
                    acc[t][u] = __builtin_amdgcn_mfma_f32_16x16x32_bf16(
                        a[t], b[u], acc[t][u], 0, 0, 0);
        }
        __syncthreads();
    }
    // epilogue: D row = quad*4+r, col = lane&15 (verified C/D mapping)
#pragma unroll
    for (int t = 0; t < 4; ++t) {
#pragma unroll
        for (int r = 0; r < 4; ++r) {
            int grow = row0 + wm + t * 16 + quad * 4 + r;
            if (grow < nrows) {
#pragma unroll
                for (int u = 0; u < 4; ++u)
                    Yb[(size_t)grow * 128 + wn + u * 16 + l15] = f2bf(acc[t][u][r]);
            }
        }
    }
}

// ---------------- final GEMM: out = X @ W2 + b2, 128->40, fp32 --------------
__global__ __launch_bounds__(256) void gemm_final_kernel(
    const float* __restrict__ X, const float* __restrict__ W,
    const float* __restrict__ bias, float* __restrict__ Y, int nrows) {
    constexpr int BM = 128, BK = 32, BN = 64, WCOLS = 40, TM = 8, TN = 4;
    __shared__ float Asf[BK][BM + 4];
    __shared__ float Bsf[BK][BN + 4];
    int tid = threadIdx.x;
    int tc = tid & 15, tr = tid >> 4;
    int row0 = blockIdx.x * BM;
    float acc[TM][TN] = {};

    for (int kc = 0; kc < D_H; kc += BK) {
        for (int i = tid; i < BM * BK / 4; i += 256) {
            int r = i >> 3;
            int k4 = (i & 7) << 2;
            int row = row0 + r;
            float4 v = make_float4(0.f, 0.f, 0.f, 0.f);
            if (row < nrows) v = *(const float4*)(X + (size_t)row * D_H + kc + k4);
            Asf[k4 + 0][r] = v.x;
            Asf[k4 + 1][r] = v.y;
            Asf[k4 + 2][r] = v.z;
            Asf[k4 + 3][r] = v.w;
        }
        for (int i = tid; i < BK * BN; i += 256) {
            int k = i >> 6, c = i & 63;
            Bsf[k][c] = (c < WCOLS) ? W[(size_t)(kc + k) * WCOLS + c] : 0.f;
        }
        __syncthreads();
#pragma unroll
        for (int k = 0; k < BK; ++k) {
            float a[TM], b[TN];
            *(float4*)&a[0] = *(const float4*)&Asf[k][tr * TM];
            *(float4*)&a[4] = *(const float4*)&Asf[k][tr * TM + 4];
            *(float4*)&b[0] = *(const float4*)&Bsf[k][tc * TN];
#pragma unroll
            for (int m = 0; m < TM; ++m)
#pragma unroll
                for (int n = 0; n < TN; ++n)
                    acc[m][n] = fmaf(a[m], b[n], acc[m][n]);
        }
        __syncthreads();
    }
    int col = tc * TN;
    if (col < WCOLS) {
        float4 bb = *(const float4*)&bias[col];
#pragma unroll
        for (int m = 0; m < TM; ++m) {
            int row = row0 + tr * TM + m;
            if (row < nrows) {
                float4 v = *(float4*)&acc[m][0];
                v.x += bb.x; v.y += bb.y; v.z += bb.z; v.w += bb.w;
                *(float4*)(Y + (size_t)row * WCOLS + col) = v;
            }
        }
    }
}

// ------- CSR aggregation (bf16 in/out): A[v] = nd[v]*sum xwb[src_e] ---------
__global__ __launch_bounds__(256) void agg128_kernel(
    const uint32* __restrict__ xwb, const int* __restrict__ row_ptr,
    const int* __restrict__ ssrc, const float* __restrict__ nd,
    uint32* __restrict__ outb, int n) {
    int node = blockIdx.x * 4 + (threadIdx.x >> 6);
    if (node >= n) return;
    int lane = threadIdx.x & 63;
    int beg = row_ptr[node], end = row_ptr[node + 1];
    float x = 0.f, y = 0.f;
    int e = beg;
    for (; e + 8 <= end; e += 8) {
        int s[8];
#pragma unroll
        for (int j = 0; j < 8; ++j) s[j] = ssrc[e + j];
        uint32 u[8];
#pragma unroll
        for (int j = 0; j < 8; ++j) u[j] = xwb[(size_t)s[j] * 64 + lane];
#pragma unroll
        for (int j = 0; j < 8; ++j) {
            float2 v = bf2f2(u[j]);
            x += v.x;
            y += v.y;
        }
    }
    for (; e + 2 <= end; e += 2) {
        uint32 u0 = xwb[(size_t)ssrc[e] * 64 + lane];
        uint32 u1 = xwb[(size_t)ssrc[e + 1] * 64 + lane];
        float2 v0 = bf2f2(u0), v1 = bf2f2(u1);
        x += v0.x + v1.x;
        y += v0.y + v1.y;
    }
    if (e < end) {
        float2 v0 = bf2f2(xwb[(size_t)ssrc[e] * 64 + lane]);
        x += v0.x;
        y += v0.y;
    }
    float s = nd[node];
    outb[(size_t)node * 64 + lane] =
        (uint32)f2bf(x * s) | ((uint32)f2bf(y * s) << 16);
}

// layer-2 variant: gathers bf16 A, applies relu(a*x+b)*ns[src], writes fp32 B.
__global__ __launch_bounds__(256) void agg128_bn_kernel(
    const uint32* __restrict__ xwb, const int* __restrict__ row_ptr,
    const int* __restrict__ ssrc, const float* __restrict__ nd,
    const float* __restrict__ ns, const float* __restrict__ ab,
    float* __restrict__ out, int n) {
    int node = blockIdx.x * 4 + (threadIdx.x >> 6);
    if (node >= n) return;
    int lane = threadIdx.x & 63;
    float2 a2 = *(const float2*)&ab[lane * 2];
    float2 b2 = *(const float2*)&ab[128 + lane * 2];
    int beg = row_ptr[node], end = row_ptr[node + 1];
    float x = 0.f, y = 0.f;
    int e = beg;
    for (; e + 8 <= end; e += 8) {
        int s[8];
#pragma unroll
        for (int j = 0; j < 8; ++j) s[j] = ssrc[e + j];
        uint32 u[8];
        float sc[8];
#pragma unroll
        for (int j = 0; j < 8; ++j) {
            u[j] = xwb[(size_t)s[j] * 64 + lane];
            sc[j] = ns[s[j]];
        }
#pragma unroll
        for (int j = 0; j < 8; ++j) {
            float2 v = bf2f2(u[j]);
            x += fmaxf(fmaf(v.x, a2.x, b2.x), 0.f) * sc[j];
            y += fmaxf(fmaf(v.y, a2.y, b2.y), 0.f) * sc[j];
        }
    }
    for (; e < end; ++e) {
        int s0 = ssrc[e];
        float2 v0 = bf2f2(xwb[(size_t)s0 * 64 + lane]);
        float sc0 = ns[s0];
        x += fmaxf(fmaf(v0.x, a2.x, b2.x), 0.f) * sc0;
        y += fmaxf(fmaf(v0.y, a2.y, b2.y), 0.f) * sc0;
    }
    float s = nd[node];
    *(float2*)(out + (size_t)node * D_H + lane * 2) = make_float2(x * s, y * s);
}

// ---------------- batchnorm stats (bf16 input) ----------------

__global__ __launch_bounds__(256) void bn_reduce_kernel(const ushort16* __restrict__ x,
                                                        float* __restrict__ stats, int n) {
    int tid = threadIdx.x;
    int col = tid & 127, half = tid >> 7;
    float s = 0.f, s2 = 0.f;
    for (int r = blockIdx.x * 2 + half; r < n; r += gridDim.x * 2) {
        float v = bf2f(x[(size_t)r * D_H + col]);
        s += v;
        s2 = fmaf(v, v, s2);
    }
    __shared__ float red[256];
    red[tid] = s;
    __syncthreads();
    if (half == 0) atomicAdd(&stats[col], s + red[tid + 128]);
    __syncthreads();
    red[tid] = s2;
    __syncthreads();
    if (half == 0) atomicAdd(&stats[128 + col], s2 + red[tid + 128]);
}

__global__ void bn_finalize_kernel(const float* __restrict__ stats,
                                   const float* __restrict__ g,
                                   const float* __restrict__ beta,
                                   float* __restrict__ ab, float inv_n) {
    int c = threadIdx.x;  // 128 threads
    float mean = stats[c] * inv_n;
    float var = stats[128 + c] * inv_n - mean * mean;
    float a = rsqrtf(var + 1e-5f) * g[c];
    ab[c] = a;
    ab[128 + c] = beta[c] - mean * a;
}

// ---------------- launch ----------------

extern "C" void kernel_launch(void* const* d_in, const int* in_sizes, int n_in,
                              void* d_out, int out_size, void* d_ws, size_t ws_size,
                              hipStream_t stream) {
    const float* feat = (const float*)d_in[0];
    const int* edge_src = (const int*)d_in[1];
    const int* edge_dst = (const int*)d_in[2];
    const float* W0 = (const float*)d_in[3];
    const float* W1 = (const float*)d_in[4];
    const float* W2 = (const float*)d_in[5];
    const float* b2 = (const float*)d_in[6];
    const float* g0 = (const float*)d_in[7];
    const float* beta0 = (const float*)d_in[8];
    const float* g1 = (const float*)d_in[9];
    const float* beta1 = (const float*)d_in[10];
    float* out = (float*)d_out;

    const int N = in_sizes[0] / D_H;  // 100000
    const int E = in_sizes[1];        // 1600000

    char* p = (char*)d_ws;
    auto alloc = [&](size_t bytes) {
        char* r = p;
        p += (bytes + 255) & ~(size_t)255;
        return r;
    };
    uint32* Ab = (uint32*)alloc((size_t)N * D_H * 2);   // bf16 A (packed pairs)
    float* B = (float*)alloc((size_t)N * D_H * 4);      // bf16 (gemm out) / fp32 (agg_bn out)
    float* ns = (float*)alloc((size_t)N * 4);
    float* nd = (float*)alloc((size_t)N * 4);
    int* outdeg = (int*)alloc((size_t)N * 4);
    int* indeg = (int*)alloc((size_t)N * 4);
    int* row_ptr = (int*)alloc((size_t)(N + 1) * 4);
    int* ssrc = (int*)alloc((size_t)E * 4);
    int* rank = (int*)alloc((size_t)E * 4);
    int* bsum = (int*)alloc(256 * 4);
    float* stats0 = (float*)alloc(256 * 4);
    float* stats1 = (float*)alloc(256 * 4);
    float* ab0 = (float*)alloc(256 * 4);
    float* ab1 = (float*)alloc(256 * 4);
    ushort16* Wt0 = (ushort16*)alloc(128 * 128 * 2);
    ushort16* Wt1 = (ushort16*)alloc(128 * 128 * 2);
    ushort16* Bb = (ushort16*)B;
    (void)ws_size;

    hipMemsetAsync(outdeg, 0, (size_t)N * 4, stream);
    hipMemsetAsync(indeg, 0, (size_t)N * 4, stream);
    hipMemsetAsync(stats0, 0, 256 * 4, stream);
    hipMemsetAsync(stats1, 0, 256 * 4, stream);

    const int e4grid = (E + 1023) / 1024;
    const int ngrid = (N + 255) / 256;
    const int ggrid = (N + 127) / 128;
    const int agrid = (N + 3) / 4;
    const int sgrid = (N + SCAN_CHUNK - 1) / SCAN_CHUNK;

    prepw_kernel<<<64, 256, 0, stream>>>(W0, W1, Wt0, Wt1);
    deg_kernel<<<e4grid, 256, 0, stream>>>(edge_src, edge_dst, outdeg, indeg, rank, E);
    norm_kernel<<<ngrid, 256, 0, stream>>>(outdeg, indeg, ns, nd, N);
    scan1_kernel<<<sgrid, 256, 0, stream>>>(indeg, bsum, N);
    scan3_kernel<<<sgrid, 256, 0, stream>>>(indeg, bsum, row_ptr, sgrid, N);
    fill_kernel<<<e4grid, 256, 0, stream>>>(edge_src, edge_dst, rank, row_ptr, ssrc, E);

    // layer 0: mfma gemm(feat*ns @ W0) -> Bb; agg -> Ab (bf16); stats
    gemm_mfma_kernel<false, false><<<ggrid, 256, 0, stream>>>(feat, Wt0, ns, nullptr, Bb, N);
    agg128_kernel<<<agrid, 256, 0, stream>>>((const uint32*)Bb, row_ptr, ssrc, nd, Ab, N);
    bn_reduce_kernel<<<512, 256, 0, stream>>>((const ushort16*)Ab, stats0, N);
    bn_finalize_kernel<<<1, 128, 0, stream>>>(stats0, g0, beta0, ab0, 1.0f / N);

    // layer 1: mfma gemm(relu(bn0(Ab))*ns @ W1) -> Bb; agg -> Ab; stats
    gemm_mfma_kernel<true, true><<<ggrid, 256, 0, stream>>>(Ab, Wt1, ns, ab0, Bb, N);
    agg128_kernel<<<agrid, 256, 0, stream>>>((const uint32*)Bb, row_ptr, ssrc, nd, Ab, N);
    bn_reduce_kernel<<<512, 256, 0, stream>>>((const ushort16*)Ab, stats1, N);
    bn_finalize_kernel<<<1, 128, 0, stream>>>(stats1, g1, beta1, ab1, 1.0f / N);

    // layer 2 (reordered): agg(relu(bn1(Ab))*ns) -> B (fp32); gemm_final -> out
    agg128_bn_kernel<<<agrid, 256, 0, stream>>>(Ab, row_ptr, ssrc, nd, ns, ab1, B, N);
    gemm_final_kernel<<<ggrid, 256, 0, stream>>>(B, W2, b2, out, N);
}

// Round 8
// 601.863 us; speedup vs baseline: 2.0597x; 1.0989x over previous
//
#include <hip/hip_runtime.h>
#include <hip/hip_bf16.h>

// 3-layer GCN. R8: CSR build rewritten as bucketed counting sort to beat the
// ~21G scattered-txn/s wall: histo_src (LDS-chunked outdeg), bucket_count
// (per-block x 256-node-bucket counts), scan over the count matrix,
// bucket_scatter (edges -> bucket-grouped packed src|dstlocal), csr (per-bucket
// LDS node-count+scan -> coalesced row_ptr/nd/ns + bucket-local ssrc scatter).
// deg_kernel / norm_kernel / fill_kernel / rank deleted.

#define D_H 128
#define SCAN_CHUNK 1024

typedef unsigned int uint32;
typedef unsigned short ushort16;
typedef __attribute__((ext_vector_type(8))) short short8v;   // 8 bf16 = 4 VGPR
typedef __attribute__((ext_vector_type(4))) float float4v;   // MFMA acc

__device__ __forceinline__ ushort16 f2bf(float f) {
    union { float f; uint32 u; } v;
    v.f = f;
    uint32 u = v.u;
    return (ushort16)((u + 0x7fffu + ((u >> 16) & 1u)) >> 16);  // RNE
}
__device__ __forceinline__ float2 bf2f2(uint32 u) {
    union { uint32 i; float f; } a, b;
    a.i = u << 16;
    b.i = u & 0xffff0000u;
    return make_float2(a.f, b.f);
}
__device__ __forceinline__ float bf2f(ushort16 h) {
    union { uint32 i; float f; } t;
    t.i = ((uint32)h) << 16;
    return t.f;
}

// ---------------- outdeg via chunked LDS histogram ----------------
// grid = nchunks * 32; chunk = blockIdx>>5 (8192-node window), j = edge slice.
__global__ __launch_bounds__(256) void histo_src_kernel(
    const int* __restrict__ src, int* __restrict__ outdeg, int E, int N) {
    __shared__ int h[8192];
    for (int i = threadIdx.x; i < 8192; i += 256) h[i] = 0;
    __syncthreads();
    int chunk = blockIdx.x >> 5, j = blockIdx.x & 31;
    int lo = chunk * 8192, hi = lo + 8192;
    int eps = (E + 31) >> 5;
    int estart = j * eps, eend = min(estart + eps, E);
    for (int e = estart + threadIdx.x; e < eend; e += 256) {
        int s = src[e];
        if (s >= lo && s < hi) atomicAdd(&h[s - lo], 1);
    }
    __syncthreads();
    for (int i = threadIdx.x; i < 8192; i += 256) {
        int v = h[i];
        int node = lo + i;
        if (v && node < N) atomicAdd(&outdeg[node], v);  // coalesced-ish flush
    }
}

// ---------------- bucket counting: M[b*128 + j] = |{e in slice j: dst>>8==b}| --
__global__ __launch_bounds__(256) void bucket_count_kernel(
    const int* __restrict__ dst, int* __restrict__ M, int E, int nbuck) {
    __shared__ int h[512];
    for (int i = threadIdx.x; i < nbuck; i += 256) h[i] = 0;
    __syncthreads();
    int j = blockIdx.x;  // 128 blocks
    int epb = (E + 127) >> 7;
    int estart = j * epb, eend = min(estart + epb, E);
    for (int e = estart + threadIdx.x; e < eend; e += 256)
        atomicAdd(&h[dst[e] >> 8], 1);
    __syncthreads();
    for (int b = threadIdx.x; b < nbuck; b += 256)
        M[(size_t)b * 128 + j] = h[b];
}

// ---------------- generic scan kernels (from R5, reused for M) ----------------
__global__ __launch_bounds__(256) void scan1_kernel(const int* __restrict__ deg,
                                                    int* __restrict__ bsum, int n) {
    int tid = threadIdx.x;
    int base = blockIdx.x * SCAN_CHUNK + tid * 4;
    int4 v = make_int4(0, 0, 0, 0);
    if (base + 3 < n) {
        v = *(const int4*)(deg + base);
    } else {
        if (base + 0 < n) v.x = deg[base + 0];
        if (base + 1 < n) v.y = deg[base + 1];
        if (base + 2 < n) v.z = deg[base + 2];
        if (base + 3 < n) v.w = deg[base + 3];
    }
    int s = v.x + v.y + v.z + v.w;
    __shared__ int red[256];
    red[tid] = s;
    __syncthreads();
#pragma unroll
    for (int off = 128; off > 0; off >>= 1) {
        if (tid < off) red[tid] += red[tid + off];
        __syncthreads();
    }
    if (tid == 0) bsum[blockIdx.x] = red[0];
}

__global__ __launch_bounds__(256) void scan3_kernel(const int* __restrict__ deg,
                                                    const int* __restrict__ bsum,
                                                    int* __restrict__ outp,
                                                    int g, int n) {
    int tid = threadIdx.x;
    int base = blockIdx.x * SCAN_CHUNK + tid * 4;
    int4 v = make_int4(0, 0, 0, 0);
    if (base + 3 < n) {
        v = *(const int4*)(deg + base);
    } else {
        if (base + 0 < n) v.x = deg[base + 0];
        if (base + 1 < n) v.y = deg[base + 1];
        if (base + 2 < n) v.z = deg[base + 2];
        if (base + 3 < n) v.w = deg[base + 3];
    }
    int s = v.x + v.y + v.z + v.w;

    __shared__ int bs[128];
    if (tid < 128) bs[tid] = (tid < g) ? bsum[tid] : 0;
    __syncthreads();
#pragma unroll
    for (int off = 1; off < 128; off <<= 1) {
        int t = (tid < 128 && tid >= off) ? bs[tid - off] : 0;
        __syncthreads();
        if (tid < 128) bs[tid] += t;
        __syncthreads();
    }
    int blockbase = (blockIdx.x == 0) ? 0 : bs[blockIdx.x - 1];
    int total = bs[g - 1];

    __shared__ int sc[256];
    sc[tid] = s;
    __syncthreads();
#pragma unroll
    for (int off = 1; off < 256; off <<= 1) {
        int t = (tid >= off) ? sc[tid - off] : 0;
        __syncthreads();
        sc[tid] += t;
        __syncthreads();
    }
    int excl = sc[tid] - s + blockbase;
    int p0 = excl;
    int p1 = p0 + v.x;
    int p2 = p1 + v.y;
    int p3 = p2 + v.z;
    if (base + 3 < n) {
        *(int4*)(outp + base) = make_int4(p0, p1, p2, p3);
    } else {
        if (base + 0 < n) outp[base + 0] = p0;
        if (base + 1 < n) outp[base + 1] = p1;
        if (base + 2 < n) outp[base + 2] = p2;
    }
    if (blockIdx.x == g - 1 && tid == 0) outp[n] = total;
}

// ---------------- bucket scatter: packed[pos] = src<<8 | (dst&255) ----------
// same edge partition as bucket_count so Mx columns match.
__global__ __launch_bounds__(256) void bucket_scatter_kernel(
    const int* __restrict__ src, const int* __restrict__ dst,
    const int* __restrict__ Mx, uint32* __restrict__ packed, int E, int nbuck) {
    __shared__ int colbase[512];
    __shared__ int cur[512];
    int j = blockIdx.x;
    for (int i = threadIdx.x; i < nbuck; i += 256) {
        colbase[i] = Mx[(size_t)i * 128 + j];
        cur[i] = 0;
    }
    __syncthreads();
    int epb = (E + 127) >> 7;
    int estart = j * epb, eend = min(estart + epb, E);
    for (int e = estart + threadIdx.x; e < eend; e += 256) {
        int s = src[e], d = dst[e];
        int b = d >> 8;
        int r = atomicAdd(&cur[b], 1);
        packed[colbase[b] + r] = ((uint32)s << 8) | (uint32)(d & 255);
    }
}

// ---------------- per-bucket CSR finalize: row_ptr, nd, ns, ssrc ------------
__global__ __launch_bounds__(256) void csr_kernel(
    const uint32* __restrict__ packed, const int* __restrict__ Mx,
    const int* __restrict__ outdeg, int* __restrict__ row_ptr,
    float* __restrict__ ns, float* __restrict__ nd, int* __restrict__ ssrc,
    int E, int N, int nbuck) {
    __shared__ int cnt[256], pos0[256], cur[256], sc[256];
    int b = blockIdx.x, tid = threadIdx.x;
    int lo = Mx[(size_t)b * 128];
    int hi = (b == nbuck - 1) ? E : Mx[(size_t)(b + 1) * 128];
    cnt[tid] = 0;
    cur[tid] = 0;
    __syncthreads();
    for (int e = lo + tid; e < hi; e += 256)
        atomicAdd(&cnt[packed[e] & 255u], 1);
    __syncthreads();
    int c = cnt[tid];
    sc[tid] = c;
    __syncthreads();
#pragma unroll
    for (int off = 1; off < 256; off <<= 1) {
        int t = (tid >= off) ? sc[tid - off] : 0;
        __syncthreads();
        sc[tid] += t;
        __syncthreads();
    }
    int excl = sc[tid] - c;
    pos0[tid] = lo + excl;
    int node = b * 256 + tid;
    if (node < N) {
        row_ptr[node] = lo + excl;
        nd[node] = rsqrtf((float)max(c, 1));
        ns[node] = rsqrtf((float)max(outdeg[node], 1));
    }
    if (b == 0 && tid == 0) row_ptr[N] = E;
    __syncthreads();
    for (int e = lo + tid; e < hi; e += 256) {
        uint32 p = packed[e];
        int local = (int)(p & 255u);
        int r = atomicAdd(&cur[local], 1);
        ssrc[pos0[local] + r] = (int)(p >> 8);  // bucket-local (L2-hot) scatter
    }
}

// ---------------- weight prep: Wt[n][k] = bf16(W[k][n]), 128x128 ------------

__global__ void prepw_kernel(const float* __restrict__ W0, const float* __restrict__ W1,
                             ushort16* __restrict__ Wt0, ushort16* __restrict__ Wt1) {
    int idx = blockIdx.x * 256 + threadIdx.x;  // 16384
    int n = idx & 127, k = idx >> 7;
    Wt0[n * 128 + k] = f2bf(W0[k * 128 + n]);
    Wt1[n * 128 + k] = f2bf(W1[k * 128 + n]);
}

// ---------------- MFMA GEMM (unchanged from R7) ----------------
template <bool XBF16, bool FUSE_BN>
__global__ __launch_bounds__(256) void gemm_mfma_kernel(
    const void* __restrict__ Xv, const ushort16* __restrict__ Wt,
    const float* __restrict__ ns, const float* __restrict__ ab,
    ushort16* __restrict__ Yb, int nrows) {
    constexpr int LDK = 72;
    __shared__ short As[128 * LDK];
    __shared__ short Ws[128 * LDK];
    int tid = threadIdx.x;
    int row0 = blockIdx.x * 128;
    int wave = tid >> 6, lane = tid & 63;
    int wm = (wave >> 1) * 64, wn = (wave & 1) * 64;
    int l15 = lane & 15, quad = lane >> 4;
    float4v acc[4][4] = {{}};

#pragma unroll
    for (int p = 0; p < 2; ++p) {
        int k0 = p * 64;
        {
            int srow = tid >> 1;
            int half = (tid & 1) * 32;
            int grow = row0 + srow;
            bool ok = grow < nrows;
            float sc = ok ? ns[grow] : 0.f;
            uint32 outu[16];
            if (XBF16) {
                const uint4* xp = (const uint4*)((const uint32*)Xv +
                                                 (size_t)grow * 64 + ((k0 + half) >> 1));
                uint4 u4[4];
#pragma unroll
                for (int q = 0; q < 4; ++q)
                    u4[q] = ok ? xp[q] : make_uint4(0, 0, 0, 0);
                const uint32* uu = (const uint32*)u4;
#pragma unroll
                for (int j = 0; j < 16; ++j) {
                    float2 f = bf2f2(uu[j]);
                    if (FUSE_BN) {
                        int c = k0 + half + j * 2;
                        f.x = fmaxf(fmaf(f.x, ab[c], ab[128 + c]), 0.f);
                        f.y = fmaxf(fmaf(f.y, ab[c + 1], ab[128 + c + 1]), 0.f);
                    }
                    outu[j] = (uint32)f2bf(f.x * sc) | ((uint32)f2bf(f.y * sc) << 16);
                }
            } else {
                const float4* xp = (const float4*)((const float*)Xv +
                                                   (size_t)grow * 128 + k0 + half);
                float4 f4[8];
#pragma unroll
                for (int q = 0; q < 8; ++q)
                    f4[q] = ok ? xp[q] : make_float4(0.f, 0.f, 0.f, 0.f);
                const float* ff = (const float*)f4;
#pragma unroll
                for (int j = 0; j < 16; ++j) {
                    float fx = ff[2 * j], fy = ff[2 * j + 1];
                    if (FUSE_BN) {
                        int c = k0 + half + j * 2;
                        fx = fmaxf(fmaf(fx, ab[c], ab[128 + c]), 0.f);
                        fy = fmaxf(fmaf(fy, ab[c + 1], ab[128 + c + 1]), 0.f);
                    }
                    outu[j] = (uint32)f2bf(fx * sc) | ((uint32)f2bf(fy * sc) << 16);
                }
            }
            uint4* dstA = (uint4*)&As[srow * LDK + half];
#pragma unroll
            for (int q = 0; q < 4; ++q) dstA[q] = ((uint4*)outu)[q];
            const uint4* wp = (const uint4*)((const uint32*)Wt +
                                             srow * 64 + ((k0 + half) >> 1));
            uint4* dstW = (uint4*)&Ws[srow * LDK + half];
#pragma unroll
            for (int q = 0; q < 4; ++q) dstW[q] = wp[q];
        }
        __syncthreads();
#pragma unroll
        for (int ks = 0; ks < 2; ++ks) {
            int koff = ks * 32 + quad * 8;
            short8v a[4], b[4];
#pragma unroll
            for (int t = 0; t < 4; ++t)
                a[t] = *(const short8v*)&As[(wm + t * 16 + l15) * LDK + koff];
#pragma unroll
            for (int u = 0; u < 4; ++u)
                b[u] = *(const short8v*)&Ws[(wn + u * 16 + l15) * LDK + koff];
#pragma unroll
            for (int t = 0; t < 4; ++t)
#pragma unroll
                for (int u = 0; u < 4; ++u)
                    acc[t][u] = __builtin_amdgcn_mfma_f32_16x16x32_bf16(
                        a[t], b[u], acc[t][u], 0, 0, 0);
        }
        __syncthreads();
    }
#pragma unroll
    for (int t = 0; t < 4; ++t) {
#pragma unroll
        for (int r = 0; r < 4; ++r) {
            int grow = row0 + wm + t * 16 + quad * 4 + r;
            if (grow < nrows) {
#pragma unroll
                for (int u = 0; u < 4; ++u)
                    Yb[(size_t)grow * 128 + wn + u * 16 + l15] = f2bf(acc[t][u][r]);
            }
        }
    }
}

// ---------------- final GEMM: out = X @ W2 + b2, 128->40, fp32 --------------
__global__ __launch_bounds__(256) void gemm_final_kernel(
    const float* __restrict__ X, const float* __restrict__ W,
    const float* __restrict__ bias, float* __restrict__ Y, int nrows) {
    constexpr int BM = 128, BK = 32, BN = 64, WCOLS = 40, TM = 8, TN = 4;
    __shared__ float Asf[BK][BM + 4];
    __shared__ float Bsf[BK][BN + 4];
    int tid = threadIdx.x;
    int tc = tid & 15, tr = tid >> 4;
    int row0 = blockIdx.x * BM;
    float acc[TM][TN] = {};

    for (int kc = 0; kc < D_H; kc += BK) {
        for (int i = tid; i < BM * BK / 4; i += 256) {
            int r = i >> 3;
            int k4 = (i & 7) << 2;
            int row = row0 + r;
            float4 v = make_float4(0.f, 0.f, 0.f, 0.f);
            if (row < nrows) v = *(const float4*)(X + (size_t)row * D_H + kc + k4);
            Asf[k4 + 0][r] = v.x;
            Asf[k4 + 1][r] = v.y;
            Asf[k4 + 2][r] = v.z;
            Asf[k4 + 3][r] = v.w;
        }
        for (int i = tid; i < BK * BN; i += 256) {
            int k = i >> 6, c = i & 63;
            Bsf[k][c] = (c < WCOLS) ? W[(size_t)(kc + k) * WCOLS + c] : 0.f;
        }
        __syncthreads();
#pragma unroll
        for (int k = 0; k < BK; ++k) {
            float a[TM], b[TN];
            *(float4*)&a[0] = *(const float4*)&Asf[k][tr * TM];
            *(float4*)&a[4] = *(const float4*)&Asf[k][tr * TM + 4];
            *(float4*)&b[0] = *(const float4*)&Bsf[k][tc * TN];
#pragma unroll
            for (int m = 0; m < TM; ++m)
#pragma unroll
                for (int n = 0; n < TN; ++n)
                    acc[m][n] = fmaf(a[m], b[n], acc[m][n]);
        }
        __syncthreads();
    }
    int col = tc * TN;
    if (col < WCOLS) {
        float4 bb = *(const float4*)&bias[col];
#pragma unroll
        for (int m = 0; m < TM; ++m) {
            int row = row0 + tr * TM + m;
            if (row < nrows) {
                float4 v = *(float4*)&acc[m][0];
                v.x += bb.x; v.y += bb.y; v.z += bb.z; v.w += bb.w;
                *(float4*)(Y + (size_t)row * WCOLS + col) = v;
            }
        }
    }
}

// ------- CSR aggregation (bf16 in/out) ----------
__global__ __launch_bounds__(256) void agg128_kernel(
    const uint32* __restrict__ xwb, const int* __restrict__ row_ptr,
    const int* __restrict__ ssrc, const float* __restrict__ nd,
    uint32* __restrict__ outb, int n) {
    int node = blockIdx.x * 4 + (threadIdx.x >> 6);
    if (node >= n) return;
    int lane = threadIdx.x & 63;
    int beg = row_ptr[node], end = row_ptr[node + 1];
    float x = 0.f, y = 0.f;
    int e = beg;
    for (; e + 8 <= end; e += 8) {
        int s[8];
#pragma unroll
        for (int j = 0; j < 8; ++j) s[j] = ssrc[e + j];
        uint32 u[8];
#pragma unroll
        for (int j = 0; j < 8; ++j) u[j] = xwb[(size_t)s[j] * 64 + lane];
#pragma unroll
        for (int j = 0; j < 8; ++j) {
            float2 v = bf2f2(u[j]);
            x += v.x;
            y += v.y;
        }
    }
    for (; e + 2 <= end; e += 2) {
        uint32 u0 = xwb[(size_t)ssrc[e] * 64 + lane];
        uint32 u1 = xwb[(size_t)ssrc[e + 1] * 64 + lane];
        float2 v0 = bf2f2(u0), v1 = bf2f2(u1);
        x += v0.x + v1.x;
        y += v0.y + v1.y;
    }
    if (e < end) {
        float2 v0 = bf2f2(xwb[(size_t)ssrc[e] * 64 + lane]);
        x += v0.x;
        y += v0.y;
    }
    float s = nd[node];
    outb[(size_t)node * 64 + lane] =
        (uint32)f2bf(x * s) | ((uint32)f2bf(y * s) << 16);
}

// layer-2 variant: gathers bf16 A, applies relu(a*x+b)*ns[src], writes fp32 B.
__global__ __launch_bounds__(256) void agg128_bn_kernel(
    const uint32* __restrict__ xwb, const int* __restrict__ row_ptr,
    const int* __restrict__ ssrc, const float* __restrict__ nd,
    const float* __restrict__ ns, const float* __restrict__ ab,
    float* __restrict__ out, int n) {
    int node = blockIdx.x * 4 + (threadIdx.x >> 6);
    if (node >= n) return;
    int lane = threadIdx.x & 63;
    float2 a2 = *(const float2*)&ab[lane * 2];
    float2 b2 = *(const float2*)&ab[128 + lane * 2];
    int beg = row_ptr[node], end = row_ptr[node + 1];
    float x = 0.f, y = 0.f;
    int e = beg;
    for (; e + 8 <= end; e += 8) {
        int s[8];
#pragma unroll
        for (int j = 0; j < 8; ++j) s[j] = ssrc[e + j];
        uint32 u[8];
        float sc[8];
#pragma unroll
        for (int j = 0; j < 8; ++j) {
            u[j] = xwb[(size_t)s[j] * 64 + lane];
            sc[j] = ns[s[j]];
        }
#pragma unroll
        for (int j = 0; j < 8; ++j) {
            float2 v = bf2f2(u[j]);
            x += fmaxf(fmaf(v.x, a2.x, b2.x), 0.f) * sc[j];
            y += fmaxf(fmaf(v.y, a2.y, b2.y), 0.f) * sc[j];
        }
    }
    for (; e < end; ++e) {
        int s0 = ssrc[e];
        float2 v0 = bf2f2(xwb[(size_t)s0 * 64 + lane]);
        float sc0 = ns[s0];
        x += fmaxf(fmaf(v0.x, a2.x, b2.x), 0.f) * sc0;
        y += fmaxf(fmaf(v0.y, a2.y, b2.y), 0.f) * sc0;
    }
    float s = nd[node];
    *(float2*)(out + (size_t)node * D_H + lane * 2) = make_float2(x * s, y * s);
}

// ---------------- batchnorm stats (bf16 input) ----------------

__global__ __launch_bounds__(256) void bn_reduce_kernel(const ushort16* __restrict__ x,
                                                        float* __restrict__ stats, int n) {
    int tid = threadIdx.x;
    int col = tid & 127, half = tid >> 7;
    float s = 0.f, s2 = 0.f;
    for (int r = blockIdx.x * 2 + half; r < n; r += gridDim.x * 2) {
        float v = bf2f(x[(size_t)r * D_H + col]);
        s += v;
        s2 = fmaf(v, v, s2);
    }
    __shared__ float red[256];
    red[tid] = s;
    __syncthreads();
    if (half == 0) atomicAdd(&stats[col], s + red[tid + 128]);
    __syncthreads();
    red[tid] = s2;
    __syncthreads();
    if (half == 0) atomicAdd(&stats[128 + col], s2 + red[tid + 128]);
}

__global__ void bn_finalize_kernel(const float* __restrict__ stats,
                                   const float* __restrict__ g,
                                   const float* __restrict__ beta,
                                   float* __restrict__ ab, float inv_n) {
    int c = threadIdx.x;  // 128 threads
    float mean = stats[c] * inv_n;
    float var = stats[128 + c] * inv_n - mean * mean;
    float a = rsqrtf(var + 1e-5f) * g[c];
    ab[c] = a;
    ab[128 + c] = beta[c] - mean * a;
}

// ---------------- launch ----------------

extern "C" void kernel_launch(void* const* d_in, const int* in_sizes, int n_in,
                              void* d_out, int out_size, void* d_ws, size_t ws_size,
                              hipStream_t stream) {
    const float* feat = (const float*)d_in[0];
    const int* edge_src = (const int*)d_in[1];
    const int* edge_dst = (const int*)d_in[2];
    const float* W0 = (const float*)d_in[3];
    const float* W1 = (const float*)d_in[4];
    const float* W2 = (const float*)d_in[5];
    const float* b2 = (const float*)d_in[6];
    const float* g0 = (const float*)d_in[7];
    const float* beta0 = (const float*)d_in[8];
    const float* g1 = (const float*)d_in[9];
    const float* beta1 = (const float*)d_in[10];
    float* out = (float*)d_out;

    const int N = in_sizes[0] / D_H;   // 100000
    const int E = in_sizes[1];         // 1600000
    const int nbuck = (N + 255) >> 8;  // 391

    char* p = (char*)d_ws;
    auto alloc = [&](size_t bytes) {
        char* r = p;
        p += (bytes + 255) & ~(size_t)255;
        return r;
    };
    uint32* Ab = (uint32*)alloc((size_t)N * D_H * 2);   // bf16 A (packed pairs)
    float* B = (float*)alloc((size_t)N * D_H * 4);      // bf16 (gemm out) / fp32 (agg_bn out)
    float* ns = (float*)alloc((size_t)N * 4);
    float* nd = (float*)alloc((size_t)N * 4);
    int* outdeg = (int*)alloc((size_t)N * 4);
    int* row_ptr = (int*)alloc((size_t)(N + 1) * 4);
    int* ssrc = (int*)alloc((size_t)E * 4);
    uint32* packed = (uint32*)alloc((size_t)E * 4);
    int* M = (int*)alloc((size_t)nbuck * 128 * 4);
    int* Mx = (int*)alloc(((size_t)nbuck * 128 + 4) * 4);
    int* bsum = (int*)alloc(256 * 4);
    float* stats0 = (float*)alloc(256 * 4);
    float* stats1 = (float*)alloc(256 * 4);
    float* ab0 = (float*)alloc(256 * 4);
    float* ab1 = (float*)alloc(256 * 4);
    ushort16* Wt0 = (ushort16*)alloc(128 * 128 * 2);
    ushort16* Wt1 = (ushort16*)alloc(128 * 128 * 2);
    ushort16* Bb = (ushort16*)B;
    (void)ws_size;

    hipMemsetAsync(outdeg, 0, (size_t)N * 4, stream);
    hipMemsetAsync(stats0, 0, 256 * 4, stream);
    hipMemsetAsync(stats1, 0, 256 * 4, stream);

    const int ggrid = (N + 127) / 128;
    const int agrid = (N + 3) / 4;
    const int nM = nbuck * 128;                            // 50048
    const int sgridM = (nM + SCAN_CHUNK - 1) / SCAN_CHUNK; // 49
    const int nchunks = (N + 8191) / 8192;                 // 13

    prepw_kernel<<<64, 256, 0, stream>>>(W0, W1, Wt0, Wt1);
    histo_src_kernel<<<nchunks * 32, 256, 0, stream>>>(edge_src, outdeg, E, N);
    bucket_count_kernel<<<128, 256, 0, stream>>>(edge_dst, M, E, nbuck);
    scan1_kernel<<<sgridM, 256, 0, stream>>>(M, bsum, nM);
    scan3_kernel<<<sgridM, 256, 0, stream>>>(M, bsum, Mx, sgridM, nM);
    bucket_scatter_kernel<<<128, 256, 0, stream>>>(edge_src, edge_dst, Mx, packed, E, nbuck);
    csr_kernel<<<nbuck, 256, 0, stream>>>(packed, Mx, outdeg, row_ptr, ns, nd, ssrc, E, N, nbuck);

    // layer 0: mfma gemm(feat*ns @ W0) -> Bb; agg -> Ab (bf16); stats
    gemm_mfma_kernel<false, false><<<ggrid, 256, 0, stream>>>(feat, Wt0, ns, nullptr, Bb, N);
    agg128_kernel<<<agrid, 256, 0, stream>>>((const uint32*)Bb, row_ptr, ssrc, nd, Ab, N);
    bn_reduce_kernel<<<512, 256, 0, stream>>>((const ushort16*)Ab, stats0, N);
    bn_finalize_kernel<<<1, 128, 0, stream>>>(stats0, g0, beta0, ab0, 1.0f / N);

    // layer 1: mfma gemm(relu(bn0(Ab))*ns @ W1) -> Bb; agg -> Ab; stats
    gemm_mfma_kernel<true, true><<<ggrid, 256, 0, stream>>>(Ab, Wt1, ns, ab0, Bb, N);
    agg128_kernel<<<agrid, 256, 0, stream>>>((const uint32*)Bb, row_ptr, ssrc, nd, Ab, N);
    bn_reduce_kernel<<<512, 256, 0, stream>>>((const ushort16*)Ab, stats1, N);
    bn_finalize_kernel<<<1, 128, 0, stream>>>(stats1, g1, beta1, ab1, 1.0f / N);

    // layer 2 (reordered): agg(relu(bn1(Ab))*ns) -> B (fp32); gemm_final -> out
    agg128_bn_kernel<<<agrid, 256, 0, stream>>>(Ab, row_ptr, ssrc, nd, ns, ab1, B, N);
    gemm_final_kernel<<<ggrid, 256, 0, stream>>>(B, W2, b2, out, N);
}

// Round 9
// 586.126 us; speedup vs baseline: 2.1150x; 1.0268x over previous
//
#include <hip/hip_runtime.h>
#include <hip/hip_bf16.h>

// 3-layer GCN. R9: outdeg histogram (92us, 13x read-amp, 1.6 blocks/CU)
// replaced by the src-side bucket pipeline: bucket_count(src) -> scan ->
// bucket_scatter_src (raw src, bucket-grouped) -> src_count (per-bucket LDS
// count -> coalesced ns write). histo_src_kernel + outdeg deleted.

#define D_H 128
#define SCAN_CHUNK 1024

typedef unsigned int uint32;
typedef unsigned short ushort16;
typedef __attribute__((ext_vector_type(8))) short short8v;   // 8 bf16 = 4 VGPR
typedef __attribute__((ext_vector_type(4))) float float4v;   // MFMA acc

__device__ __forceinline__ ushort16 f2bf(float f) {
    union { float f; uint32 u; } v;
    v.f = f;
    uint32 u = v.u;
    return (ushort16)((u + 0x7fffu + ((u >> 16) & 1u)) >> 16);  // RNE
}
__device__ __forceinline__ float2 bf2f2(uint32 u) {
    union { uint32 i; float f; } a, b;
    a.i = u << 16;
    b.i = u & 0xffff0000u;
    return make_float2(a.f, b.f);
}
__device__ __forceinline__ float bf2f(ushort16 h) {
    union { uint32 i; float f; } t;
    t.i = ((uint32)h) << 16;
    return t.f;
}

// ------- bucket counting: M[b*128 + j] = |{e in slice j: idx[e]>>8 == b}| ----
__global__ __launch_bounds__(256) void bucket_count_kernel(
    const int* __restrict__ idx, int* __restrict__ M, int E, int nbuck) {
    __shared__ int h[512];
    for (int i = threadIdx.x; i < nbuck; i += 256) h[i] = 0;
    __syncthreads();
    int j = blockIdx.x;  // 128 blocks
    int epb = (E + 127) >> 7;
    int estart = j * epb, eend = min(estart + epb, E);
    for (int e = estart + threadIdx.x; e < eend; e += 256)
        atomicAdd(&h[idx[e] >> 8], 1);
    __syncthreads();
    for (int b = threadIdx.x; b < nbuck; b += 256)
        M[(size_t)b * 128 + j] = h[b];
}

// ---------------- generic scan kernels ----------------
__global__ __launch_bounds__(256) void scan1_kernel(const int* __restrict__ deg,
                                                    int* __restrict__ bsum, int n) {
    int tid = threadIdx.x;
    int base = blockIdx.x * SCAN_CHUNK + tid * 4;
    int4 v = make_int4(0, 0, 0, 0);
    if (base + 3 < n) {
        v = *(const int4*)(deg + base);
    } else {
        if (base + 0 < n) v.x = deg[base + 0];
        if (base + 1 < n) v.y = deg[base + 1];
        if (base + 2 < n) v.z = deg[base + 2];
        if (base + 3 < n) v.w = deg[base + 3];
    }
    int s = v.x + v.y + v.z + v.w;
    __shared__ int red[256];
    red[tid] = s;
    __syncthreads();
#pragma unroll
    for (int off = 128; off > 0; off >>= 1) {
        if (tid < off) red[tid] += red[tid + off];
        __syncthreads();
    }
    if (tid == 0) bsum[blockIdx.x] = red[0];
}

__global__ __launch_bounds__(256) void scan3_kernel(const int* __restrict__ deg,
                                                    const int* __restrict__ bsum,
                                                    int* __restrict__ outp,
                                                    int g, int n) {
    int tid = threadIdx.x;
    int base = blockIdx.x * SCAN_CHUNK + tid * 4;
    int4 v = make_int4(0, 0, 0, 0);
    if (base + 3 < n) {
        v = *(const int4*)(deg + base);
    } else {
        if (base + 0 < n) v.x = deg[base + 0];
        if (base + 1 < n) v.y = deg[base + 1];
        if (base + 2 < n) v.z = deg[base + 2];
        if (base + 3 < n) v.w = deg[base + 3];
    }
    int s = v.x + v.y + v.z + v.w;

    __shared__ int bs[128];
    if (tid < 128) bs[tid] = (tid < g) ? bsum[tid] : 0;
    __syncthreads();
#pragma unroll
    for (int off = 1; off < 128; off <<= 1) {
        int t = (tid < 128 && tid >= off) ? bs[tid - off] : 0;
        __syncthreads();
        if (tid < 128) bs[tid] += t;
        __syncthreads();
    }
    int blockbase = (blockIdx.x == 0) ? 0 : bs[blockIdx.x - 1];
    int total = bs[g - 1];

    __shared__ int sc[256];
    sc[tid] = s;
    __syncthreads();
#pragma unroll
    for (int off = 1; off < 256; off <<= 1) {
        int t = (tid >= off) ? sc[tid - off] : 0;
        __syncthreads();
        sc[tid] += t;
        __syncthreads();
    }
    int excl = sc[tid] - s + blockbase;
    int p0 = excl;
    int p1 = p0 + v.x;
    int p2 = p1 + v.y;
    int p3 = p2 + v.z;
    if (base + 3 < n) {
        *(int4*)(outp + base) = make_int4(p0, p1, p2, p3);
    } else {
        if (base + 0 < n) outp[base + 0] = p0;
        if (base + 1 < n) outp[base + 1] = p1;
        if (base + 2 < n) outp[base + 2] = p2;
    }
    if (blockIdx.x == g - 1 && tid == 0) outp[n] = total;
}

// -------- dst bucket scatter: packed[pos] = src<<8 | (dst&255) --------------
__global__ __launch_bounds__(256) void bucket_scatter_kernel(
    const int* __restrict__ src, const int* __restrict__ dst,
    const int* __restrict__ Mx, uint32* __restrict__ packed, int E, int nbuck) {
    __shared__ int colbase[512];
    __shared__ int cur[512];
    int j = blockIdx.x;
    for (int i = threadIdx.x; i < nbuck; i += 256) {
        colbase[i] = Mx[(size_t)i * 128 + j];
        cur[i] = 0;
    }
    __syncthreads();
    int epb = (E + 127) >> 7;
    int estart = j * epb, eend = min(estart + epb, E);
    for (int e = estart + threadIdx.x; e < eend; e += 256) {
        int s = src[e], d = dst[e];
        int b = d >> 8;
        int r = atomicAdd(&cur[b], 1);
        packed[colbase[b] + r] = ((uint32)s << 8) | (uint32)(d & 255);
    }
}

// -------- src bucket scatter: sp[pos] = src (bucket-grouped raw values) -----
__global__ __launch_bounds__(256) void bucket_scatter_src_kernel(
    const int* __restrict__ src, const int* __restrict__ Mx2,
    uint32* __restrict__ sp, int E, int nbuck) {
    __shared__ int colbase[512];
    __shared__ int cur[512];
    int j = blockIdx.x;
    for (int i = threadIdx.x; i < nbuck; i += 256) {
        colbase[i] = Mx2[(size_t)i * 128 + j];
        cur[i] = 0;
    }
    __syncthreads();
    int epb = (E + 127) >> 7;
    int estart = j * epb, eend = min(estart + epb, E);
    for (int e = estart + threadIdx.x; e < eend; e += 256) {
        int s = src[e];
        int b = s >> 8;
        int r = atomicAdd(&cur[b], 1);
        sp[colbase[b] + r] = (uint32)s;
    }
}

// -------- src per-node count -> ns (coalesced write) ------------------------
__global__ __launch_bounds__(256) void src_count_kernel(
    const uint32* __restrict__ sp, const int* __restrict__ Mx2,
    float* __restrict__ ns, int E, int N, int nbuck) {
    __shared__ int cnt[256];
    int b = blockIdx.x, tid = threadIdx.x;
    int lo = Mx2[(size_t)b * 128];
    int hi = (b == nbuck - 1) ? E : Mx2[(size_t)(b + 1) * 128];
    cnt[tid] = 0;
    __syncthreads();
    for (int e = lo + tid; e < hi; e += 256)
        atomicAdd(&cnt[sp[e] & 255u], 1);
    __syncthreads();
    int node = b * 256 + tid;
    if (node < N) ns[node] = rsqrtf((float)max(cnt[tid], 1));
}

// -------- per-bucket CSR finalize: row_ptr, nd, ssrc ------------------------
__global__ __launch_bounds__(256) void csr_kernel(
    const uint32* __restrict__ packed, const int* __restrict__ Mx,
    int* __restrict__ row_ptr, float* __restrict__ nd, int* __restrict__ ssrc,
    int E, int N, int nbuck) {
    __shared__ int cnt[256], pos0[256], cur[256], sc[256];
    int b = blockIdx.x, tid = threadIdx.x;
    int lo = Mx[(size_t)b * 128];
    int hi = (b == nbuck - 1) ? E : Mx[(size_t)(b + 1) * 128];
    cnt[tid] = 0;
    cur[tid] = 0;
    __syncthreads();
    for (int e = lo + tid; e < hi; e += 256)
        atomicAdd(&cnt[packed[e] & 255u], 1);
    __syncthreads();
    int c = cnt[tid];
    sc[tid] = c;
    __syncthreads();
#pragma unroll
    for (int off = 1; off < 256; off <<= 1) {
        int t = (tid >= off) ? sc[tid - off] : 0;
        __syncthreads();
        sc[tid] += t;
        __syncthreads();
    }
    int excl = sc[tid] - c;
    pos0[tid] = lo + excl;
    int node = b * 256 + tid;
    if (node < N) {
        row_ptr[node] = lo + excl;
        nd[node] = rsqrtf((float)max(c, 1));
    }
    if (b == 0 && tid == 0) row_ptr[N] = E;
    __syncthreads();
    for (int e = lo + tid; e < hi; e += 256) {
        uint32 p = packed[e];
        int local = (int)(p & 255u);
        int r = atomicAdd(&cur[local], 1);
        ssrc[pos0[local] + r] = (int)(p >> 8);  // bucket-local (L2-hot) scatter
    }
}

// ---------------- weight prep: Wt[n][k] = bf16(W[k][n]), 128x128 ------------

__global__ void prepw_kernel(const float* __restrict__ W0, const float* __restrict__ W1,
                             ushort16* __restrict__ Wt0, ushort16* __restrict__ Wt1) {
    int idx = blockIdx.x * 256 + threadIdx.x;  // 16384
    int n = idx & 127, k = idx >> 7;
    Wt0[n * 128 + k] = f2bf(W0[k * 128 + n]);
    Wt1[n * 128 + k] = f2bf(W1[k * 128 + n]);
}

// ---------------- MFMA GEMM (unchanged from R7) ----------------
template <bool XBF16, bool FUSE_BN>
__global__ __launch_bounds__(256) void gemm_mfma_kernel(
    const void* __restrict__ Xv, const ushort16* __restrict__ Wt,
    const float* __restrict__ ns, const float* __restrict__ ab,
    ushort16* __restrict__ Yb, int nrows) {
    constexpr int LDK = 72;
    __shared__ short As[128 * LDK];
    __shared__ short Ws[128 * LDK];
    int tid = threadIdx.x;
    int row0 = blockIdx.x * 128;
    int wave = tid >> 6, lane = tid & 63;
    int wm = (wave >> 1) * 64, wn = (wave & 1) * 64;
    int l15 = lane & 15, quad = lane >> 4;
    float4v acc[4][4] = {{}};

#pragma unroll
    for (int p = 0; p < 2; ++p) {
        int k0 = p * 64;
        {
            int srow = tid >> 1;
            int half = (tid & 1) * 32;
            int grow = row0 + srow;
            bool ok = grow < nrows;
            float sc = ok ? ns[grow] : 0.f;
            uint32 outu[16];
            if (XBF16) {
                const uint4* xp = (const uint4*)((const uint32*)Xv +
                                                 (size_t)grow * 64 + ((k0 + half) >> 1));
                uint4 u4[4];
#pragma unroll
                for (int q = 0; q < 4; ++q)
                    u4[q] = ok ? xp[q] : make_uint4(0, 0, 0, 0);
                const uint32* uu = (const uint32*)u4;
#pragma unroll
                for (int j = 0; j < 16; ++j) {
                    float2 f = bf2f2(uu[j]);
                    if (FUSE_BN) {
                        int c = k0 + half + j * 2;
                        f.x = fmaxf(fmaf(f.x, ab[c], ab[128 + c]), 0.f);
                        f.y = fmaxf(fmaf(f.y, ab[c + 1], ab[128 + c + 1]), 0.f);
                    }
                    outu[j] = (uint32)f2bf(f.x * sc) | ((uint32)f2bf(f.y * sc) << 16);
                }
            } else {
                const float4* xp = (const float4*)((const float*)Xv +
                                                   (size_t)grow * 128 + k0 + half);
                float4 f4[8];
#pragma unroll
                for (int q = 0; q < 8; ++q)
                    f4[q] = ok ? xp[q] : make_float4(0.f, 0.f, 0.f, 0.f);
                const float* ff = (const float*)f4;
#pragma unroll
                for (int j = 0; j < 16; ++j) {
                    float fx = ff[2 * j], fy = ff[2 * j + 1];
                    if (FUSE_BN) {
                        int c = k0 + half + j * 2;
                        fx = fmaxf(fmaf(fx, ab[c], ab[128 + c]), 0.f);
                        fy = fmaxf(fmaf(fy, ab[c + 1], ab[128 + c + 1]), 0.f);
                    }
                    outu[j] = (uint32)f2bf(fx * sc) | ((uint32)f2bf(fy * sc) << 16);
                }
            }
            uint4* dstA = (uint4*)&As[srow * LDK + half];
#pragma unroll
            for (int q = 0; q < 4; ++q) dstA[q] = ((uint4*)outu)[q];
            const uint4* wp = (const uint4*)((const uint32*)Wt +
                                             srow * 64 + ((k0 + half) >> 1));
            uint4* dstW = (uint4*)&Ws[srow * LDK + half];
#pragma unroll
            for (int q = 0; q < 4; ++q) dstW[q] = wp[q];
        }
        __syncthreads();
#pragma unroll
        for (int ks = 0; ks < 2; ++ks) {
            int koff = ks * 32 + quad * 8;
            short8v a[4], b[4];
#pragma unroll
            for (int t = 0; t < 4; ++t)
                a[t] = *(const short8v*)&As[(wm + t * 16 + l15) * LDK + koff];
#pragma unroll
            for (int u = 0; u < 4; ++u)
                b[u] = *(const short8v*)&Ws[(wn + u * 16 + l15) * LDK + koff];
#pragma unroll
            for (int t = 0; t < 4; ++t)
#pragma unroll
                for (int u = 0; u < 4; ++u)
                    acc[t][u] = __builtin_amdgcn_mfma_f32_16x16x32_bf16(
                        a[t], b[u], acc[t][u], 0, 0, 0);
        }
        __syncthreads();
    }
#pragma unroll
    for (int t = 0; t < 4; ++t) {
#pragma unroll
        for (int r = 0; r < 4; ++r) {
            int grow = row0 + wm + t * 16 + quad * 4 + r;
            if (grow < nrows) {
#pragma unroll
                for (int u = 0; u < 4; ++u)
                    Yb[(size_t)grow * 128 + wn + u * 16 + l15] = f2bf(acc[t][u][r]);
            }
        }
    }
}

// ---------------- final GEMM: out = X @ W2 + b2, 128->40, fp32 --------------
__global__ __launch_bounds__(256) void gemm_final_kernel(
    const float* __restrict__ X, const float* __restrict__ W,
    const float* __restrict__ bias, float* __restrict__ Y, int nrows) {
    constexpr int BM = 128, BK = 32, BN = 64, WCOLS = 40, TM = 8, TN = 4;
    __shared__ float Asf[BK][BM + 4];
    __shared__ float Bsf[BK][BN + 4];
    int tid = threadIdx.x;
    int tc = tid & 15, tr = tid >> 4;
    int row0 = blockIdx.x * BM;
    float acc[TM][TN] = {};

    for (int kc = 0; kc < D_H; kc += BK) {
        for (int i = tid; i < BM * BK / 4; i += 256) {
            int r = i >> 3;
            int k4 = (i & 7) << 2;
            int row = row0 + r;
            float4 v = make_float4(0.f, 0.f, 0.f, 0.f);
            if (row < nrows) v = *(const float4*)(X + (size_t)row * D_H + kc + k4);
            Asf[k4 + 0][r] = v.x;
            Asf[k4 + 1][r] = v.y;
            Asf[k4 + 2][r] = v.z;
            Asf[k4 + 3][r] = v.w;
        }
        for (int i = tid; i < BK * BN; i += 256) {
            int k = i >> 6, c = i & 63;
            Bsf[k][c] = (c < WCOLS) ? W[(size_t)(kc + k) * WCOLS + c] : 0.f;
        }
        __syncthreads();
#pragma unroll
        for (int k = 0; k < BK; ++k) {
            float a[TM], b[TN];
            *(float4*)&a[0] = *(const float4*)&Asf[k][tr * TM];
            *(float4*)&a[4] = *(const float4*)&Asf[k][tr * TM + 4];
            *(float4*)&b[0] = *(const float4*)&Bsf[k][tc * TN];
#pragma unroll
            for (int m = 0; m < TM; ++m)
#pragma unroll
                for (int n = 0; n < TN; ++n)
                    acc[m][n] = fmaf(a[m], b[n], acc[m][n]);
        }
        __syncthreads();
    }
    int col = tc * TN;
    if (col < WCOLS) {
        float4 bb = *(const float4*)&bias[col];
#pragma unroll
        for (int m = 0; m < TM; ++m) {
            int row = row0 + tr * TM + m;
            if (row < nrows) {
                float4 v = *(float4*)&acc[m][0];
                v.x += bb.x; v.y += bb.y; v.z += bb.z; v.w += bb.w;
                *(float4*)(Y + (size_t)row * WCOLS + col) = v;
            }
        }
    }
}

// ------- CSR aggregation (bf16 in/out) ----------
__global__ __launch_bounds__(256) void agg128_kernel(
    const uint32* __restrict__ xwb, const int* __restrict__ row_ptr,
    const int* __restrict__ ssrc, const float* __restrict__ nd,
    uint32* __restrict__ outb, int n) {
    int node = blockIdx.x * 4 + (threadIdx.x >> 6);
    if (node >= n) return;
    int lane = threadIdx.x & 63;
    int beg = row_ptr[node], end = row_ptr[node + 1];
    float x = 0.f, y = 0.f;
    int e = beg;
    for (; e + 8 <= end; e += 8) {
        int s[8];
#pragma unroll
        for (int j = 0; j < 8; ++j) s[j] = ssrc[e + j];
        uint32 u[8];
#pragma unroll
        for (int j = 0; j < 8; ++j) u[j] = xwb[(size_t)s[j] * 64 + lane];
#pragma unroll
        for (int j = 0; j < 8; ++j) {
            float2 v = bf2f2(u[j]);
            x += v.x;
            y += v.y;
        }
    }
    for (; e + 2 <= end; e += 2) {
        uint32 u0 = xwb[(size_t)ssrc[e] * 64 + lane];
        uint32 u1 = xwb[(size_t)ssrc[e + 1] * 64 + lane];
        float2 v0 = bf2f2(u0), v1 = bf2f2(u1);
        x += v0.x + v1.x;
        y += v0.y + v1.y;
    }
    if (e < end) {
        float2 v0 = bf2f2(xwb[(size_t)ssrc[e] * 64 + lane]);
        x += v0.x;
        y += v0.y;
    }
    float s = nd[node];
    outb[(size_t)node * 64 + lane] =
        (uint32)f2bf(x * s) | ((uint32)f2bf(y * s) << 16);
}

// layer-2 variant: gathers bf16 A, applies relu(a*x+b)*ns[src], writes fp32 B.
__global__ __launch_bounds__(256) void agg128_bn_kernel(
    const uint32* __restrict__ xwb, const int* __restrict__ row_ptr,
    const int* __restrict__ ssrc, const float* __restrict__ nd,
    const float* __restrict__ ns, const float* __restrict__ ab,
    float* __restrict__ out, int n) {
    int node = blockIdx.x * 4 + (threadIdx.x >> 6);
    if (node >= n) return;
    int lane = threadIdx.x & 63;
    float2 a2 = *(const float2*)&ab[lane * 2];
    float2 b2 = *(const float2*)&ab[128 + lane * 2];
    int beg = row_ptr[node], end = row_ptr[node + 1];
    float x = 0.f, y = 0.f;
    int e = beg;
    for (; e + 8 <= end; e += 8) {
        int s[8];
#pragma unroll
        for (int j = 0; j < 8; ++j) s[j] = ssrc[e + j];
        uint32 u[8];
        float sc[8];
#pragma unroll
        for (int j = 0; j < 8; ++j) {
            u[j] = xwb[(size_t)s[j] * 64 + lane];
            sc[j] = ns[s[j]];
        }
#pragma unroll
        for (int j = 0; j < 8; ++j) {
            float2 v = bf2f2(u[j]);
            x += fmaxf(fmaf(v.x, a2.x, b2.x), 0.f) * sc[j];
            y += fmaxf(fmaf(v.y, a2.y, b2.y), 0.f) * sc[j];
        }
    }
    for (; e < end; ++e) {
        int s0 = ssrc[e];
        float2 v0 = bf2f2(xwb[(size_t)s0 * 64 + lane]);
        float sc0 = ns[s0];
        x += fmaxf(fmaf(v0.x, a2.x, b2.x), 0.f) * sc0;
        y += fmaxf(fmaf(v0.y, a2.y, b2.y), 0.f) * sc0;
    }
    float s = nd[node];
    *(float2*)(out + (size_t)node * D_H + lane * 2) = make_float2(x * s, y * s);
}

// ---------------- batchnorm stats (bf16 input) ----------------

__global__ __launch_bounds__(256) void bn_reduce_kernel(const ushort16* __restrict__ x,
                                                        float* __restrict__ stats, int n) {
    int tid = threadIdx.x;
    int col = tid & 127, half = tid >> 7;
    float s = 0.f, s2 = 0.f;
    for (int r = blockIdx.x * 2 + half; r < n; r += gridDim.x * 2) {
        float v = bf2f(x[(size_t)r * D_H + col]);
        s += v;
        s2 = fmaf(v, v, s2);
    }
    __shared__ float red[256];
    red[tid] = s;
    __syncthreads();
    if (half == 0) atomicAdd(&stats[col], s + red[tid + 128]);
    __syncthreads();
    red[tid] = s2;
    __syncthreads();
    if (half == 0) atomicAdd(&stats[128 + col], s2 + red[tid + 128]);
}

__global__ void bn_finalize_kernel(const float* __restrict__ stats,
                                   const float* __restrict__ g,
                                   const float* __restrict__ beta,
                                   float* __restrict__ ab, float inv_n) {
    int c = threadIdx.x;  // 128 threads
    float mean = stats[c] * inv_n;
    float var = stats[128 + c] * inv_n - mean * mean;
    float a = rsqrtf(var + 1e-5f) * g[c];
    ab[c] = a;
    ab[128 + c] = beta[c] - mean * a;
}

// ---------------- launch ----------------

extern "C" void kernel_launch(void* const* d_in, const int* in_sizes, int n_in,
                              void* d_out, int out_size, void* d_ws, size_t ws_size,
                              hipStream_t stream) {
    const float* feat = (const float*)d_in[0];
    const int* edge_src = (const int*)d_in[1];
    const int* edge_dst = (const int*)d_in[2];
    const float* W0 = (const float*)d_in[3];
    const float* W1 = (const float*)d_in[4];
    const float* W2 = (const float*)d_in[5];
    const float* b2 = (const float*)d_in[6];
    const float* g0 = (const float*)d_in[7];
    const float* beta0 = (const float*)d_in[8];
    const float* g1 = (const float*)d_in[9];
    const float* beta1 = (const float*)d_in[10];
    float* out = (float*)d_out;

    const int N = in_sizes[0] / D_H;   // 100000
    const int E = in_sizes[1];         // 1600000
    const int nbuck = (N + 255) >> 8;  // 391

    char* p = (char*)d_ws;
    auto alloc = [&](size_t bytes) {
        char* r = p;
        p += (bytes + 255) & ~(size_t)255;
        return r;
    };
    uint32* Ab = (uint32*)alloc((size_t)N * D_H * 2);   // bf16 A (packed pairs)
    float* B = (float*)alloc((size_t)N * D_H * 4);      // bf16 (gemm out) / fp32 (agg_bn out)
    float* ns = (float*)alloc((size_t)N * 4);
    float* nd = (float*)alloc((size_t)N * 4);
    int* row_ptr = (int*)alloc((size_t)(N + 1) * 4);
    int* ssrc = (int*)alloc((size_t)E * 4);
    uint32* packed = (uint32*)alloc((size_t)E * 4);     // dst pipeline; then reused as sp
    int* M = (int*)alloc((size_t)nbuck * 128 * 4);
    int* Mx = (int*)alloc(((size_t)nbuck * 128 + 4) * 4);
    int* M2 = (int*)alloc((size_t)nbuck * 128 * 4);
    int* Mx2 = (int*)alloc(((size_t)nbuck * 128 + 4) * 4);
    uint32* sp = (uint32*)alloc((size_t)E * 4);         // src-bucketed values
    int* bsum = (int*)alloc(256 * 4);
    float* stats0 = (float*)alloc(256 * 4);
    float* stats1 = (float*)alloc(256 * 4);
    float* ab0 = (float*)alloc(256 * 4);
    float* ab1 = (float*)alloc(256 * 4);
    ushort16* Wt0 = (ushort16*)alloc(128 * 128 * 2);
    ushort16* Wt1 = (ushort16*)alloc(128 * 128 * 2);
    ushort16* Bb = (ushort16*)B;
    (void)ws_size;

    hipMemsetAsync(stats0, 0, 256 * 4, stream);
    hipMemsetAsync(stats1, 0, 256 * 4, stream);

    const int ggrid = (N + 127) / 128;
    const int agrid = (N + 3) / 4;
    const int nM = nbuck * 128;                            // 50048
    const int sgridM = (nM + SCAN_CHUNK - 1) / SCAN_CHUNK; // 49

    prepw_kernel<<<64, 256, 0, stream>>>(W0, W1, Wt0, Wt1);

    // dst pipeline: bucket CSR
    bucket_count_kernel<<<128, 256, 0, stream>>>(edge_dst, M, E, nbuck);
    scan1_kernel<<<sgridM, 256, 0, stream>>>(M, bsum, nM);
    scan3_kernel<<<sgridM, 256, 0, stream>>>(M, bsum, Mx, sgridM, nM);
    bucket_scatter_kernel<<<128, 256, 0, stream>>>(edge_src, edge_dst, Mx, packed, E, nbuck);
    csr_kernel<<<nbuck, 256, 0, stream>>>(packed, Mx, row_ptr, nd, ssrc, E, N, nbuck);

    // src pipeline: out-degree -> ns
    bucket_count_kernel<<<128, 256, 0, stream>>>(edge_src, M2, E, nbuck);
    scan1_kernel<<<sgridM, 256, 0, stream>>>(M2, bsum, nM);
    scan3_kernel<<<sgridM, 256, 0, stream>>>(M2, bsum, Mx2, sgridM, nM);
    bucket_scatter_src_kernel<<<128, 256, 0, stream>>>(edge_src, Mx2, sp, E, nbuck);
    src_count_kernel<<<nbuck, 256, 0, stream>>>(sp, Mx2, ns, E, N, nbuck);

    // layer 0: mfma gemm(feat*ns @ W0) -> Bb; agg -> Ab (bf16); stats
    gemm_mfma_kernel<false, false><<<ggrid, 256, 0, stream>>>(feat, Wt0, ns, nullptr, Bb, N);
    agg128_kernel<<<agrid, 256, 0, stream>>>((const uint32*)Bb, row_ptr, ssrc, nd, Ab, N);
    bn_reduce_kernel<<<512, 256, 0, stream>>>((const ushort16*)Ab, stats0, N);
    bn_finalize_kernel<<<1, 128, 0, stream>>>(stats0, g0, beta0, ab0, 1.0f / N);

    // layer 1: mfma gemm(relu(bn0(Ab))*ns @ W1) -> Bb; agg -> Ab; stats
    gemm_mfma_kernel<true, true><<<ggrid, 256, 0, stream>>>(Ab, Wt1, ns, ab0, Bb, N);
    agg128_kernel<<<agrid, 256, 0, stream>>>((const uint32*)Bb, row_ptr, ssrc, nd, Ab, N);
    bn_reduce_kernel<<<512, 256, 0, stream>>>((const ushort16*)Ab, stats1, N);
    bn_finalize_kernel<<<1, 128, 0, stream>>>(stats1, g1, beta1, ab1, 1.0f / N);

    // layer 2 (reordered): agg(relu(bn1(Ab))*ns) -> B (fp32); gemm_final -> out
    agg128_bn_kernel<<<agrid, 256, 0, stream>>>(Ab, row_ptr, ssrc, nd, ns, ab1, B, N);
    gemm_final_kernel<<<ggrid, 256, 0, stream>>>(B, W2, b2, out, N);
}

// Round 10
// 566.341 us; speedup vs baseline: 2.1889x; 1.0349x over previous
//
#include <hip/hip_runtime.h>
#include <hip/hip_bf16.h>

// 3-layer GCN. R10: (1) agg loops software-pipelined (double-buffered 8-edge
// batches, gathers stay in flight across iterations); (2) agg_bn writes bf16 +
// gemm_final -> MFMA with bf16 W2 (padded to 64 cols); (3) bucket count/scatter
// fused across src+dst pipelines (one edge pass each).

#define D_H 128
#define SCAN_CHUNK 1024

typedef unsigned int uint32;
typedef unsigned short ushort16;
typedef __attribute__((ext_vector_type(8))) short short8v;   // 8 bf16 = 4 VGPR
typedef __attribute__((ext_vector_type(4))) float float4v;   // MFMA acc

__device__ __forceinline__ ushort16 f2bf(float f) {
    union { float f; uint32 u; } v;
    v.f = f;
    uint32 u = v.u;
    return (ushort16)((u + 0x7fffu + ((u >> 16) & 1u)) >> 16);  // RNE
}
__device__ __forceinline__ float2 bf2f2(uint32 u) {
    union { uint32 i; float f; } a, b;
    a.i = u << 16;
    b.i = u & 0xffff0000u;
    return make_float2(a.f, b.f);
}
__device__ __forceinline__ float bf2f(ushort16 h) {
    union { uint32 i; float f; } t;
    t.i = ((uint32)h) << 16;
    return t.f;
}

// ------- fused bucket counting (dst -> M, src -> M2), one edge pass ---------
__global__ __launch_bounds__(256) void bucket_count2_kernel(
    const int* __restrict__ src, const int* __restrict__ dst,
    int* __restrict__ M, int* __restrict__ M2, int E, int nbuck) {
    __shared__ int h[512], h2[512];
    for (int i = threadIdx.x; i < nbuck; i += 256) { h[i] = 0; h2[i] = 0; }
    __syncthreads();
    int j = blockIdx.x;  // 128 blocks
    int epb = (E + 127) >> 7;
    int estart = j * epb, eend = min(estart + epb, E);
    for (int e = estart + threadIdx.x; e < eend; e += 256) {
        atomicAdd(&h[dst[e] >> 8], 1);
        atomicAdd(&h2[src[e] >> 8], 1);
    }
    __syncthreads();
    for (int b = threadIdx.x; b < nbuck; b += 256) {
        M[(size_t)b * 128 + j] = h[b];
        M2[(size_t)b * 128 + j] = h2[b];
    }
}

// ---------------- generic scan kernels ----------------
__global__ __launch_bounds__(256) void scan1_kernel(const int* __restrict__ deg,
                                                    int* __restrict__ bsum, int n) {
    int tid = threadIdx.x;
    int base = blockIdx.x * SCAN_CHUNK + tid * 4;
    int4 v = make_int4(0, 0, 0, 0);
    if (base + 3 < n) {
        v = *(const int4*)(deg + base);
    } else {
        if (base + 0 < n) v.x = deg[base + 0];
        if (base + 1 < n) v.y = deg[base + 1];
        if (base + 2 < n) v.z = deg[base + 2];
        if (base + 3 < n) v.w = deg[base + 3];
    }
    int s = v.x + v.y + v.z + v.w;
    __shared__ int red[256];
    red[tid] = s;
    __syncthreads();
#pragma unroll
    for (int off = 128; off > 0; off >>= 1) {
        if (tid < off) red[tid] += red[tid + off];
        __syncthreads();
    }
    if (tid == 0) bsum[blockIdx.x] = red[0];
}

__global__ __launch_bounds__(256) void scan3_kernel(const int* __restrict__ deg,
                                                    const int* __restrict__ bsum,
                                                    int* __restrict__ outp,
                                                    int g, int n) {
    int tid = threadIdx.x;
    int base = blockIdx.x * SCAN_CHUNK + tid * 4;
    int4 v = make_int4(0, 0, 0, 0);
    if (base + 3 < n) {
        v = *(const int4*)(deg + base);
    } else {
        if (base + 0 < n) v.x = deg[base + 0];
        if (base + 1 < n) v.y = deg[base + 1];
        if (base + 2 < n) v.z = deg[base + 2];
        if (base + 3 < n) v.w = deg[base + 3];
    }
    int s = v.x + v.y + v.z + v.w;

    __shared__ int bs[128];
    if (tid < 128) bs[tid] = (tid < g) ? bsum[tid] : 0;
    __syncthreads();
#pragma unroll
    for (int off = 1; off < 128; off <<= 1) {
        int t = (tid < 128 && tid >= off) ? bs[tid - off] : 0;
        __syncthreads();
        if (tid < 128) bs[tid] += t;
        __syncthreads();
    }
    int blockbase = (blockIdx.x == 0) ? 0 : bs[blockIdx.x - 1];
    int total = bs[g - 1];

    __shared__ int sc[256];
    sc[tid] = s;
    __syncthreads();
#pragma unroll
    for (int off = 1; off < 256; off <<= 1) {
        int t = (tid >= off) ? sc[tid - off] : 0;
        __syncthreads();
        sc[tid] += t;
        __syncthreads();
    }
    int excl = sc[tid] - s + blockbase;
    int p0 = excl;
    int p1 = p0 + v.x;
    int p2 = p1 + v.y;
    int p3 = p2 + v.z;
    if (base + 3 < n) {
        *(int4*)(outp + base) = make_int4(p0, p1, p2, p3);
    } else {
        if (base + 0 < n) outp[base + 0] = p0;
        if (base + 1 < n) outp[base + 1] = p1;
        if (base + 2 < n) outp[base + 2] = p2;
    }
    if (blockIdx.x == g - 1 && tid == 0) outp[n] = total;
}

// ------- fused bucket scatter: dst-packed + src-raw, one edge pass ----------
__global__ __launch_bounds__(256) void bucket_scatter2_kernel(
    const int* __restrict__ src, const int* __restrict__ dst,
    const int* __restrict__ Mx, const int* __restrict__ Mx2,
    uint32* __restrict__ packed, uint32* __restrict__ sp, int E, int nbuck) {
    __shared__ int cb1[512], c1[512], cb2[512], c2[512];
    int j = blockIdx.x;
    for (int i = threadIdx.x; i < nbuck; i += 256) {
        cb1[i] = Mx[(size_t)i * 128 + j];
        c1[i] = 0;
        cb2[i] = Mx2[(size_t)i * 128 + j];
        c2[i] = 0;
    }
    __syncthreads();
    int epb = (E + 127) >> 7;
    int estart = j * epb, eend = min(estart + epb, E);
    for (int e = estart + threadIdx.x; e < eend; e += 256) {
        int s = src[e], d = dst[e];
        int b = d >> 8;
        int r = atomicAdd(&c1[b], 1);
        packed[cb1[b] + r] = ((uint32)s << 8) | (uint32)(d & 255);
        int b2 = s >> 8;
        int r2 = atomicAdd(&c2[b2], 1);
        sp[cb2[b2] + r2] = (uint32)s;
    }
}

// -------- src per-node count -> ns (coalesced write) ------------------------
__global__ __launch_bounds__(256) void src_count_kernel(
    const uint32* __restrict__ sp, const int* __restrict__ Mx2,
    float* __restrict__ ns, int E, int N, int nbuck) {
    __shared__ int cnt[256];
    int b = blockIdx.x, tid = threadIdx.x;
    int lo = Mx2[(size_t)b * 128];
    int hi = (b == nbuck - 1) ? E : Mx2[(size_t)(b + 1) * 128];
    cnt[tid] = 0;
    __syncthreads();
    for (int e = lo + tid; e < hi; e += 256)
        atomicAdd(&cnt[sp[e] & 255u], 1);
    __syncthreads();
    int node = b * 256 + tid;
    if (node < N) ns[node] = rsqrtf((float)max(cnt[tid], 1));
}

// -------- per-bucket CSR finalize: row_ptr, nd, ssrc ------------------------
__global__ __launch_bounds__(256) void csr_kernel(
    const uint32* __restrict__ packed, const int* __restrict__ Mx,
    int* __restrict__ row_ptr, float* __restrict__ nd, int* __restrict__ ssrc,
    int E, int N, int nbuck) {
    __shared__ int cnt[256], pos0[256], cur[256], sc[256];
    int b = blockIdx.x, tid = threadIdx.x;
    int lo = Mx[(size_t)b * 128];
    int hi = (b == nbuck - 1) ? E : Mx[(size_t)(b + 1) * 128];
    cnt[tid] = 0;
    cur[tid] = 0;
    __syncthreads();
    for (int e = lo + tid; e < hi; e += 256)
        atomicAdd(&cnt[packed[e] & 255u], 1);
    __syncthreads();
    int c = cnt[tid];
    sc[tid] = c;
    __syncthreads();
#pragma unroll
    for (int off = 1; off < 256; off <<= 1) {
        int t = (tid >= off) ? sc[tid - off] : 0;
        __syncthreads();
        sc[tid] += t;
        __syncthreads();
    }
    int excl = sc[tid] - c;
    pos0[tid] = lo + excl;
    int node = b * 256 + tid;
    if (node < N) {
        row_ptr[node] = lo + excl;
        nd[node] = rsqrtf((float)max(c, 1));
    }
    if (b == 0 && tid == 0) row_ptr[N] = E;
    __syncthreads();
    for (int e = lo + tid; e < hi; e += 256) {
        uint32 p = packed[e];
        int local = (int)(p & 255u);
        int r = atomicAdd(&cur[local], 1);
        ssrc[pos0[local] + r] = (int)(p >> 8);
    }
}

// --- weight prep: Wt0/Wt1 [128][128], Wt2 [64][128] (rows 40..63 zero) ------
__global__ void prepw_kernel(const float* __restrict__ W0, const float* __restrict__ W1,
                             const float* __restrict__ W2,
                             ushort16* __restrict__ Wt0, ushort16* __restrict__ Wt1,
                             ushort16* __restrict__ Wt2) {
    int idx = blockIdx.x * 256 + threadIdx.x;  // 24576
    if (idx < 16384) {
        int n = idx & 127, k = idx >> 7;
        Wt0[n * 128 + k] = f2bf(W0[k * 128 + n]);
        Wt1[n * 128 + k] = f2bf(W1[k * 128 + n]);
    } else {
        int i2 = idx - 16384;  // < 8192
        int n = i2 >> 7, k = i2 & 127;
        Wt2[n * 128 + k] = (n < 40) ? f2bf(W2[k * 40 + n]) : (ushort16)0;
    }
}

// ---------------- MFMA GEMM (layers 0/1, unchanged from R7) ----------------
template <bool XBF16, bool FUSE_BN>
__global__ __launch_bounds__(256) void gemm_mfma_kernel(
    const void* __restrict__ Xv, const ushort16* __restrict__ Wt,
    const float* __restrict__ ns, const float* __restrict__ ab,
    ushort16* __restrict__ Yb, int nrows) {
    constexpr int LDK = 72;
    __shared__ short As[128 * LDK];
    __shared__ short Ws[128 * LDK];
    int tid = threadIdx.x;
    int row0 = blockIdx.x * 128;
    int wave = tid >> 6, lane = tid & 63;
    int wm = (wave >> 1) * 64, wn = (wave & 1) * 64;
    int l15 = lane & 15, quad = lane >> 4;
    float4v acc[4][4] = {{}};

#pragma unroll
    for (int p = 0; p < 2; ++p) {
        int k0 = p * 64;
        {
            int srow = tid >> 1;
            int half = (tid & 1) * 32;
            int grow = row0 + srow;
            bool ok = grow < nrows;
            float sc = ok ? ns[grow] : 0.f;
            uint32 outu[16];
            if (XBF16) {
                const uint4* xp = (const uint4*)((const uint32*)Xv +
                                                 (size_t)grow * 64 + ((k0 + half) >> 1));
                uint4 u4[4];
#pragma unroll
                for (int q = 0; q < 4; ++q)
                    u4[q] = ok ? xp[q] : make_uint4(0, 0, 0, 0);
                const uint32* uu = (const uint32*)u4;
#pragma unroll
                for (int j = 0; j < 16; ++j) {
                    float2 f = bf2f2(uu[j]);
                    if (FUSE_BN) {
                        int c = k0 + half + j * 2;
                        f.x = fmaxf(fmaf(f.x, ab[c], ab[128 + c]), 0.f);
                        f.y = fmaxf(fmaf(f.y, ab[c + 1], ab[128 + c + 1]), 0.f);
                    }
                    outu[j] = (uint32)f2bf(f.x * sc) | ((uint32)f2bf(f.y * sc) << 16);
                }
            } else {
                const float4* xp = (const float4*)((const float*)Xv +
                                                   (size_t)grow * 128 + k0 + half);
                float4 f4[8];
#pragma unroll
                for (int q = 0; q < 8; ++q)
                    f4[q] = ok ? xp[q] : make_float4(0.f, 0.f, 0.f, 0.f);
                const float* ff = (const float*)f4;
#pragma unroll
                for (int j = 0; j < 16; ++j) {
                    float fx = ff[2 * j], fy = ff[2 * j + 1];
                    if (FUSE_BN) {
                        int c = k0 + half + j * 2;
                        fx = fmaxf(fmaf(fx, ab[c], ab[128 + c]), 0.f);
                        fy = fmaxf(fmaf(fy, ab[c + 1], ab[128 + c + 1]), 0.f);
                    }
                    outu[j] = (uint32)f2bf(fx * sc) | ((uint32)f2bf(fy * sc) << 16);
                }
            }
            uint4* dstA = (uint4*)&As[srow * LDK + half];
#pragma unroll
            for (int q = 0; q < 4; ++q) dstA[q] = ((uint4*)outu)[q];
            const uint4* wp = (const uint4*)((const uint32*)Wt +
                                             srow * 64 + ((k0 + half) >> 1));
            uint4* dstW = (uint4*)&Ws[srow * LDK + half];
#pragma unroll
            for (int q = 0; q < 4; ++q) dstW[q] = wp[q];
        }
        __syncthreads();
#pragma unroll
        for (int ks = 0; ks < 2; ++ks) {
            int koff = ks * 32 + quad * 8;
            short8v a[4], b[4];
#pragma unroll
            for (int t = 0; t < 4; ++t)
                a[t] = *(const short8v*)&As[(wm + t * 16 + l15) * LDK + koff];
#pragma unroll
            for (int u = 0; u < 4; ++u)
                b[u] = *(const short8v*)&Ws[(wn + u * 16 + l15) * LDK + koff];
#pragma unroll
            for (int t = 0; t < 4; ++t)
#pragma unroll
                for (int u = 0; u < 4; ++u)
                    acc[t][u] = __builtin_amdgcn_mfma_f32_16x16x32_bf16(
                        a[t], b[u], acc[t][u], 0, 0, 0);
        }
        __syncthreads();
    }
#pragma unroll
    for (int t = 0; t < 4; ++t) {
#pragma unroll
        for (int r = 0; r < 4; ++r) {
            int grow = row0 + wm + t * 16 + quad * 4 + r;
            if (grow < nrows) {
#pragma unroll
                for (int u = 0; u < 4; ++u)
                    Yb[(size_t)grow * 128 + wn + u * 16 + l15] = f2bf(acc[t][u][r]);
            }
        }
    }
}

// ------- final MFMA GEMM: out = Xb(bf16) @ W2 + b2, 128->40 (64 padded) -----
__global__ __launch_bounds__(256) void gemm_final_mfma_kernel(
    const uint32* __restrict__ Xb, const ushort16* __restrict__ Wt2,
    const float* __restrict__ bias, float* __restrict__ Y, int nrows) {
    constexpr int LDK = 72;
    __shared__ short As[128 * LDK];
    __shared__ short Ws[64 * LDK];
    int tid = threadIdx.x;
    int row0 = blockIdx.x * 128;
    int wave = tid >> 6, lane = tid & 63;
    int wm = (wave >> 1) * 64, wn = (wave & 1) * 32;
    int l15 = lane & 15, quad = lane >> 4;
    float4v acc[4][2] = {{}};

#pragma unroll
    for (int p = 0; p < 2; ++p) {
        int k0 = p * 64;
        {
            int srow = tid >> 1;
            int half = (tid & 1) * 32;
            int grow = row0 + srow;
            bool ok = grow < nrows;
            const uint4* xp = (const uint4*)(Xb + (size_t)grow * 64 + ((k0 + half) >> 1));
            uint4 u4[4];
#pragma unroll
            for (int q = 0; q < 4; ++q)
                u4[q] = ok ? xp[q] : make_uint4(0, 0, 0, 0);
            uint4* dstA = (uint4*)&As[srow * LDK + half];
#pragma unroll
            for (int q = 0; q < 4; ++q) dstA[q] = u4[q];
        }
        {
            int srow = tid >> 2;           // 64 rows
            int off = (tid & 3) * 16;      // 16 shorts each
            const uint4* wp = (const uint4*)((const uint32*)Wt2 +
                                             srow * 64 + ((k0 + off) >> 1));
            uint4* dw = (uint4*)&Ws[srow * LDK + off];
            dw[0] = wp[0];
            dw[1] = wp[1];
        }
        __syncthreads();
#pragma unroll
        for (int ks = 0; ks < 2; ++ks) {
            int koff = ks * 32 + quad * 8;
            short8v a[4], b[2];
#pragma unroll
            for (int t = 0; t < 4; ++t)
                a[t] = *(const short8v*)&As[(wm + t * 16 + l15) * LDK + koff];
#pragma unroll
            for (int u = 0; u < 2; ++u)
                b[u] = *(const short8v*)&Ws[(wn + u * 16 + l15) * LDK + koff];
#pragma unroll
            for (int t = 0; t < 4; ++t)
#pragma unroll
                for (int u = 0; u < 2; ++u)
                    acc[t][u] = __builtin_amdgcn_mfma_f32_16x16x32_bf16(
                        a[t], b[u], acc[t][u], 0, 0, 0);
        }
        __syncthreads();
    }
#pragma unroll
    for (int t = 0; t < 4; ++t) {
#pragma unroll
        for (int r = 0; r < 4; ++r) {
            int grow = row0 + wm + t * 16 + quad * 4 + r;
            if (grow < nrows) {
#pragma unroll
                for (int u = 0; u < 2; ++u) {
                    int col = wn + u * 16 + l15;
                    if (col < 40)
                        Y[(size_t)grow * 40 + col] = acc[t][u][r] + bias[col];
                }
            }
        }
    }
}

// ------- CSR aggregation (bf16 in/out), software-pipelined ------------------
__global__ __launch_bounds__(256) void agg128_kernel(
    const uint32* __restrict__ xwb, const int* __restrict__ row_ptr,
    const int* __restrict__ ssrc, const float* __restrict__ nd,
    uint32* __restrict__ outb, int n) {
    int node = blockIdx.x * 4 + (threadIdx.x >> 6);
    if (node >= n) return;
    int lane = threadIdx.x & 63;
    int beg = row_ptr[node], end = row_ptr[node + 1];
    float x = 0.f, y = 0.f;
    int e = beg;
    int nfull = (end - beg) >> 3;
    if (nfull > 0) {
        int s[8];
        uint32 u[8];
#pragma unroll
        for (int j = 0; j < 8; ++j) s[j] = ssrc[e + j];
#pragma unroll
        for (int j = 0; j < 8; ++j) u[j] = xwb[(size_t)s[j] * 64 + lane];
        e += 8;
        for (int it = 1; it < nfull; ++it, e += 8) {
            int s2[8];
            uint32 u2[8];
#pragma unroll
            for (int j = 0; j < 8; ++j) s2[j] = ssrc[e + j];
#pragma unroll
            for (int j = 0; j < 8; ++j) u2[j] = xwb[(size_t)s2[j] * 64 + lane];
#pragma unroll
            for (int j = 0; j < 8; ++j) {
                float2 v = bf2f2(u[j]);
                x += v.x;
                y += v.y;
            }
#pragma unroll
            for (int j = 0; j < 8; ++j) u[j] = u2[j];
        }
#pragma unroll
        for (int j = 0; j < 8; ++j) {
            float2 v = bf2f2(u[j]);
            x += v.x;
            y += v.y;
        }
    }
    for (; e < end; ++e) {
        float2 v = bf2f2(xwb[(size_t)ssrc[e] * 64 + lane]);
        x += v.x;
        y += v.y;
    }
    float s = nd[node];
    outb[(size_t)node * 64 + lane] =
        (uint32)f2bf(x * s) | ((uint32)f2bf(y * s) << 16);
}

// layer-2 variant: relu(a*x+b)*ns[src] on the fly; bf16 packed output.
__global__ __launch_bounds__(256) void agg128_bn_kernel(
    const uint32* __restrict__ xwb, const int* __restrict__ row_ptr,
    const int* __restrict__ ssrc, const float* __restrict__ nd,
    const float* __restrict__ ns, const float* __restrict__ ab,
    uint32* __restrict__ outb, int n) {
    int node = blockIdx.x * 4 + (threadIdx.x >> 6);
    if (node >= n) return;
    int lane = threadIdx.x & 63;
    float2 a2 = *(const float2*)&ab[lane * 2];
    float2 b2 = *(const float2*)&ab[128 + lane * 2];
    int beg = row_ptr[node], end = row_ptr[node + 1];
    float x = 0.f, y = 0.f;
    int e = beg;
    int nfull = (end - beg) >> 3;
    if (nfull > 0) {
        int s[8];
        uint32 u[8];
        float sc[8];
#pragma unroll
        for (int j = 0; j < 8; ++j) s[j] = ssrc[e + j];
#pragma unroll
        for (int j = 0; j < 8; ++j) {
            u[j] = xwb[(size_t)s[j] * 64 + lane];
            sc[j] = ns[s[j]];
        }
        e += 8;
        for (int it = 1; it < nfull; ++it, e += 8) {
            int s2[8];
            uint32 u2[8];
            float sc2[8];
#pragma unroll
            for (int j = 0; j < 8; ++j) s2[j] = ssrc[e + j];
#pragma unroll
            for (int j = 0; j < 8; ++j) {
                u2[j] = xwb[(size_t)s2[j] * 64 + lane];
                sc2[j] = ns[s2[j]];
            }
#pragma unroll
            for (int j = 0; j < 8; ++j) {
                float2 v = bf2f2(u[j]);
                x += fmaxf(fmaf(v.x, a2.x, b2.x), 0.f) * sc[j];
                y += fmaxf(fmaf(v.y, a2.y, b2.y), 0.f) * sc[j];
            }
#pragma unroll
            for (int j = 0; j < 8; ++j) { u[j] = u2[j]; sc[j] = sc2[j]; }
        }
#pragma unroll
        for (int j = 0; j < 8; ++j) {
            float2 v = bf2f2(u[j]);
            x += fmaxf(fmaf(v.x, a2.x, b2.x), 0.f) * sc[j];
            y += fmaxf(fmaf(v.y, a2.y, b2.y), 0.f) * sc[j];
        }
    }
    for (; e < end; ++e) {
        int s0 = ssrc[e];
        float2 v0 = bf2f2(xwb[(size_t)s0 * 64 + lane]);
        float sc0 = ns[s0];
        x += fmaxf(fmaf(v0.x, a2.x, b2.x), 0.f) * sc0;
        y += fmaxf(fmaf(v0.y, a2.y, b2.y), 0.f) * sc0;
    }
    float s = nd[node];
    outb[(size_t)node * 64 + lane] =
        (uint32)f2bf(x * s) | ((uint32)f2bf(y * s) << 16);
}

// ---------------- batchnorm stats (bf16 input) ----------------

__global__ __launch_bounds__(256) void bn_reduce_kernel(const ushort16* __restrict__ x,
                                                        float* __restrict__ stats, int n) {
    int tid = threadIdx.x;
    int col = tid & 127, half = tid >> 7;
    float s = 0.f, s2 = 0.f;
    for (int r = blockIdx.x * 2 + half; r < n; r += gridDim.x * 2) {
        float v = bf2f(x[(size_t)r * D_H + col]);
        s += v;
        s2 = fmaf(v, v, s2);
    }
    __shared__ float red[256];
    red[tid] = s;
    __syncthreads();
    if (half == 0) atomicAdd(&stats[col], s + red[tid + 128]);
    __syncthreads();
    red[tid] = s2;
    __syncthreads();
    if (half == 0) atomicAdd(&stats[128 + col], s2 + red[tid + 128]);
}

__global__ void bn_finalize_kernel(const float* __restrict__ stats,
                                   const float* __restrict__ g,
                                   const float* __restrict__ beta,
                                   float* __restrict__ ab, float inv_n) {
    int c = threadIdx.x;  // 128 threads
    float mean = stats[c] * inv_n;
    float var = stats[128 + c] * inv_n - mean * mean;
    float a = rsqrtf(var + 1e-5f) * g[c];
    ab[c] = a;
    ab[128 + c] = beta[c] - mean * a;
}

// ---------------- launch ----------------

extern "C" void kernel_launch(void* const* d_in, const int* in_sizes, int n_in,
                              void* d_out, int out_size, void* d_ws, size_t ws_size,
                              hipStream_t stream) {
    const float* feat = (const float*)d_in[0];
    const int* edge_src = (const int*)d_in[1];
    const int* edge_dst = (const int*)d_in[2];
    const float* W0 = (const float*)d_in[3];
    const float* W1 = (const float*)d_in[4];
    const float* W2 = (const float*)d_in[5];
    const float* b2 = (const float*)d_in[6];
    const float* g0 = (const float*)d_in[7];
    const float* beta0 = (const float*)d_in[8];
    const float* g1 = (const float*)d_in[9];
    const float* beta1 = (const float*)d_in[10];
    float* out = (float*)d_out;

    const int N = in_sizes[0] / D_H;   // 100000
    const int E = in_sizes[1];         // 1600000
    const int nbuck = (N + 255) >> 8;  // 391

    char* p = (char*)d_ws;
    auto alloc = [&](size_t bytes) {
        char* r = p;
        p += (bytes + 255) & ~(size_t)255;
        return r;
    };
    uint32* Ab = (uint32*)alloc((size_t)N * D_H * 2);   // bf16 A (packed pairs)
    uint32* Bb = (uint32*)alloc((size_t)N * D_H * 2);   // bf16 B (packed pairs)
    float* ns = (float*)alloc((size_t)N * 4);
    float* nd = (float*)alloc((size_t)N * 4);
    int* row_ptr = (int*)alloc((size_t)(N + 1) * 4);
    int* ssrc = (int*)alloc((size_t)E * 4);
    uint32* packed = (uint32*)alloc((size_t)E * 4);
    uint32* sp = (uint32*)alloc((size_t)E * 4);
    int* M = (int*)alloc((size_t)nbuck * 128 * 4);
    int* Mx = (int*)alloc(((size_t)nbuck * 128 + 4) * 4);
    int* M2 = (int*)alloc((size_t)nbuck * 128 * 4);
    int* Mx2 = (int*)alloc(((size_t)nbuck * 128 + 4) * 4);
    int* bsum = (int*)alloc(256 * 4);
    float* stats0 = (float*)alloc(256 * 4);
    float* stats1 = (float*)alloc(256 * 4);
    float* ab0 = (float*)alloc(256 * 4);
    float* ab1 = (float*)alloc(256 * 4);
    ushort16* Wt0 = (ushort16*)alloc(128 * 128 * 2);
    ushort16* Wt1 = (ushort16*)alloc(128 * 128 * 2);
    ushort16* Wt2 = (ushort16*)alloc(64 * 128 * 2);
    (void)ws_size;

    hipMemsetAsync(stats0, 0, 256 * 4, stream);
    hipMemsetAsync(stats1, 0, 256 * 4, stream);

    const int ggrid = (N + 127) / 128;
    const int agrid = (N + 3) / 4;
    const int nM = nbuck * 128;                            // 50048
    const int sgridM = (nM + SCAN_CHUNK - 1) / SCAN_CHUNK; // 49

    prepw_kernel<<<96, 256, 0, stream>>>(W0, W1, W2, Wt0, Wt1, Wt2);

    bucket_count2_kernel<<<128, 256, 0, stream>>>(edge_src, edge_dst, M, M2, E, nbuck);
    scan1_kernel<<<sgridM, 256, 0, stream>>>(M, bsum, nM);
    scan3_kernel<<<sgridM, 256, 0, stream>>>(M, bsum, Mx, sgridM, nM);
    scan1_kernel<<<sgridM, 256, 0, stream>>>(M2, bsum, nM);
    scan3_kernel<<<sgridM, 256, 0, stream>>>(M2, bsum, Mx2, sgridM, nM);
    bucket_scatter2_kernel<<<128, 256, 0, stream>>>(edge_src, edge_dst, Mx, Mx2,
                                                    packed, sp, E, nbuck);
    csr_kernel<<<nbuck, 256, 0, stream>>>(packed, Mx, row_ptr, nd, ssrc, E, N, nbuck);
    src_count_kernel<<<nbuck, 256, 0, stream>>>(sp, Mx2, ns, E, N, nbuck);

    // layer 0: mfma gemm(feat*ns @ W0) -> Bb; agg -> Ab (bf16); stats
    gemm_mfma_kernel<false, false><<<ggrid, 256, 0, stream>>>(
        feat, Wt0, ns, nullptr, (ushort16*)Bb, N);
    agg128_kernel<<<agrid, 256, 0, stream>>>(Bb, row_ptr, ssrc, nd, Ab, N);
    bn_reduce_kernel<<<512, 256, 0, stream>>>((const ushort16*)Ab, stats0, N);
    bn_finalize_kernel<<<1, 128, 0, stream>>>(stats0, g0, beta0, ab0, 1.0f / N);

    // layer 1: mfma gemm(relu(bn0(Ab))*ns @ W1) -> Bb; agg -> Ab; stats
    gemm_mfma_kernel<true, true><<<ggrid, 256, 0, stream>>>(
        Ab, Wt1, ns, ab0, (ushort16*)Bb, N);
    agg128_kernel<<<agrid, 256, 0, stream>>>(Bb, row_ptr, ssrc, nd, Ab, N);
    bn_reduce_kernel<<<512, 256, 0, stream>>>((const ushort16*)Ab, stats1, N);
    bn_finalize_kernel<<<1, 128, 0, stream>>>(stats1, g1, beta1, ab1, 1.0f / N);

    // layer 2: agg(relu(bn1(Ab))*ns) -> Bb (bf16); mfma final -> out
    agg128_bn_kernel<<<agrid, 256, 0, stream>>>(Ab, row_ptr, ssrc, nd, ns, ab1, Bb, N);
    gemm_final_mfma_kernel<<<ggrid, 256, 0, stream>>>(Bb, Wt2, b2, out, N);
}

// Round 11
// 495.733 us; speedup vs baseline: 2.5006x; 1.1424x over previous
//
#include <hip/hip_runtime.h>
#include <hip/hip_bf16.h>

// 3-layer GCN. R11: (1) agg pipelining reverted (R10 regressed: VGPR 28->36,
// occ 68->59, reg-move tail); bf16 agg_bn output kept. (2) bn_finalize deleted
// — consumers derive a/b from raw stats (LDS in gemm, per-lane in agg_bn).
// (3) launch fusion: scans 4->2, csr+src_count->1, memsets->1. (4) bn_reduce
// vectorized (uint4, 8 cols/thread, LDS reduce).

#define D_H 128
#define SCAN_CHUNK 1024

typedef unsigned int uint32;
typedef unsigned short ushort16;
typedef __attribute__((ext_vector_type(8))) short short8v;   // 8 bf16 = 4 VGPR
typedef __attribute__((ext_vector_type(4))) float float4v;   // MFMA acc

__device__ __forceinline__ ushort16 f2bf(float f) {
    union { float f; uint32 u; } v;
    v.f = f;
    uint32 u = v.u;
    return (ushort16)((u + 0x7fffu + ((u >> 16) & 1u)) >> 16);  // RNE
}
__device__ __forceinline__ float2 bf2f2(uint32 u) {
    union { uint32 i; float f; } a, b;
    a.i = u << 16;
    b.i = u & 0xffff0000u;
    return make_float2(a.f, b.f);
}

// ------- fused bucket counting (dst -> M, src -> M2), one edge pass ---------
__global__ __launch_bounds__(256) void bucket_count2_kernel(
    const int* __restrict__ src, const int* __restrict__ dst,
    int* __restrict__ M, int* __restrict__ M2, int E, int nbuck) {
    __shared__ int h[512], h2[512];
    for (int i = threadIdx.x; i < nbuck; i += 256) { h[i] = 0; h2[i] = 0; }
    __syncthreads();
    int j = blockIdx.x;  // 128 blocks
    int epb = (E + 127) >> 7;
    int estart = j * epb, eend = min(estart + epb, E);
    for (int e = estart + threadIdx.x; e < eend; e += 256) {
        atomicAdd(&h[dst[e] >> 8], 1);
        atomicAdd(&h2[src[e] >> 8], 1);
    }
    __syncthreads();
    for (int b = threadIdx.x; b < nbuck; b += 256) {
        M[(size_t)b * 128 + j] = h[b];
        M2[(size_t)b * 128 + j] = h2[b];
    }
}

// ------- fused scans: blocks [0,g) handle M, [g,2g) handle M2 ---------------
__global__ __launch_bounds__(256) void scan1f_kernel(
    const int* __restrict__ M, const int* __restrict__ M2,
    int* __restrict__ bsum, int g, int n) {
    int half = (blockIdx.x >= g) ? 1 : 0;
    int blk = blockIdx.x - half * g;
    const int* deg = half ? M2 : M;
    int tid = threadIdx.x;
    int base = blk * SCAN_CHUNK + tid * 4;
    int4 v = make_int4(0, 0, 0, 0);
    if (base + 3 < n) {
        v = *(const int4*)(deg + base);
    } else {
        if (base + 0 < n) v.x = deg[base + 0];
        if (base + 1 < n) v.y = deg[base + 1];
        if (base + 2 < n) v.z = deg[base + 2];
        if (base + 3 < n) v.w = deg[base + 3];
    }
    int s = v.x + v.y + v.z + v.w;
    __shared__ int red[256];
    red[tid] = s;
    __syncthreads();
#pragma unroll
    for (int off = 128; off > 0; off >>= 1) {
        if (tid < off) red[tid] += red[tid + off];
        __syncthreads();
    }
    if (tid == 0) bsum[blockIdx.x] = red[0];
}

__global__ __launch_bounds__(256) void scan3f_kernel(
    const int* __restrict__ M, const int* __restrict__ M2,
    const int* __restrict__ bsum, int* __restrict__ Mx, int* __restrict__ Mx2,
    int g, int n) {
    int half = (blockIdx.x >= g) ? 1 : 0;
    int blk = blockIdx.x - half * g;
    const int* deg = half ? M2 : M;
    int* outp = half ? Mx2 : Mx;
    int tid = threadIdx.x;
    int base = blk * SCAN_CHUNK + tid * 4;
    int4 v = make_int4(0, 0, 0, 0);
    if (base + 3 < n) {
        v = *(const int4*)(deg + base);
    } else {
        if (base + 0 < n) v.x = deg[base + 0];
        if (base + 1 < n) v.y = deg[base + 1];
        if (base + 2 < n) v.z = deg[base + 2];
        if (base + 3 < n) v.w = deg[base + 3];
    }
    int s = v.x + v.y + v.z + v.w;

    __shared__ int bs[128];
    if (tid < 128) bs[tid] = (tid < g) ? bsum[half * g + tid] : 0;
    __syncthreads();
#pragma unroll
    for (int off = 1; off < 128; off <<= 1) {
        int t = (tid < 128 && tid >= off) ? bs[tid - off] : 0;
        __syncthreads();
        if (tid < 128) bs[tid] += t;
        __syncthreads();
    }
    int blockbase = (blk == 0) ? 0 : bs[blk - 1];
    int total = bs[g - 1];

    __shared__ int sc[256];
    sc[tid] = s;
    __syncthreads();
#pragma unroll
    for (int off = 1; off < 256; off <<= 1) {
        int t = (tid >= off) ? sc[tid - off] : 0;
        __syncthreads();
        sc[tid] += t;
        __syncthreads();
    }
    int excl = sc[tid] - s + blockbase;
    int p0 = excl;
    int p1 = p0 + v.x;
    int p2 = p1 + v.y;
    int p3 = p2 + v.z;
    if (base + 3 < n) {
        *(int4*)(outp + base) = make_int4(p0, p1, p2, p3);
    } else {
        if (base + 0 < n) outp[base + 0] = p0;
        if (base + 1 < n) outp[base + 1] = p1;
        if (base + 2 < n) outp[base + 2] = p2;
    }
    if (blk == g - 1 && tid == 0) outp[n] = total;
}

// ------- fused bucket scatter: dst-packed + src-raw, one edge pass ----------
__global__ __launch_bounds__(256) void bucket_scatter2_kernel(
    const int* __restrict__ src, const int* __restrict__ dst,
    const int* __restrict__ Mx, const int* __restrict__ Mx2,
    uint32* __restrict__ packed, uint32* __restrict__ sp, int E, int nbuck) {
    __shared__ int cb1[512], c1[512], cb2[512], c2[512];
    int j = blockIdx.x;
    for (int i = threadIdx.x; i < nbuck; i += 256) {
        cb1[i] = Mx[(size_t)i * 128 + j];
        c1[i] = 0;
        cb2[i] = Mx2[(size_t)i * 128 + j];
        c2[i] = 0;
    }
    __syncthreads();
    int epb = (E + 127) >> 7;
    int estart = j * epb, eend = min(estart + epb, E);
    for (int e = estart + threadIdx.x; e < eend; e += 256) {
        int s = src[e], d = dst[e];
        int b = d >> 8;
        int r = atomicAdd(&c1[b], 1);
        packed[cb1[b] + r] = ((uint32)s << 8) | (uint32)(d & 255);
        int b2 = s >> 8;
        int r2 = atomicAdd(&c2[b2], 1);
        sp[cb2[b2] + r2] = (uint32)s;
    }
}

// ---- fused per-bucket CSR finalize (row_ptr/nd/ssrc) + src count (ns) ------
__global__ __launch_bounds__(256) void csr_src_kernel(
    const uint32* __restrict__ packed, const int* __restrict__ Mx,
    const uint32* __restrict__ sp, const int* __restrict__ Mx2,
    int* __restrict__ row_ptr, float* __restrict__ nd, float* __restrict__ ns,
    int* __restrict__ ssrc, int E, int N, int nbuck) {
    __shared__ int cnt[256], pos0[256], cur[256], sc[256], cnt2[256];
    int b = blockIdx.x, tid = threadIdx.x;
    int lo = Mx[(size_t)b * 128];
    int hi = (b == nbuck - 1) ? E : Mx[(size_t)(b + 1) * 128];
    int lo2 = Mx2[(size_t)b * 128];
    int hi2 = (b == nbuck - 1) ? E : Mx2[(size_t)(b + 1) * 128];
    cnt[tid] = 0;
    cur[tid] = 0;
    cnt2[tid] = 0;
    __syncthreads();
    for (int e = lo + tid; e < hi; e += 256)
        atomicAdd(&cnt[packed[e] & 255u], 1);
    for (int e = lo2 + tid; e < hi2; e += 256)
        atomicAdd(&cnt2[sp[e] & 255u], 1);
    __syncthreads();
    int c = cnt[tid];
    sc[tid] = c;
    __syncthreads();
#pragma unroll
    for (int off = 1; off < 256; off <<= 1) {
        int t = (tid >= off) ? sc[tid - off] : 0;
        __syncthreads();
        sc[tid] += t;
        __syncthreads();
    }
    int excl = sc[tid] - c;
    pos0[tid] = lo + excl;
    int node = b * 256 + tid;
    if (node < N) {
        row_ptr[node] = lo + excl;
        nd[node] = rsqrtf((float)max(c, 1));
        ns[node] = rsqrtf((float)max(cnt2[tid], 1));
    }
    if (b == 0 && tid == 0) row_ptr[N] = E;
    __syncthreads();
    for (int e = lo + tid; e < hi; e += 256) {
        uint32 p = packed[e];
        int local = (int)(p & 255u);
        int r = atomicAdd(&cur[local], 1);
        ssrc[pos0[local] + r] = (int)(p >> 8);
    }
}

// --- weight prep: Wt0/Wt1 [128][128], Wt2 [64][128] (rows 40..63 zero) ------
__global__ void prepw_kernel(const float* __restrict__ W0, const float* __restrict__ W1,
                             const float* __restrict__ W2,
                             ushort16* __restrict__ Wt0, ushort16* __restrict__ Wt1,
                             ushort16* __restrict__ Wt2) {
    int idx = blockIdx.x * 256 + threadIdx.x;  // 24576
    if (idx < 16384) {
        int n = idx & 127, k = idx >> 7;
        Wt0[n * 128 + k] = f2bf(W0[k * 128 + n]);
        Wt1[n * 128 + k] = f2bf(W1[k * 128 + n]);
    } else {
        int i2 = idx - 16384;  // < 8192
        int n = i2 >> 7, k = i2 & 127;
        Wt2[n * 128 + k] = (n < 40) ? f2bf(W2[k * 40 + n]) : (ushort16)0;
    }
}

// ---------------- MFMA GEMM (layers 0/1) ----------------
// FUSE_BN: a/b derived from raw stats (no bn_finalize kernel).
template <bool XBF16, bool FUSE_BN>
__global__ __launch_bounds__(256) void gemm_mfma_kernel(
    const void* __restrict__ Xv, const ushort16* __restrict__ Wt,
    const float* __restrict__ ns, const float* __restrict__ stats,
    const float* __restrict__ gamma, const float* __restrict__ beta,
    float invn, ushort16* __restrict__ Yb, int nrows) {
    constexpr int LDK = 72;
    __shared__ short As[128 * LDK];
    __shared__ short Ws[128 * LDK];
    __shared__ float abl[256];
    int tid = threadIdx.x;
    int row0 = blockIdx.x * 128;
    int wave = tid >> 6, lane = tid & 63;
    int wm = (wave >> 1) * 64, wn = (wave & 1) * 64;
    int l15 = lane & 15, quad = lane >> 4;
    float4v acc[4][4] = {{}};

    if (FUSE_BN) {
        if (tid < 128) {
            float mean = stats[tid] * invn;
            float var = stats[128 + tid] * invn - mean * mean;
            float a = rsqrtf(var + 1e-5f) * gamma[tid];
            abl[tid] = a;
            abl[128 + tid] = beta[tid] - mean * a;
        }
        __syncthreads();
    }

#pragma unroll
    for (int p = 0; p < 2; ++p) {
        int k0 = p * 64;
        {
            int srow = tid >> 1;
            int half = (tid & 1) * 32;
            int grow = row0 + srow;
            bool ok = grow < nrows;
            float sc = ok ? ns[grow] : 0.f;
            uint32 outu[16];
            if (XBF16) {
                const uint4* xp = (const uint4*)((const uint32*)Xv +
                                                 (size_t)grow * 64 + ((k0 + half) >> 1));
                uint4 u4[4];
#pragma unroll
                for (int q = 0; q < 4; ++q)
                    u4[q] = ok ? xp[q] : make_uint4(0, 0, 0, 0);
                const uint32* uu = (const uint32*)u4;
#pragma unroll
                for (int j = 0; j < 16; ++j) {
                    float2 f = bf2f2(uu[j]);
                    if (FUSE_BN) {
                        int c = k0 + half + j * 2;
                        f.x = fmaxf(fmaf(f.x, abl[c], abl[128 + c]), 0.f);
                        f.y = fmaxf(fmaf(f.y, abl[c + 1], abl[128 + c + 1]), 0.f);
                    }
                    outu[j] = (uint32)f2bf(f.x * sc) | ((uint32)f2bf(f.y * sc) << 16);
                }
            } else {
                const float4* xp = (const float4*)((const float*)Xv +
                                                   (size_t)grow * 128 + k0 + half);
                float4 f4[8];
#pragma unroll
                for (int q = 0; q < 8; ++q)
                    f4[q] = ok ? xp[q] : make_float4(0.f, 0.f, 0.f, 0.f);
                const float* ff = (const float*)f4;
#pragma unroll
                for (int j = 0; j < 16; ++j) {
                    float fx = ff[2 * j], fy = ff[2 * j + 1];
                    outu[j] = (uint32)f2bf(fx * sc) | ((uint32)f2bf(fy * sc) << 16);
                }
            }
            uint4* dstA = (uint4*)&As[srow * LDK + half];
#pragma unroll
            for (int q = 0; q < 4; ++q) dstA[q] = ((uint4*)outu)[q];
            const uint4* wp = (const uint4*)((const uint32*)Wt +
                                             srow * 64 + ((k0 + half) >> 1));
            uint4* dstW = (uint4*)&Ws[srow * LDK + half];
#pragma unroll
            for (int q = 0; q < 4; ++q) dstW[q] = wp[q];
        }
        __syncthreads();
#pragma unroll
        for (int ks = 0; ks < 2; ++ks) {
            int koff = ks * 32 + quad * 8;
            short8v a[4], b[4];
#pragma unroll
            for (int t = 0; t < 4; ++t)
                a[t] = *(const short8v*)&As[(wm + t * 16 + l15) * LDK + koff];
#pragma unroll
            for (int u = 0; u < 4; ++u)
                b[u] = *(const short8v*)&Ws[(wn + u * 16 + l15) * LDK + koff];
#pragma unroll
            for (int t = 0; t < 4; ++t)
#pragma unroll
                for (int u = 0; u < 4; ++u)
                    acc[t][u] = __builtin_amdgcn_mfma_f32_16x16x32_bf16(
                        a[t], b[u], acc[t][u], 0, 0, 0);
        }
        __syncthreads();
    }
#pragma unroll
    for (int t = 0; t < 4; ++t) {
#pragma unroll
        for (int r = 0; r < 4; ++r) {
            int grow = row0 + wm + t * 16 + quad * 4 + r;
            if (grow < nrows) {
#pragma unroll
                for (int u = 0; u < 4; ++u)
                    Yb[(size_t)grow * 128 + wn + u * 16 + l15] = f2bf(acc[t][u][r]);
            }
        }
    }
}

// ------- final MFMA GEMM: out = Xb(bf16) @ W2 + b2, 128->40 (64 padded) -----
__global__ __launch_bounds__(256) void gemm_final_mfma_kernel(
    const uint32* __restrict__ Xb, const ushort16* __restrict__ Wt2,
    const float* __restrict__ bias, float* __restrict__ Y, int nrows) {
    constexpr int LDK = 72;
    __shared__ short As[128 * LDK];
    __shared__ short Ws[64 * LDK];
    int tid = threadIdx.x;
    int row0 = blockIdx.x * 128;
    int wave = tid >> 6, lane = tid & 63;
    int wm = (wave >> 1) * 64, wn = (wave & 1) * 32;
    int l15 = lane & 15, quad = lane >> 4;
    float4v acc[4][2] = {{}};

#pragma unroll
    for (int p = 0; p < 2; ++p) {
        int k0 = p * 64;
        {
            int srow = tid >> 1;
            int half = (tid & 1) * 32;
            int grow = row0 + srow;
            bool ok = grow < nrows;
            const uint4* xp = (const uint4*)(Xb + (size_t)grow * 64 + ((k0 + half) >> 1));
            uint4 u4[4];
#pragma unroll
            for (int q = 0; q < 4; ++q)
                u4[q] = ok ? xp[q] : make_uint4(0, 0, 0, 0);
            uint4* dstA = (uint4*)&As[srow * LDK + half];
#pragma unroll
            for (int q = 0; q < 4; ++q) dstA[q] = u4[q];
        }
        {
            int srow = tid >> 2;           // 64 rows
            int off = (tid & 3) * 16;      // 16 shorts each
            const uint4* wp = (const uint4*)((const uint32*)Wt2 +
                                             srow * 64 + ((k0 + off) >> 1));
            uint4* dw = (uint4*)&Ws[srow * LDK + off];
            dw[0] = wp[0];
            dw[1] = wp[1];
        }
        __syncthreads();
#pragma unroll
        for (int ks = 0; ks < 2; ++ks) {
            int koff = ks * 32 + quad * 8;
            short8v a[4], b[2];
#pragma unroll
            for (int t = 0; t < 4; ++t)
                a[t] = *(const short8v*)&As[(wm + t * 16 + l15) * LDK + koff];
#pragma unroll
            for (int u = 0; u < 2; ++u)
                b[u] = *(const short8v*)&Ws[(wn + u * 16 + l15) * LDK + koff];
#pragma unroll
            for (int t = 0; t < 4; ++t)
#pragma unroll
                for (int u = 0; u < 2; ++u)
                    acc[t][u] = __builtin_amdgcn_mfma_f32_16x16x32_bf16(
                        a[t], b[u], acc[t][u], 0, 0, 0);
        }
        __syncthreads();
    }
#pragma unroll
    for (int t = 0; t < 4; ++t) {
#pragma unroll
        for (int r = 0; r < 4; ++r) {
            int grow = row0 + wm + t * 16 + quad * 4 + r;
            if (grow < nrows) {
#pragma unroll
                for (int u = 0; u < 2; ++u) {
                    int col = wn + u * 16 + l15;
                    if (col < 40)
                        Y[(size_t)grow * 40 + col] = acc[t][u][r] + bias[col];
                }
            }
        }
    }
}

// ------- CSR aggregation (bf16 in/out), simple 8-batch (R9 form) ------------
__global__ __launch_bounds__(256) void agg128_kernel(
    const uint32* __restrict__ xwb, const int* __restrict__ row_ptr,
    const int* __restrict__ ssrc, const float* __restrict__ nd,
    uint32* __restrict__ outb, int n) {
    int node = blockIdx.x * 4 + (threadIdx.x >> 6);
    if (node >= n) return;
    int lane = threadIdx.x & 63;
    int beg = row_ptr[node], end = row_ptr[node + 1];
    float x = 0.f, y = 0.f;
    int e = beg;
    for (; e + 8 <= end; e += 8) {
        int s[8];
#pragma unroll
        for (int j = 0; j < 8; ++j) s[j] = ssrc[e + j];
        uint32 u[8];
#pragma unroll
        for (int j = 0; j < 8; ++j) u[j] = xwb[(size_t)s[j] * 64 + lane];
#pragma unroll
        for (int j = 0; j < 8; ++j) {
            float2 v = bf2f2(u[j]);
            x += v.x;
            y += v.y;
        }
    }
    for (; e + 2 <= end; e += 2) {
        uint32 u0 = xwb[(size_t)ssrc[e] * 64 + lane];
        uint32 u1 = xwb[(size_t)ssrc[e + 1] * 64 + lane];
        float2 v0 = bf2f2(u0), v1 = bf2f2(u1);
        x += v0.x + v1.x;
        y += v0.y + v1.y;
    }
    if (e < end) {
        float2 v0 = bf2f2(xwb[(size_t)ssrc[e] * 64 + lane]);
        x += v0.x;
        y += v0.y;
    }
    float s = nd[node];
    outb[(size_t)node * 64 + lane] =
        (uint32)f2bf(x * s) | ((uint32)f2bf(y * s) << 16);
}

// layer-2 variant: relu(a*x+b)*ns[src]; a/b derived per-lane from raw stats.
__global__ __launch_bounds__(256) void agg128_bn_kernel(
    const uint32* __restrict__ xwb, const int* __restrict__ row_ptr,
    const int* __restrict__ ssrc, const float* __restrict__ nd,
    const float* __restrict__ ns, const float* __restrict__ stats,
    const float* __restrict__ gamma, const float* __restrict__ beta,
    float invn, uint32* __restrict__ outb, int n) {
    int node = blockIdx.x * 4 + (threadIdx.x >> 6);
    if (node >= n) return;
    int lane = threadIdx.x & 63;
    int c = lane * 2;
    float m0 = stats[c] * invn, m1 = stats[c + 1] * invn;
    float v0_ = stats[128 + c] * invn - m0 * m0;
    float v1_ = stats[128 + c + 1] * invn - m1 * m1;
    float a0 = rsqrtf(v0_ + 1e-5f) * gamma[c];
    float a1 = rsqrtf(v1_ + 1e-5f) * gamma[c + 1];
    float2 a2 = make_float2(a0, a1);
    float2 b2 = make_float2(beta[c] - m0 * a0, beta[c + 1] - m1 * a1);
    int beg = row_ptr[node], end = row_ptr[node + 1];
    float x = 0.f, y = 0.f;
    int e = beg;
    for (; e + 8 <= end; e += 8) {
        int s[8];
#pragma unroll
        for (int j = 0; j < 8; ++j) s[j] = ssrc[e + j];
        uint32 u[8];
        float sc[8];
#pragma unroll
        for (int j = 0; j < 8; ++j) {
            u[j] = xwb[(size_t)s[j] * 64 + lane];
            sc[j] = ns[s[j]];
        }
#pragma unroll
        for (int j = 0; j < 8; ++j) {
            float2 v = bf2f2(u[j]);
            x += fmaxf(fmaf(v.x, a2.x, b2.x), 0.f) * sc[j];
            y += fmaxf(fmaf(v.y, a2.y, b2.y), 0.f) * sc[j];
        }
    }
    for (; e < end; ++e) {
        int s0 = ssrc[e];
        float2 v0 = bf2f2(xwb[(size_t)s0 * 64 + lane]);
        float sc0 = ns[s0];
        x += fmaxf(fmaf(v0.x, a2.x, b2.x), 0.f) * sc0;
        y += fmaxf(fmaf(v0.y, a2.y, b2.y), 0.f) * sc0;
    }
    float s = nd[node];
    outb[(size_t)node * 64 + lane] =
        (uint32)f2bf(x * s) | ((uint32)f2bf(y * s) << 16);
}

// -------- batchnorm stats (bf16 input, uint4 loads, 8 cols/thread) ----------
__global__ __launch_bounds__(256) void bn_reduce_kernel(const uint4* __restrict__ x4,
                                                        float* __restrict__ stats, int n) {
    int tid = threadIdx.x;
    int ctile = tid & 15;    // 16 col-tiles of 8 cols
    int rgrp = tid >> 4;     // 16 row groups
    float s[8] = {}, s2[8] = {};
    for (int r = blockIdx.x * 16 + rgrp; r < n; r += gridDim.x * 16) {
        uint4 u = x4[(size_t)r * 16 + ctile];
        uint32 uu[4] = {u.x, u.y, u.z, u.w};
#pragma unroll
        for (int q = 0; q < 4; ++q) {
            float2 v = bf2f2(uu[q]);
            s[q * 2] += v.x;
            s[q * 2 + 1] += v.y;
            s2[q * 2] = fmaf(v.x, v.x, s2[q * 2]);
            s2[q * 2 + 1] = fmaf(v.y, v.y, s2[q * 2 + 1]);
        }
    }
    __shared__ float ls[128], ls2[128];
    if (tid < 128) { ls[tid] = 0.f; ls2[tid] = 0.f; }
    __syncthreads();
#pragma unroll
    for (int j = 0; j < 8; ++j) {
        atomicAdd(&ls[ctile * 8 + j], s[j]);
        atomicAdd(&ls2[ctile * 8 + j], s2[j]);
    }
    __syncthreads();
    if (tid < 128) {
        atomicAdd(&stats[tid], ls[tid]);
        atomicAdd(&stats[128 + tid], ls2[tid]);
    }
}

// ---------------- launch ----------------

extern "C" void kernel_launch(void* const* d_in, const int* in_sizes, int n_in,
                              void* d_out, int out_size, void* d_ws, size_t ws_size,
                              hipStream_t stream) {
    const float* feat = (const float*)d_in[0];
    const int* edge_src = (const int*)d_in[1];
    const int* edge_dst = (const int*)d_in[2];
    const float* W0 = (const float*)d_in[3];
    const float* W1 = (const float*)d_in[4];
    const float* W2 = (const float*)d_in[5];
    const float* b2 = (const float*)d_in[6];
    const float* g0 = (const float*)d_in[7];
    const float* beta0 = (const float*)d_in[8];
    const float* g1 = (const float*)d_in[9];
    const float* beta1 = (const float*)d_in[10];
    float* out = (float*)d_out;

    const int N = in_sizes[0] / D_H;   // 100000
    const int E = in_sizes[1];         // 1600000
    const int nbuck = (N + 255) >> 8;  // 391
    const float invN = 1.0f / (float)N;

    char* p = (char*)d_ws;
    auto alloc = [&](size_t bytes) {
        char* r = p;
        p += (bytes + 255) & ~(size_t)255;
        return r;
    };
    uint32* Ab = (uint32*)alloc((size_t)N * D_H * 2);   // bf16 A (packed pairs)
    uint32* Bb = (uint32*)alloc((size_t)N * D_H * 2);   // bf16 B (packed pairs)
    float* ns = (float*)alloc((size_t)N * 4);
    float* nd = (float*)alloc((size_t)N * 4);
    int* row_ptr = (int*)alloc((size_t)(N + 1) * 4);
    int* ssrc = (int*)alloc((size_t)E * 4);
    uint32* packed = (uint32*)alloc((size_t)E * 4);
    uint32* sp = (uint32*)alloc((size_t)E * 4);
    int* M = (int*)alloc((size_t)nbuck * 128 * 4);
    int* Mx = (int*)alloc(((size_t)nbuck * 128 + 4) * 4);
    int* M2 = (int*)alloc((size_t)nbuck * 128 * 4);
    int* Mx2 = (int*)alloc(((size_t)nbuck * 128 + 4) * 4);
    int* bsum = (int*)alloc(256 * 4);
    float* stats0 = (float*)alloc(256 * 4);   // contiguous with stats1 (256B granules)
    float* stats1 = (float*)alloc(256 * 4);
    ushort16* Wt0 = (ushort16*)alloc(128 * 128 * 2);
    ushort16* Wt1 = (ushort16*)alloc(128 * 128 * 2);
    ushort16* Wt2 = (ushort16*)alloc(64 * 128 * 2);
    (void)ws_size;

    hipMemsetAsync(stats0, 0, 2048, stream);  // stats0 + stats1 (adjacent)

    const int ggrid = (N + 127) / 128;
    const int agrid = (N + 3) / 4;
    const int nM = nbuck * 128;                            // 50048
    const int sgridM = (nM + SCAN_CHUNK - 1) / SCAN_CHUNK; // 49

    prepw_kernel<<<96, 256, 0, stream>>>(W0, W1, W2, Wt0, Wt1, Wt2);

    bucket_count2_kernel<<<128, 256, 0, stream>>>(edge_src, edge_dst, M, M2, E, nbuck);
    scan1f_kernel<<<2 * sgridM, 256, 0, stream>>>(M, M2, bsum, sgridM, nM);
    scan3f_kernel<<<2 * sgridM, 256, 0, stream>>>(M, M2, bsum, Mx, Mx2, sgridM, nM);
    bucket_scatter2_kernel<<<128, 256, 0, stream>>>(edge_src, edge_dst, Mx, Mx2,
                                                    packed, sp, E, nbuck);
    csr_src_kernel<<<nbuck, 256, 0, stream>>>(packed, Mx, sp, Mx2, row_ptr, nd, ns,
                                              ssrc, E, N, nbuck);

    // layer 0
    gemm_mfma_kernel<false, false><<<ggrid, 256, 0, stream>>>(
        feat, Wt0, ns, nullptr, nullptr, nullptr, invN, (ushort16*)Bb, N);
    agg128_kernel<<<agrid, 256, 0, stream>>>(Bb, row_ptr, ssrc, nd, Ab, N);
    bn_reduce_kernel<<<512, 256, 0, stream>>>((const uint4*)Ab, stats0, N);

    // layer 1
    gemm_mfma_kernel<true, true><<<ggrid, 256, 0, stream>>>(
        Ab, Wt1, ns, stats0, g0, beta0, invN, (ushort16*)Bb, N);
    agg128_kernel<<<agrid, 256, 0, stream>>>(Bb, row_ptr, ssrc, nd, Ab, N);
    bn_reduce_kernel<<<512, 256, 0, stream>>>((const uint4*)Ab, stats1, N);

    // layer 2: agg(relu(bn1(Ab))*ns) -> Bb (bf16); mfma final -> out
    agg128_bn_kernel<<<agrid, 256, 0, stream>>>(Ab, row_ptr, ssrc, nd, ns,
                                                stats1, g1, beta1, invN, Bb, N);
    gemm_final_mfma_kernel<<<ggrid, 256, 0, stream>>>(Bb, Wt2, b2, out, N);
}

// Round 12
// 468.643 us; speedup vs baseline: 2.6452x; 1.0578x over previous
//
#include <hip/hip_runtime.h>
#include <hip/hip_bf16.h>

// 3-layer GCN. R12: layer-2 re-reordered to project-then-aggregate:
// gemm_mfma2 (BN+relu+ns folded into A-staging, 128->64-padded bf16 out) then
// agg40 (gathers 128B rows — 2x less than 256B — writes d_out with nd+bias).
// Deletes agg128_bn (85us: 410MB gather + per-edge BN VALU) + gemm_final_mfma.

#define D_H 128
#define SCAN_CHUNK 1024

typedef unsigned int uint32;
typedef unsigned short ushort16;
typedef __attribute__((ext_vector_type(8))) short short8v;   // 8 bf16 = 4 VGPR
typedef __attribute__((ext_vector_type(4))) float float4v;   // MFMA acc

__device__ __forceinline__ ushort16 f2bf(float f) {
    union { float f; uint32 u; } v;
    v.f = f;
    uint32 u = v.u;
    return (ushort16)((u + 0x7fffu + ((u >> 16) & 1u)) >> 16);  // RNE
}
__device__ __forceinline__ float2 bf2f2(uint32 u) {
    union { uint32 i; float f; } a, b;
    a.i = u << 16;
    b.i = u & 0xffff0000u;
    return make_float2(a.f, b.f);
}

// ------- fused bucket counting (dst -> M, src -> M2), one edge pass ---------
__global__ __launch_bounds__(256) void bucket_count2_kernel(
    const int* __restrict__ src, const int* __restrict__ dst,
    int* __restrict__ M, int* __restrict__ M2, int E, int nbuck) {
    __shared__ int h[512], h2[512];
    for (int i = threadIdx.x; i < nbuck; i += 256) { h[i] = 0; h2[i] = 0; }
    __syncthreads();
    int j = blockIdx.x;  // 128 blocks
    int epb = (E + 127) >> 7;
    int estart = j * epb, eend = min(estart + epb, E);
    for (int e = estart + threadIdx.x; e < eend; e += 256) {
        atomicAdd(&h[dst[e] >> 8], 1);
        atomicAdd(&h2[src[e] >> 8], 1);
    }
    __syncthreads();
    for (int b = threadIdx.x; b < nbuck; b += 256) {
        M[(size_t)b * 128 + j] = h[b];
        M2[(size_t)b * 128 + j] = h2[b];
    }
}

// ------- fused scans: blocks [0,g) handle M, [g,2g) handle M2 ---------------
__global__ __launch_bounds__(256) void scan1f_kernel(
    const int* __restrict__ M, const int* __restrict__ M2,
    int* __restrict__ bsum, int g, int n) {
    int half = (blockIdx.x >= g) ? 1 : 0;
    int blk = blockIdx.x - half * g;
    const int* deg = half ? M2 : M;
    int tid = threadIdx.x;
    int base = blk * SCAN_CHUNK + tid * 4;
    int4 v = make_int4(0, 0, 0, 0);
    if (base + 3 < n) {
        v = *(const int4*)(deg + base);
    } else {
        if (base + 0 < n) v.x = deg[base + 0];
        if (base + 1 < n) v.y = deg[base + 1];
        if (base + 2 < n) v.z = deg[base + 2];
        if (base + 3 < n) v.w = deg[base + 3];
    }
    int s = v.x + v.y + v.z + v.w;
    __shared__ int red[256];
    red[tid] = s;
    __syncthreads();
#pragma unroll
    for (int off = 128; off > 0; off >>= 1) {
        if (tid < off) red[tid] += red[tid + off];
        __syncthreads();
    }
    if (tid == 0) bsum[blockIdx.x] = red[0];
}

__global__ __launch_bounds__(256) void scan3f_kernel(
    const int* __restrict__ M, const int* __restrict__ M2,
    const int* __restrict__ bsum, int* __restrict__ Mx, int* __restrict__ Mx2,
    int g, int n) {
    int half = (blockIdx.x >= g) ? 1 : 0;
    int blk = blockIdx.x - half * g;
    const int* deg = half ? M2 : M;
    int* outp = half ? Mx2 : Mx;
    int tid = threadIdx.x;
    int base = blk * SCAN_CHUNK + tid * 4;
    int4 v = make_int4(0, 0, 0, 0);
    if (base + 3 < n) {
        v = *(const int4*)(deg + base);
    } else {
        if (base + 0 < n) v.x = deg[base + 0];
        if (base + 1 < n) v.y = deg[base + 1];
        if (base + 2 < n) v.z = deg[base + 2];
        if (base + 3 < n) v.w = deg[base + 3];
    }
    int s = v.x + v.y + v.z + v.w;

    __shared__ int bs[128];
    if (tid < 128) bs[tid] = (tid < g) ? bsum[half * g + tid] : 0;
    __syncthreads();
#pragma unroll
    for (int off = 1; off < 128; off <<= 1) {
        int t = (tid < 128 && tid >= off) ? bs[tid - off] : 0;
        __syncthreads();
        if (tid < 128) bs[tid] += t;
        __syncthreads();
    }
    int blockbase = (blk == 0) ? 0 : bs[blk - 1];
    int total = bs[g - 1];

    __shared__ int sc[256];
    sc[tid] = s;
    __syncthreads();
#pragma unroll
    for (int off = 1; off < 256; off <<= 1) {
        int t = (tid >= off) ? sc[tid - off] : 0;
        __syncthreads();
        sc[tid] += t;
        __syncthreads();
    }
    int excl = sc[tid] - s + blockbase;
    int p0 = excl;
    int p1 = p0 + v.x;
    int p2 = p1 + v.y;
    int p3 = p2 + v.z;
    if (base + 3 < n) {
        *(int4*)(outp + base) = make_int4(p0, p1, p2, p3);
    } else {
        if (base + 0 < n) outp[base + 0] = p0;
        if (base + 1 < n) outp[base + 1] = p1;
        if (base + 2 < n) outp[base + 2] = p2;
    }
    if (blk == g - 1 && tid == 0) outp[n] = total;
}

// ------- fused bucket scatter: dst-packed + src-raw, one edge pass ----------
__global__ __launch_bounds__(256) void bucket_scatter2_kernel(
    const int* __restrict__ src, const int* __restrict__ dst,
    const int* __restrict__ Mx, const int* __restrict__ Mx2,
    uint32* __restrict__ packed, uint32* __restrict__ sp, int E, int nbuck) {
    __shared__ int cb1[512], c1[512], cb2[512], c2[512];
    int j = blockIdx.x;
    for (int i = threadIdx.x; i < nbuck; i += 256) {
        cb1[i] = Mx[(size_t)i * 128 + j];
        c1[i] = 0;
        cb2[i] = Mx2[(size_t)i * 128 + j];
        c2[i] = 0;
    }
    __syncthreads();
    int epb = (E + 127) >> 7;
    int estart = j * epb, eend = min(estart + epb, E);
    for (int e = estart + threadIdx.x; e < eend; e += 256) {
        int s = src[e], d = dst[e];
        int b = d >> 8;
        int r = atomicAdd(&c1[b], 1);
        packed[cb1[b] + r] = ((uint32)s << 8) | (uint32)(d & 255);
        int b2 = s >> 8;
        int r2 = atomicAdd(&c2[b2], 1);
        sp[cb2[b2] + r2] = (uint32)s;
    }
}

// ---- fused per-bucket CSR finalize (row_ptr/nd/ssrc) + src count (ns) ------
__global__ __launch_bounds__(256) void csr_src_kernel(
    const uint32* __restrict__ packed, const int* __restrict__ Mx,
    const uint32* __restrict__ sp, const int* __restrict__ Mx2,
    int* __restrict__ row_ptr, float* __restrict__ nd, float* __restrict__ ns,
    int* __restrict__ ssrc, int E, int N, int nbuck) {
    __shared__ int cnt[256], pos0[256], cur[256], sc[256], cnt2[256];
    int b = blockIdx.x, tid = threadIdx.x;
    int lo = Mx[(size_t)b * 128];
    int hi = (b == nbuck - 1) ? E : Mx[(size_t)(b + 1) * 128];
    int lo2 = Mx2[(size_t)b * 128];
    int hi2 = (b == nbuck - 1) ? E : Mx2[(size_t)(b + 1) * 128];
    cnt[tid] = 0;
    cur[tid] = 0;
    cnt2[tid] = 0;
    __syncthreads();
    for (int e = lo + tid; e < hi; e += 256)
        atomicAdd(&cnt[packed[e] & 255u], 1);
    for (int e = lo2 + tid; e < hi2; e += 256)
        atomicAdd(&cnt2[sp[e] & 255u], 1);
    __syncthreads();
    int c = cnt[tid];
    sc[tid] = c;
    __syncthreads();
#pragma unroll
    for (int off = 1; off < 256; off <<= 1) {
        int t = (tid >= off) ? sc[tid - off] : 0;
        __syncthreads();
        sc[tid] += t;
        __syncthreads();
    }
    int excl = sc[tid] - c;
    pos0[tid] = lo + excl;
    int node = b * 256 + tid;
    if (node < N) {
        row_ptr[node] = lo + excl;
        nd[node] = rsqrtf((float)max(c, 1));
        ns[node] = rsqrtf((float)max(cnt2[tid], 1));
    }
    if (b == 0 && tid == 0) row_ptr[N] = E;
    __syncthreads();
    for (int e = lo + tid; e < hi; e += 256) {
        uint32 p = packed[e];
        int local = (int)(p & 255u);
        int r = atomicAdd(&cur[local], 1);
        ssrc[pos0[local] + r] = (int)(p >> 8);
    }
}

// --- weight prep: Wt0/Wt1 [128][128], Wt2 [64][128] (rows 40..63 zero) ------
__global__ void prepw_kernel(const float* __restrict__ W0, const float* __restrict__ W1,
                             const float* __restrict__ W2,
                             ushort16* __restrict__ Wt0, ushort16* __restrict__ Wt1,
                             ushort16* __restrict__ Wt2) {
    int idx = blockIdx.x * 256 + threadIdx.x;  // 24576
    if (idx < 16384) {
        int n = idx & 127, k = idx >> 7;
        Wt0[n * 128 + k] = f2bf(W0[k * 128 + n]);
        Wt1[n * 128 + k] = f2bf(W1[k * 128 + n]);
    } else {
        int i2 = idx - 16384;  // < 8192
        int n = i2 >> 7, k = i2 & 127;
        Wt2[n * 128 + k] = (n < 40) ? f2bf(W2[k * 40 + n]) : (ushort16)0;
    }
}

// ---------------- MFMA GEMM (layers 0/1): 128x128 out, bf16 -----------------
template <bool XBF16, bool FUSE_BN>
__global__ __launch_bounds__(256) void gemm_mfma_kernel(
    const void* __restrict__ Xv, const ushort16* __restrict__ Wt,
    const float* __restrict__ ns, const float* __restrict__ stats,
    const float* __restrict__ gamma, const float* __restrict__ beta,
    float invn, ushort16* __restrict__ Yb, int nrows) {
    constexpr int LDK = 72;
    __shared__ short As[128 * LDK];
    __shared__ short Ws[128 * LDK];
    __shared__ float abl[256];
    int tid = threadIdx.x;
    int row0 = blockIdx.x * 128;
    int wave = tid >> 6, lane = tid & 63;
    int wm = (wave >> 1) * 64, wn = (wave & 1) * 64;
    int l15 = lane & 15, quad = lane >> 4;
    float4v acc[4][4] = {{}};

    if (FUSE_BN) {
        if (tid < 128) {
            float mean = stats[tid] * invn;
            float var = stats[128 + tid] * invn - mean * mean;
            float a = rsqrtf(var + 1e-5f) * gamma[tid];
            abl[tid] = a;
            abl[128 + tid] = beta[tid] - mean * a;
        }
        __syncthreads();
    }

#pragma unroll
    for (int p = 0; p < 2; ++p) {
        int k0 = p * 64;
        {
            int srow = tid >> 1;
            int half = (tid & 1) * 32;
            int grow = row0 + srow;
            bool ok = grow < nrows;
            float sc = ok ? ns[grow] : 0.f;
            uint32 outu[16];
            if (XBF16) {
                const uint4* xp = (const uint4*)((const uint32*)Xv +
                                                 (size_t)grow * 64 + ((k0 + half) >> 1));
                uint4 u4[4];
#pragma unroll
                for (int q = 0; q < 4; ++q)
                    u4[q] = ok ? xp[q] : make_uint4(0, 0, 0, 0);
                const uint32* uu = (const uint32*)u4;
#pragma unroll
                for (int j = 0; j < 16; ++j) {
                    float2 f = bf2f2(uu[j]);
                    if (FUSE_BN) {
                        int c = k0 + half + j * 2;
                        f.x = fmaxf(fmaf(f.x, abl[c], abl[128 + c]), 0.f);
                        f.y = fmaxf(fmaf(f.y, abl[c + 1], abl[128 + c + 1]), 0.f);
                    }
                    outu[j] = (uint32)f2bf(f.x * sc) | ((uint32)f2bf(f.y * sc) << 16);
                }
            } else {
                const float4* xp = (const float4*)((const float*)Xv +
                                                   (size_t)grow * 128 + k0 + half);
                float4 f4[8];
#pragma unroll
                for (int q = 0; q < 8; ++q)
                    f4[q] = ok ? xp[q] : make_float4(0.f, 0.f, 0.f, 0.f);
                const float* ff = (const float*)f4;
#pragma unroll
                for (int j = 0; j < 16; ++j) {
                    float fx = ff[2 * j], fy = ff[2 * j + 1];
                    outu[j] = (uint32)f2bf(fx * sc) | ((uint32)f2bf(fy * sc) << 16);
                }
            }
            uint4* dstA = (uint4*)&As[srow * LDK + half];
#pragma unroll
            for (int q = 0; q < 4; ++q) dstA[q] = ((uint4*)outu)[q];
            const uint4* wp = (const uint4*)((const uint32*)Wt +
                                             srow * 64 + ((k0 + half) >> 1));
            uint4* dstW = (uint4*)&Ws[srow * LDK + half];
#pragma unroll
            for (int q = 0; q < 4; ++q) dstW[q] = wp[q];
        }
        __syncthreads();
#pragma unroll
        for (int ks = 0; ks < 2; ++ks) {
            int koff = ks * 32 + quad * 8;
            short8v a[4], b[4];
#pragma unroll
            for (int t = 0; t < 4; ++t)
                a[t] = *(const short8v*)&As[(wm + t * 16 + l15) * LDK + koff];
#pragma unroll
            for (int u = 0; u < 4; ++u)
                b[u] = *(const short8v*)&Ws[(wn + u * 16 + l15) * LDK + koff];
#pragma unroll
            for (int t = 0; t < 4; ++t)
#pragma unroll
                for (int u = 0; u < 4; ++u)
                    acc[t][u] = __builtin_amdgcn_mfma_f32_16x16x32_bf16(
                        a[t], b[u], acc[t][u], 0, 0, 0);
        }
        __syncthreads();
    }
#pragma unroll
    for (int t = 0; t < 4; ++t) {
#pragma unroll
        for (int r = 0; r < 4; ++r) {
            int grow = row0 + wm + t * 16 + quad * 4 + r;
            if (grow < nrows) {
#pragma unroll
                for (int u = 0; u < 4; ++u)
                    Yb[(size_t)grow * 128 + wn + u * 16 + l15] = f2bf(acc[t][u][r]);
            }
        }
    }
}

// ---- layer-2 projection: Y2b = bf16((ns*relu(bn1(Ab))) @ W2), 128->64 ------
__global__ __launch_bounds__(256) void gemm_mfma2_kernel(
    const uint32* __restrict__ Xb, const ushort16* __restrict__ Wt2,
    const float* __restrict__ ns, const float* __restrict__ stats,
    const float* __restrict__ gamma, const float* __restrict__ beta,
    float invn, ushort16* __restrict__ Y2b, int nrows) {
    constexpr int LDK = 72;
    __shared__ short As[128 * LDK];
    __shared__ short Ws[64 * LDK];
    __shared__ float abl[256];
    int tid = threadIdx.x;
    int row0 = blockIdx.x * 128;
    int wave = tid >> 6, lane = tid & 63;
    int wm = (wave >> 1) * 64, wn = (wave & 1) * 32;
    int l15 = lane & 15, quad = lane >> 4;
    float4v acc[4][2] = {{}};

    if (tid < 128) {
        float mean = stats[tid] * invn;
        float var = stats[128 + tid] * invn - mean * mean;
        float a = rsqrtf(var + 1e-5f) * gamma[tid];
        abl[tid] = a;
        abl[128 + tid] = beta[tid] - mean * a;
    }
    __syncthreads();

#pragma unroll
    for (int p = 0; p < 2; ++p) {
        int k0 = p * 64;
        {
            int srow = tid >> 1;
            int half = (tid & 1) * 32;
            int grow = row0 + srow;
            bool ok = grow < nrows;
            float sc = ok ? ns[grow] : 0.f;
            const uint4* xp = (const uint4*)(Xb + (size_t)grow * 64 + ((k0 + half) >> 1));
            uint4 u4[4];
#pragma unroll
            for (int q = 0; q < 4; ++q)
                u4[q] = ok ? xp[q] : make_uint4(0, 0, 0, 0);
            const uint32* uu = (const uint32*)u4;
            uint32 outu[16];
#pragma unroll
            for (int j = 0; j < 16; ++j) {
                float2 f = bf2f2(uu[j]);
                int c = k0 + half + j * 2;
                f.x = fmaxf(fmaf(f.x, abl[c], abl[128 + c]), 0.f);
                f.y = fmaxf(fmaf(f.y, abl[c + 1], abl[128 + c + 1]), 0.f);
                outu[j] = (uint32)f2bf(f.x * sc) | ((uint32)f2bf(f.y * sc) << 16);
            }
            uint4* dstA = (uint4*)&As[srow * LDK + half];
#pragma unroll
            for (int q = 0; q < 4; ++q) dstA[q] = ((uint4*)outu)[q];
        }
        {
            int srow = tid >> 2;           // 64 rows
            int off = (tid & 3) * 16;      // 16 shorts each
            const uint4* wp = (const uint4*)((const uint32*)Wt2 +
                                             srow * 64 + ((k0 + off) >> 1));
            uint4* dw = (uint4*)&Ws[srow * LDK + off];
            dw[0] = wp[0];
            dw[1] = wp[1];
        }
        __syncthreads();
#pragma unroll
        for (int ks = 0; ks < 2; ++ks) {
            int koff = ks * 32 + quad * 8;
            short8v a[4], b[2];
#pragma unroll
            for (int t = 0; t < 4; ++t)
                a[t] = *(const short8v*)&As[(wm + t * 16 + l15) * LDK + koff];
#pragma unroll
            for (int u = 0; u < 2; ++u)
                b[u] = *(const short8v*)&Ws[(wn + u * 16 + l15) * LDK + koff];
#pragma unroll
            for (int t = 0; t < 4; ++t)
#pragma unroll
                for (int u = 0; u < 2; ++u)
                    acc[t][u] = __builtin_amdgcn_mfma_f32_16x16x32_bf16(
                        a[t], b[u], acc[t][u], 0, 0, 0);
        }
        __syncthreads();
    }
#pragma unroll
    for (int t = 0; t < 4; ++t) {
#pragma unroll
        for (int r = 0; r < 4; ++r) {
            int grow = row0 + wm + t * 16 + quad * 4 + r;
            if (grow < nrows) {
#pragma unroll
                for (int u = 0; u < 2; ++u)
                    Y2b[(size_t)grow * 64 + wn + u * 16 + l15] = f2bf(acc[t][u][r]);
            }
        }
    }
}

// ------- CSR aggregation (bf16 in/out), 128-wide hidden layers --------------
__global__ __launch_bounds__(256) void agg128_kernel(
    const uint32* __restrict__ xwb, const int* __restrict__ row_ptr,
    const int* __restrict__ ssrc, const float* __restrict__ nd,
    uint32* __restrict__ outb, int n) {
    int node = blockIdx.x * 4 + (threadIdx.x >> 6);
    if (node >= n) return;
    int lane = threadIdx.x & 63;
    int beg = row_ptr[node], end = row_ptr[node + 1];
    float x = 0.f, y = 0.f;
    int e = beg;
    for (; e + 8 <= end; e += 8) {
        int s[8];
#pragma unroll
        for (int j = 0; j < 8; ++j) s[j] = ssrc[e + j];
        uint32 u[8];
#pragma unroll
        for (int j = 0; j < 8; ++j) u[j] = xwb[(size_t)s[j] * 64 + lane];
#pragma unroll
        for (int j = 0; j < 8; ++j) {
            float2 v = bf2f2(u[j]);
            x += v.x;
            y += v.y;
        }
    }
    for (; e + 2 <= end; e += 2) {
        uint32 u0 = xwb[(size_t)ssrc[e] * 64 + lane];
        uint32 u1 = xwb[(size_t)ssrc[e + 1] * 64 + lane];
        float2 v0 = bf2f2(u0), v1 = bf2f2(u1);
        x += v0.x + v1.x;
        y += v0.y + v1.y;
    }
    if (e < end) {
        float2 v0 = bf2f2(xwb[(size_t)ssrc[e] * 64 + lane]);
        x += v0.x;
        y += v0.y;
    }
    float s = nd[node];
    outb[(size_t)node * 64 + lane] =
        (uint32)f2bf(x * s) | ((uint32)f2bf(y * s) << 16);
}

// ---- layer-2 aggregation: out[v,c] = nd[v]*sum Y2b[src,c] + b2[c], c<40 ----
// full wave per node; lane&31 = uint idx (2 cols of 64); lane>>5 = edge parity
// (2 edges/step, 4-batched = 8 edges in flight); shuffle-combine at end.
__global__ __launch_bounds__(256) void agg40_kernel(
    const uint32* __restrict__ y2b, const int* __restrict__ row_ptr,
    const int* __restrict__ ssrc, const float* __restrict__ nd,
    const float* __restrict__ bias, float* __restrict__ out, int n) {
    int node = blockIdx.x * 4 + (threadIdx.x >> 6);
    if (node >= n) return;
    int lane = threadIdx.x & 63;
    int l32 = lane & 31;
    int par = lane >> 5;
    int beg = row_ptr[node], end = row_ptr[node + 1];
    float x = 0.f, y = 0.f;
    int e = beg;
    for (; e + 8 <= end; e += 8) {
        int s[4];
#pragma unroll
        for (int j = 0; j < 4; ++j) s[j] = ssrc[e + 2 * j + par];
        uint32 u[4];
#pragma unroll
        for (int j = 0; j < 4; ++j) u[j] = y2b[(size_t)s[j] * 32 + l32];
#pragma unroll
        for (int j = 0; j < 4; ++j) {
            float2 v = bf2f2(u[j]);
            x += v.x;
            y += v.y;
        }
    }
    for (; e + 2 <= end; e += 2) {
        uint32 u0 = y2b[(size_t)ssrc[e + par] * 32 + l32];
        float2 v = bf2f2(u0);
        x += v.x;
        y += v.y;
    }
    if (e < end && par == 0) {
        float2 v = bf2f2(y2b[(size_t)ssrc[e] * 32 + l32]);
        x += v.x;
        y += v.y;
    }
    // combine the two edge-parity halves: lane i += lane i+32
    x += __shfl_down(x, 32, 64);
    y += __shfl_down(y, 32, 64);
    if (par == 0 && l32 < 20) {
        float s = nd[node];
        int c = l32 * 2;
        float2 bb = *(const float2*)&bias[c];
        *(float2*)(out + (size_t)node * 40 + c) =
            make_float2(fmaf(x, s, bb.x), fmaf(y, s, bb.y));
    }
}

// -------- batchnorm stats (bf16 input, uint4 loads, 8 cols/thread) ----------
__global__ __launch_bounds__(256) void bn_reduce_kernel(const uint4* __restrict__ x4,
                                                        float* __restrict__ stats, int n) {
    int tid = threadIdx.x;
    int ctile = tid & 15;    // 16 col-tiles of 8 cols
    int rgrp = tid >> 4;     // 16 row groups
    float s[8] = {}, s2[8] = {};
    for (int r = blockIdx.x * 16 + rgrp; r < n; r += gridDim.x * 16) {
        uint4 u = x4[(size_t)r * 16 + ctile];
        uint32 uu[4] = {u.x, u.y, u.z, u.w};
#pragma unroll
        for (int q = 0; q < 4; ++q) {
            float2 v = bf2f2(uu[q]);
            s[q * 2] += v.x;
            s[q * 2 + 1] += v.y;
            s2[q * 2] = fmaf(v.x, v.x, s2[q * 2]);
            s2[q * 2 + 1] = fmaf(v.y, v.y, s2[q * 2 + 1]);
        }
    }
    __shared__ float ls[128], ls2[128];
    if (tid < 128) { ls[tid] = 0.f; ls2[tid] = 0.f; }
    __syncthreads();
#pragma unroll
    for (int j = 0; j < 8; ++j) {
        atomicAdd(&ls[ctile * 8 + j], s[j]);
        atomicAdd(&ls2[ctile * 8 + j], s2[j]);
    }
    __syncthreads();
    if (tid < 128) {
        atomicAdd(&stats[tid], ls[tid]);
        atomicAdd(&stats[128 + tid], ls2[tid]);
    }
}

// ---------------- launch ----------------

extern "C" void kernel_launch(void* const* d_in, const int* in_sizes, int n_in,
                              void* d_out, int out_size, void* d_ws, size_t ws_size,
                              hipStream_t stream) {
    const float* feat = (const float*)d_in[0];
    const int* edge_src = (const int*)d_in[1];
    const int* edge_dst = (const int*)d_in[2];
    const float* W0 = (const float*)d_in[3];
    const float* W1 = (const float*)d_in[4];
    const float* W2 = (const float*)d_in[5];
    const float* b2 = (const float*)d_in[6];
    const float* g0 = (const float*)d_in[7];
    const float* beta0 = (const float*)d_in[8];
    const float* g1 = (const float*)d_in[9];
    const float* beta1 = (const float*)d_in[10];
    float* out = (float*)d_out;

    const int N = in_sizes[0] / D_H;   // 100000
    const int E = in_sizes[1];         // 1600000
    const int nbuck = (N + 255) >> 8;  // 391
    const float invN = 1.0f / (float)N;

    char* p = (char*)d_ws;
    auto alloc = [&](size_t bytes) {
        char* r = p;
        p += (bytes + 255) & ~(size_t)255;
        return r;
    };
    uint32* Ab = (uint32*)alloc((size_t)N * D_H * 2);   // bf16 A (packed pairs)
    uint32* Bb = (uint32*)alloc((size_t)N * D_H * 2);   // bf16 B / Y2b (N x 32 uints)
    float* ns = (float*)alloc((size_t)N * 4);
    float* nd = (float*)alloc((size_t)N * 4);
    int* row_ptr = (int*)alloc((size_t)(N + 1) * 4);
    int* ssrc = (int*)alloc((size_t)E * 4);
    uint32* packed = (uint32*)alloc((size_t)E * 4);
    uint32* sp = (uint32*)alloc((size_t)E * 4);
    int* M = (int*)alloc((size_t)nbuck * 128 * 4);
    int* Mx = (int*)alloc(((size_t)nbuck * 128 + 4) * 4);
    int* M2 = (int*)alloc((size_t)nbuck * 128 * 4);
    int* Mx2 = (int*)alloc(((size_t)nbuck * 128 + 4) * 4);
    int* bsum = (int*)alloc(256 * 4);
    float* stats0 = (float*)alloc(256 * 4);   // contiguous with stats1
    float* stats1 = (float*)alloc(256 * 4);
    ushort16* Wt0 = (ushort16*)alloc(128 * 128 * 2);
    ushort16* Wt1 = (ushort16*)alloc(128 * 128 * 2);
    ushort16* Wt2 = (ushort16*)alloc(64 * 128 * 2);
    (void)ws_size;

    hipMemsetAsync(stats0, 0, 2048, stream);  // stats0 + stats1 (adjacent)

    const int ggrid = (N + 127) / 128;
    const int agrid = (N + 3) / 4;
    const int nM = nbuck * 128;                            // 50048
    const int sgridM = (nM + SCAN_CHUNK - 1) / SCAN_CHUNK; // 49

    prepw_kernel<<<96, 256, 0, stream>>>(W0, W1, W2, Wt0, Wt1, Wt2);

    bucket_count2_kernel<<<128, 256, 0, stream>>>(edge_src, edge_dst, M, M2, E, nbuck);
    scan1f_kernel<<<2 * sgridM, 256, 0, stream>>>(M, M2, bsum, sgridM, nM);
    scan3f_kernel<<<2 * sgridM, 256, 0, stream>>>(M, M2, bsum, Mx, Mx2, sgridM, nM);
    bucket_scatter2_kernel<<<128, 256, 0, stream>>>(edge_src, edge_dst, Mx, Mx2,
                                                    packed, sp, E, nbuck);
    csr_src_kernel<<<nbuck, 256, 0, stream>>>(packed, Mx, sp, Mx2, row_ptr, nd, ns,
                                              ssrc, E, N, nbuck);

    // layer 0
    gemm_mfma_kernel<false, false><<<ggrid, 256, 0, stream>>>(
        feat, Wt0, ns, nullptr, nullptr, nullptr, invN, (ushort16*)Bb, N);
    agg128_kernel<<<agrid, 256, 0, stream>>>(Bb, row_ptr, ssrc, nd, Ab, N);
    bn_reduce_kernel<<<512, 256, 0, stream>>>((const uint4*)Ab, stats0, N);

    // layer 1
    gemm_mfma_kernel<true, true><<<ggrid, 256, 0, stream>>>(
        Ab, Wt1, ns, stats0, g0, beta0, invN, (ushort16*)Bb, N);
    agg128_kernel<<<agrid, 256, 0, stream>>>(Bb, row_ptr, ssrc, nd, Ab, N);
    bn_reduce_kernel<<<512, 256, 0, stream>>>((const uint4*)Ab, stats1, N);

    // layer 2: project (BN+relu+ns in staging) -> Y2b (N x 64 bf16); agg40 -> out
    gemm_mfma2_kernel<<<ggrid, 256, 0, stream>>>(
        Ab, Wt2, ns, stats1, g1, beta1, invN, (ushort16*)Bb, N);
    agg40_kernel<<<agrid, 256, 0, stream>>>(Bb, row_ptr, ssrc, nd, b2, out, N);
}